// Round 4
// baseline (26737.085 us; speedup 1.0000x reference)
//
#include <hip/hip_runtime.h>

#define CDIV(a,b) (((a)+(b)-1)/(b))

static const int N_ATOM = 131072, N_FRAG = 32768, N_EDGE = 262144,
                 N_FEDGE = 65536, N_MEM = 196608, BATCH = 4096, H = 256;

typedef unsigned short ushort_t;

__device__ __forceinline__ float bf2f(unsigned short u) {
    return __uint_as_float(((unsigned int)u) << 16);
}
__device__ __forceinline__ unsigned short f2bf(float f) {
    unsigned int x = __float_as_uint(f);
    x += 0x7FFFu + ((x >> 16) & 1u);   // round-to-nearest-even
    return (unsigned short)(x >> 16);
}

// diagnostic: if workspace too small, d_out = ws_size/1024 (KB)
__global__ void fill_const(float* p, long n, float v) {
    long t = (long)blockIdx.x * blockDim.x + threadIdx.x;
    long stride = (long)gridDim.x * blockDim.x;
    for (; t < n; t += stride) p[t] = v;
}

// ---------------------------------------------------------------------------
// Tiled GEMM: C = op(A)@W + bias (+ReLU). mu: subtract mu[col] before bf16
// store (mean-shift for BN conditioning). cstat: fused fp32 col sum/sumsq
// (cstat[col], cstat[M+col]) of the stored (rounded) values.
// aidx: A-row gather. sidx: scatter-atomicAdd epilogue (f32 out only).
// ---------------------------------------------------------------------------
template<int RELU, typename TA, typename TC>
__global__ __launch_bounds__(256)
void gemm_k(const TA* __restrict__ A, const float* __restrict__ W,
            const float* __restrict__ bias, TC* __restrict__ C,
            const int* __restrict__ aidx, const int* __restrict__ sidx,
            const float* __restrict__ mu, float* __restrict__ cstat,
            int N, int K, int M)
{
    const int BK = 16, LDA = 132;
    __shared__ float As[BK * LDA];
    __shared__ float Bs[BK * LDA];
    const int brow = blockIdx.y * 128;
    const int bcol = blockIdx.x * 128;
    const int tid  = threadIdx.x;
    const int tr = tid >> 4, tc = tid & 15;

    float acc[8][8];
    #pragma unroll
    for (int i = 0; i < 8; ++i)
        #pragma unroll
        for (int j = 0; j < 8; ++j) acc[i][j] = 0.f;

    for (int k0 = 0; k0 < K; k0 += BK) {
        if constexpr (sizeof(TA) == 2) {
            #pragma unroll
            for (int u = 0; u < 4; ++u) {
                int idx = tid + u * 256;            // 0..1023
                int m = idx >> 3, kk2 = (idx & 7) * 2;
                int row = brow + m;
                long ar = aidx ? (long)aidx[row] : (long)row;
                ushort2 p = *(const ushort2*)(A + ar * (long)K + k0 + kk2);
                As[kk2 * LDA + m]       = bf2f(p.x);
                As[(kk2 + 1) * LDA + m] = bf2f(p.y);
            }
        } else {
            #pragma unroll
            for (int u = 0; u < 8; ++u) {
                int idx = tid + u * 256;            // 0..2047
                int m = idx >> 4, kk = idx & 15;
                int row = brow + m;
                long ar = aidx ? (long)aidx[row] : (long)row;
                As[kk * LDA + m] = ((const float*)A)[ar * (long)K + k0 + kk];
            }
        }
        #pragma unroll
        for (int u = 0; u < 8; ++u) {
            int idx = tid + u * 256;
            int kk = idx >> 7, n = idx & 127;
            int col = bcol + n;
            Bs[kk * LDA + n] = (col < M) ? W[(long)(k0 + kk) * M + col] : 0.f;
        }
        __syncthreads();
        #pragma unroll
        for (int kk = 0; kk < BK; ++kk) {
            float av[8], bv[8];
            float4 a0 = *(const float4*)&As[kk * LDA + tr * 8];
            float4 a1 = *(const float4*)&As[kk * LDA + tr * 8 + 4];
            float4 b0 = *(const float4*)&Bs[kk * LDA + tc * 8];
            float4 b1 = *(const float4*)&Bs[kk * LDA + tc * 8 + 4];
            av[0]=a0.x; av[1]=a0.y; av[2]=a0.z; av[3]=a0.w;
            av[4]=a1.x; av[5]=a1.y; av[6]=a1.z; av[7]=a1.w;
            bv[0]=b0.x; bv[1]=b0.y; bv[2]=b0.z; bv[3]=b0.w;
            bv[4]=b1.x; bv[5]=b1.y; bv[6]=b1.z; bv[7]=b1.w;
            #pragma unroll
            for (int i = 0; i < 8; ++i)
                #pragma unroll
                for (int j = 0; j < 8; ++j)
                    acc[i][j] = fmaf(av[i], bv[j], acc[i][j]);
        }
        __syncthreads();
    }

    if constexpr (sizeof(TC) == 2) {
        float csum[8], cssq[8];
        #pragma unroll
        for (int j = 0; j < 8; ++j) { csum[j] = 0.f; cssq[j] = 0.f; }
        #pragma unroll
        for (int i = 0; i < 8; ++i) {
            int row = brow + tr * 8 + i;
            unsigned short us[8];
            #pragma unroll
            for (int j = 0; j < 8; ++j) {
                int col = bcol + tc * 8 + j;
                float v = acc[i][j] + bias[col];
                if (mu) v -= mu[col];
                if (RELU) v = fmaxf(v, 0.f);
                us[j] = f2bf(v);
                if (cstat) {
                    float vq = bf2f(us[j]);
                    csum[j] += vq; cssq[j] = fmaf(vq, vq, cssq[j]);
                }
            }
            ushort4 s0, s1;
            s0.x=us[0]; s0.y=us[1]; s0.z=us[2]; s0.w=us[3];
            s1.x=us[4]; s1.y=us[5]; s1.z=us[6]; s1.w=us[7];
            *(ushort4*)((ushort_t*)C + (long)row * M + bcol + tc * 8)     = s0;
            *(ushort4*)((ushort_t*)C + (long)row * M + bcol + tc * 8 + 4) = s1;
        }
        if (cstat) {   // block-level column reduce reusing As/Bs (post-loop)
            #pragma unroll
            for (int j = 0; j < 8; ++j) {
                As[tr * 128 + tc * 8 + j] = csum[j];
                Bs[tr * 128 + tc * 8 + j] = cssq[j];
            }
            __syncthreads();
            if (tid < 128) {
                float s = 0.f, sq = 0.f;
                #pragma unroll
                for (int r = 0; r < 16; ++r) {
                    s  += As[r * 128 + tid];
                    sq += Bs[r * 128 + tid];
                }
                atomicAdd(&cstat[bcol + tid], s);
                atomicAdd(&cstat[M + bcol + tid], sq);
            }
        }
    } else {
        #pragma unroll
        for (int i = 0; i < 8; ++i) {
            int row = brow + tr * 8 + i;
            long orow = sidx ? (long)sidx[row] : (long)row;
            #pragma unroll
            for (int j = 0; j < 8; ++j) {
                int col = bcol + tc * 8 + j;
                if (col < M) {
                    float v = acc[i][j] + bias[col];
                    if (RELU) v = fmaxf(v, 0.f);
                    if (sidx) atomicAdd((float*)C + orow * M + col, v);
                    else      ((float*)C)[orow * M + col] = v;
                }
            }
        }
    }
}

// mu[c] = (colsum_x[c'] dot W[:,c]) * invN + bias[c]
__global__ void mu_gemv(const float* __restrict__ colsum_x, const float* __restrict__ W,
                        const float* __restrict__ bias, float* __restrict__ mu,
                        int K, int M, float invN)
{
    int c = blockIdx.x * blockDim.x + threadIdx.x;
    if (c >= M) return;
    float acc = 0.f;
    for (int k = 0; k < K; ++k) acc = fmaf(colsum_x[k], W[(long)k * M + c], acc);
    mu[c] = acc * invN + bias[c];
}

// ---------------------------------------------------------------------------
// GINE: agg[dst[i]] += relu(a[src[i]] + edge_attr[i] @ Wb + bb), a bf16.
// ---------------------------------------------------------------------------
__global__ __launch_bounds__(256)
void gine_scatter(const ushort_t* __restrict__ a, const float* __restrict__ eattr,
                  const float* __restrict__ Wb, const float* __restrict__ bb,
                  const int* __restrict__ src, const int* __restrict__ dst,
                  float* __restrict__ agg, long nE)
{
    __shared__ float Ws[16][256];
    __shared__ float bs[256];
    for (int i = threadIdx.x; i < 16 * 256; i += 256) Ws[i >> 8][i & 255] = Wb[i];
    bs[threadIdx.x] = bb[threadIdx.x];
    __syncthreads();

    long t = (long)blockIdx.x * 256 + threadIdx.x;
    if (t >= nE * 64) return;
    long i = t >> 6; int lane = (int)(t & 63);
    int s = src[i], d = dst[i];

    float ev[16];
    const float4* ea = (const float4*)(eattr + i * 16);
    float4 e0 = ea[0], e1 = ea[1], e2 = ea[2], e3 = ea[3];
    ev[0]=e0.x; ev[1]=e0.y; ev[2]=e0.z; ev[3]=e0.w;
    ev[4]=e1.x; ev[5]=e1.y; ev[6]=e1.z; ev[7]=e1.w;
    ev[8]=e2.x; ev[9]=e2.y; ev[10]=e2.z; ev[11]=e2.w;
    ev[12]=e3.x; ev[13]=e3.y; ev[14]=e3.z; ev[15]=e3.w;

    #pragma unroll
    for (int j = 0; j < 4; ++j) {
        int c = lane + j * 64;
        float r = bs[c];
        #pragma unroll
        for (int k = 0; k < 16; ++k) r = fmaf(ev[k], Ws[k][c], r);
        r += bf2f(a[(long)s * 256 + c]);
        r = fmaxf(r, 0.f);
        atomicAdd(&agg[(long)d * 256 + c], r);
    }
}

// out[sidx[i]] += T[gidx ? gidx[i] : i]  (256-ch rows)
template<typename TS>
__global__ __launch_bounds__(256)
void scatter_add_rows(const TS* __restrict__ T, const int* __restrict__ gidx,
                      const int* __restrict__ sidx, float* __restrict__ out, long nrows)
{
    long t = (long)blockIdx.x * 256 + threadIdx.x;
    if (t >= nrows * 64) return;
    long i = t >> 6; int c4 = (int)(t & 63);
    long srow = gidx ? (long)gidx[i] : i;
    float4 v;
    if constexpr (sizeof(TS) == 2) {
        ushort4 u = *(const ushort4*)((const ushort_t*)T + srow * 256 + c4 * 4);
        v.x = bf2f(u.x); v.y = bf2f(u.y); v.z = bf2f(u.z); v.w = bf2f(u.w);
    } else {
        v = *(const float4*)((const float*)T + srow * 256 + c4 * 4);
    }
    float* o = out + (long)sidx[i] * 256 + c4 * 4;
    atomicAdd(o + 0, v.x); atomicAdd(o + 1, v.y);
    atomicAdd(o + 2, v.z); atomicAdd(o + 3, v.w);
}

// a(bf16) <- (1+eps)*a + agg(f32); fused col-sum of result (H=256 fixed).
__global__ __launch_bounds__(256)
void combine_eps_bf(ushort_t* __restrict__ a, const float* __restrict__ agg,
                    const float* __restrict__ eps, long n4, float* __restrict__ colsum)
{
    __shared__ float ls[1024];
    float s = 1.f + eps[0];
    int tid = threadIdx.x;
    long stride = (long)gridDim.x * 256;
    float loc[4] = {0.f, 0.f, 0.f, 0.f};
    for (long t = (long)blockIdx.x * 256 + tid; t < n4; t += stride) {
        ushort4 av = ((const ushort4*)a)[t];
        float4 gv = ((const float4*)agg)[t];
        ushort4 r;
        r.x = f2bf(fmaf(s, bf2f(av.x), gv.x));
        r.y = f2bf(fmaf(s, bf2f(av.y), gv.y));
        r.z = f2bf(fmaf(s, bf2f(av.z), gv.z));
        r.w = f2bf(fmaf(s, bf2f(av.w), gv.w));
        ((ushort4*)a)[t] = r;
        loc[0] += bf2f(r.x); loc[1] += bf2f(r.y);
        loc[2] += bf2f(r.z); loc[3] += bf2f(r.w);
    }
    #pragma unroll
    for (int j = 0; j < 4; ++j) ls[tid * 4 + j] = loc[j];
    __syncthreads();
    if (tid < 64) {     // quad cq = tid&63 is shared by tid, tid+64, +128, +192
        #pragma unroll
        for (int j = 0; j < 4; ++j) {
            float v = ls[tid*4+j] + ls[(tid+64)*4+j] + ls[(tid+128)*4+j] + ls[(tid+192)*4+j];
            atomicAdd(&colsum[tid * 4 + j], v);
        }
    }
}

// y = relu((xs - m')*sc*g + b) vectorized; optional fused col-sum of y.
// Requires (gridDim*256) % (MqMask+1) == 0 so each thread's col-quad is fixed.
template<int RELU>
__global__ __launch_bounds__(256)
void bn_apply_v(const ushort_t* __restrict__ X, ushort_t* __restrict__ Y, long nq, int MqMask,
                const float* __restrict__ cstat, int M,
                const float* __restrict__ g, const float* __restrict__ b, float invN,
                float* __restrict__ colsum_out)
{
    int tid = threadIdx.x;
    long t0 = (long)blockIdx.x * 256 + tid;
    int cq = (int)(t0 & MqMask);
    float sa[4], sb[4], loc[4] = {0.f, 0.f, 0.f, 0.f};
    #pragma unroll
    for (int j = 0; j < 4; ++j) {
        int c = cq * 4 + j;
        float m = cstat[c] * invN;
        float var = cstat[M + c] * invN - m * m;
        float sc = rsqrtf(var + 1e-5f) * g[c];
        sa[j] = sc; sb[j] = b[c] - m * sc;
    }
    long stride = (long)gridDim.x * 256;
    for (long t = t0; t < nq; t += stride) {
        ushort4 xv = ((const ushort4*)X)[t];
        float y0 = bf2f(xv.x) * sa[0] + sb[0];
        float y1 = bf2f(xv.y) * sa[1] + sb[1];
        float y2 = bf2f(xv.z) * sa[2] + sb[2];
        float y3 = bf2f(xv.w) * sa[3] + sb[3];
        if (RELU) { y0=fmaxf(y0,0.f); y1=fmaxf(y1,0.f); y2=fmaxf(y2,0.f); y3=fmaxf(y3,0.f); }
        ushort4 r; r.x=f2bf(y0); r.y=f2bf(y1); r.z=f2bf(y2); r.w=f2bf(y3);
        ((ushort4*)Y)[t] = r;
        loc[0]+=bf2f(r.x); loc[1]+=bf2f(r.y); loc[2]+=bf2f(r.z); loc[3]+=bf2f(r.w);
    }
    if (colsum_out) {
        #pragma unroll
        for (int j = 0; j < 4; ++j) atomicAdd(&colsum_out[cq * 4 + j], loc[j]);
    }
}

__global__ void count_idx(const int* __restrict__ idx, int n, int* __restrict__ cnt)
{
    int i = blockIdx.x * blockDim.x + threadIdx.x;
    if (i < n) atomicAdd(&cnt[idx[i]], 1);
}

template<int ASSIGN, typename TOUT>
__global__ __launch_bounds__(256)
void apply_mean(TOUT* __restrict__ out, const float* __restrict__ sums,
                const int* __restrict__ cnt, long nrows)
{
    long t = (long)blockIdx.x * 256 + threadIdx.x;
    if (t >= nrows * 64) return;
    long row = t >> 6;
    float dinv = 1.f / fmaxf((float)cnt[row], 1.f);
    float4 v = *(const float4*)(sums + t * 4);
    v.x *= dinv; v.y *= dinv; v.z *= dinv; v.w *= dinv;
    if constexpr (ASSIGN) {
        *(float4*)((float*)out + t * 4) = v;
    } else {
        ushort4* o = (ushort4*)((ushort_t*)out + t * 4);
        ushort4 c = *o;
        c.x = f2bf(bf2f(c.x) + v.x); c.y = f2bf(bf2f(c.y) + v.y);
        c.z = f2bf(bf2f(c.z) + v.z); c.w = f2bf(bf2f(c.w) + v.w);
        *o = c;
    }
}

__global__ void vadd(float* __restrict__ out, const float* __restrict__ in, long n4)
{
    long t = (long)blockIdx.x * blockDim.x + threadIdx.x;
    if (t >= n4) return;
    float4 a = ((float4*)out)[t];
    float4 b = ((const float4*)in)[t];
    a.x += b.x; a.y += b.y; a.z += b.z; a.w += b.w;
    ((float4*)out)[t] = a;
}

// ---------------------------------------------------------------------------
extern "C" void kernel_launch(void* const* d_in, const int* in_sizes, int n_in,
                              void* d_out, int out_size, void* d_ws, size_t ws_size,
                              hipStream_t stream)
{
    (void)in_sizes; (void)n_in;
    const float* x          = (const float*)d_in[0];
    const float* fragments  = (const float*)d_in[1];
    const float* edge_attr  = (const float*)d_in[2];
    const float* atom_enc_W = (const float*)d_in[3];
    const float* atom_enc_b = (const float*)d_in[4];
    const float* frag_enc_W = (const float*)d_in[5];
    const float* frag_enc_b = (const float*)d_in[6];
    const float* bond_W     = (const float*)d_in[7];
    const float* bond_b     = (const float*)d_in[8];
    const float* gine_eps   = (const float*)d_in[9];
    const float* gine_W1    = (const float*)d_in[10];
    const float* gine_b1    = (const float*)d_in[11];
    const float* gine_bn_g  = (const float*)d_in[12];
    const float* gine_bn_b  = (const float*)d_in[13];
    const float* gine_W2    = (const float*)d_in[14];
    const float* gine_b2    = (const float*)d_in[15];
    const float* atom_bn_g  = (const float*)d_in[16];
    const float* atom_bn_b  = (const float*)d_in[17];
    const float* gin_eps    = (const float*)d_in[18];
    const float* gin_W1     = (const float*)d_in[19];
    const float* gin_b1     = (const float*)d_in[20];
    const float* gin_bn_g   = (const float*)d_in[21];
    const float* gin_bn_b   = (const float*)d_in[22];
    const float* gin_W2     = (const float*)d_in[23];
    const float* gin_b2     = (const float*)d_in[24];
    const float* frag_bn_g  = (const float*)d_in[25];
    const float* frag_bn_b  = (const float*)d_in[26];
    const float* a2f_W      = (const float*)d_in[27];
    const float* a2f_b      = (const float*)d_in[28];
    const float* f2a_W      = (const float*)d_in[29];
    const float* f2a_b      = (const float*)d_in[30];
    const float* fo_W1      = (const float*)d_in[31];
    const float* fo_b1      = (const float*)d_in[32];
    const float* fo_W2      = (const float*)d_in[33];
    const float* fo_b2      = (const float*)d_in[34];
    const float* ao_W1      = (const float*)d_in[35];
    const float* ao_b1      = (const float*)d_in[36];
    const float* ao_W2      = (const float*)d_in[37];
    const float* ao_b2      = (const float*)d_in[38];
    const float* out_W1     = (const float*)d_in[39];
    const float* out_b1     = (const float*)d_in[40];
    const float* out_W2     = (const float*)d_in[41];
    const float* out_b2     = (const float*)d_in[42];
    const int* edge_index   = (const int*)d_in[43];
    const int* fedge_index  = (const int*)d_in[44];
    const int* batch        = (const int*)d_in[45];
    const int* fbatch       = (const int*)d_in[46];
    const int* mem_atom     = (const int*)d_in[47];
    const int* mem_frag     = (const int*)d_in[48];

    const int* src  = edge_index;
    const int* dst  = edge_index + N_EDGE;
    const int* fsrc = fedge_index;
    const int* fdst = fedge_index + N_FEDGE;

    // ---- arena (~219 MB) with lifetime-based aliasing ----
    char* w = (char*)d_ws;
    auto alloc = [&](size_t bytes) -> char* {
        char* p = w; w += (bytes + 255) & ~(size_t)255; return p;
    };
    char*     big      = alloc((size_t)N_ATOM * 512 * 2);           // 134 MB
    ushort_t* a        = (ushort_t*)alloc((size_t)N_ATOM * H * 2);  // 67 MB
    ushort_t* f        = (ushort_t*)alloc((size_t)N_FRAG * H * 2);  // 17 MB
    float*    stats    = (float*)alloc(8192 * 4);                   // stats arena
    int*      cnt_atom = (int*)alloc((size_t)N_ATOM * 4);
    int*      cnt_frag = (int*)alloc((size_t)N_FRAG * 4);
    int*      cnt_ab   = (int*)alloc((size_t)BATCH * 4);
    int*      cnt_fb   = (int*)alloc((size_t)BATCH * 4);
    size_t need = (size_t)(w - (char*)d_ws);
    if (need > ws_size) {
        fill_const<<<64, 256, 0, stream>>>((float*)d_out, out_size,
                                           (float)((double)ws_size / 1024.0));
        return;
    }
    // stats arena layout (floats):
    float* csh_a  = stats + 0;      // 256  colsum of atom h
    float* cst1_a = stats + 256;    // 1024 GEMM1 atom col sum/ssq
    float* csy_a  = stats + 1280;   // 512  colsum of atom y (BN1 out)
    float* cst2_a = stats + 1792;   // 512  GEMM2 atom col sum/ssq
    float* csh_f  = stats + 2304;   // 256
    float* cst1_f = stats + 2560;   // 1024
    float* csy_f  = stats + 3584;   // 512
    float* cst2_f = stats + 4096;   // 512
    float* muB    = stats + 4608;   // 512  mu scratch (written fully each use)
    // aliases inside `big` (disjoint lifetimes):
    float*    A1       = (float*)big;
    ushort_t* Hb       = (ushort_t*)big;
    float*    F1       = (float*)big;
    ushort_t* Hbf      = (ushort_t*)big;
    float*    pooled_f = (float*)big;
    float*    pooled_a = (float*)(big + (size_t)8 * 1024 * 1024);
    float*    tmp      = (float*)(big + (size_t)16 * 1024 * 1024);

    // ---- segment counts ----
    hipMemsetAsync(cnt_atom, 0, (size_t)N_ATOM * 4, stream);
    hipMemsetAsync(cnt_frag, 0, (size_t)N_FRAG * 4, stream);
    hipMemsetAsync(cnt_ab,   0, (size_t)BATCH * 4, stream);
    hipMemsetAsync(cnt_fb,   0, (size_t)BATCH * 4, stream);
    count_idx<<<CDIV(N_MEM,256),256,0,stream>>>(mem_atom, N_MEM, cnt_atom);
    count_idx<<<CDIV(N_MEM,256),256,0,stream>>>(mem_frag, N_MEM, cnt_frag);
    count_idx<<<CDIV(N_ATOM,256),256,0,stream>>>(batch, N_ATOM, cnt_ab);
    count_idx<<<CDIV(N_FRAG,256),256,0,stream>>>(fbatch, N_FRAG, cnt_fb);

    // ---- encoders (fp32 in -> bf16 state) ----
    gemm_k<0,float,ushort_t><<<dim3(2, N_ATOM/128), 256, 0, stream>>>(
        x, atom_enc_W, atom_enc_b, a, nullptr, nullptr, nullptr, nullptr, N_ATOM, 64, H);
    gemm_k<0,float,ushort_t><<<dim3(2, N_FRAG/128), 256, 0, stream>>>(
        fragments, frag_enc_W, frag_enc_b, f, nullptr, nullptr, nullptr, nullptr, N_FRAG, 32, H);

    const float invNA = 1.f / N_ATOM, invNF = 1.f / N_FRAG;

    for (int l = 0; l < 4; ++l) {
        hipMemsetAsync(stats, 0, 4608 * 4, stream);   // zero all accumulators

        // ===== GINE on atoms =====
        hipMemsetAsync(A1, 0, (size_t)N_ATOM * H * 4, stream);
        gine_scatter<<<(int)((long)N_EDGE*64/256), 256, 0, stream>>>(
            a, edge_attr, bond_W + (long)l*16*H, bond_b + l*H, src, dst, A1, N_EDGE);
        combine_eps_bf<<<1024, 256, 0, stream>>>(a, A1, gine_eps + l,
                                                 (long)N_ATOM * H / 4, csh_a);
        mu_gemv<<<2, 256, 0, stream>>>(csh_a, gine_W1 + (long)l*H*512,
                                       gine_b1 + l*512, muB, H, 512, invNA);
        gemm_k<0,ushort_t,ushort_t><<<dim3(4, N_ATOM/128), 256, 0, stream>>>(
            a, gine_W1 + (long)l*H*512, gine_b1 + l*512, Hb,
            nullptr, nullptr, muB, cst1_a, N_ATOM, H, 512);
        bn_apply_v<1><<<2048, 256, 0, stream>>>(Hb, Hb, (long)N_ATOM*512/4, 127,
            cst1_a, 512, gine_bn_g + l*512, gine_bn_b + l*512, invNA, csy_a);
        mu_gemv<<<1, 256, 0, stream>>>(csy_a, gine_W2 + (long)l*512*H,
                                       gine_b2 + l*H, muB, 512, H, invNA);
        gemm_k<0,ushort_t,ushort_t><<<dim3(2, N_ATOM/128), 256, 0, stream>>>(
            Hb, gine_W2 + (long)l*512*H, gine_b2 + l*H, a,
            nullptr, nullptr, muB, cst2_a, N_ATOM, 512, H);
        bn_apply_v<1><<<2048, 256, 0, stream>>>(a, a, (long)N_ATOM*H/4, 63,
            cst2_a, H, atom_bn_g + l*H, atom_bn_b + l*H, invNA, nullptr);

        // ===== GIN on fragments =====
        hipMemsetAsync(F1, 0, (size_t)N_FRAG * H * 4, stream);
        scatter_add_rows<ushort_t><<<(int)((long)N_FEDGE*64/256), 256, 0, stream>>>(
            f, fsrc, fdst, F1, N_FEDGE);
        combine_eps_bf<<<512, 256, 0, stream>>>(f, F1, gin_eps + l,
                                                (long)N_FRAG * H / 4, csh_f);
        mu_gemv<<<2, 256, 0, stream>>>(csh_f, gin_W1 + (long)l*H*512,
                                       gin_b1 + l*512, muB, H, 512, invNF);
        gemm_k<0,ushort_t,ushort_t><<<dim3(4, N_FRAG/128), 256, 0, stream>>>(
            f, gin_W1 + (long)l*H*512, gin_b1 + l*512, Hbf,
            nullptr, nullptr, muB, cst1_f, N_FRAG, H, 512);
        bn_apply_v<1><<<1024, 256, 0, stream>>>(Hbf, Hbf, (long)N_FRAG*512/4, 127,
            cst1_f, 512, gin_bn_g + l*512, gin_bn_b + l*512, invNF, csy_f);
        mu_gemv<<<1, 256, 0, stream>>>(csy_f, gin_W2 + (long)l*512*H,
                                       gin_b2 + l*H, muB, 512, H, invNF);
        gemm_k<0,ushort_t,ushort_t><<<dim3(2, N_FRAG/128), 256, 0, stream>>>(
            Hbf, gin_W2 + (long)l*512*H, gin_b2 + l*H, f,
            nullptr, nullptr, muB, cst2_f, N_FRAG, 512, H);
        bn_apply_v<1><<<512, 256, 0, stream>>>(f, f, (long)N_FRAG*H/4, 63,
            cst2_f, H, frag_bn_g + l*H, frag_bn_b + l*H, invNF, nullptr);

        // ===== inter MP: atoms -> fragments =====
        hipMemsetAsync(F1, 0, (size_t)N_FRAG * H * 4, stream);
        gemm_k<1,ushort_t,float><<<dim3(2, N_MEM/128), 256, 0, stream>>>(
            a, a2f_W + (long)l*H*H, a2f_b + l*H, F1,
            mem_atom, mem_frag, nullptr, nullptr, N_MEM, H, H);
        apply_mean<0,ushort_t><<<(int)((long)N_FRAG*64/256), 256, 0, stream>>>(
            f, F1, cnt_frag, N_FRAG);

        // ===== fragments -> atoms =====
        hipMemsetAsync(A1, 0, (size_t)N_ATOM * H * 4, stream);
        gemm_k<1,ushort_t,float><<<dim3(2, N_MEM/128), 256, 0, stream>>>(
            f, f2a_W + (long)l*H*H, f2a_b + l*H, A1,
            mem_frag, mem_atom, nullptr, nullptr, N_MEM, H, H);
        apply_mean<0,ushort_t><<<(int)((long)N_ATOM*64/256), 256, 0, stream>>>(
            a, A1, cnt_atom, N_ATOM);
    }

    // ===== readout =====
    hipMemsetAsync(pooled_f, 0, (size_t)BATCH * H * 4, stream);
    scatter_add_rows<ushort_t><<<(int)((long)N_FRAG*64/256), 256, 0, stream>>>(
        f, nullptr, fbatch, pooled_f, N_FRAG);
    apply_mean<1,float><<<(int)((long)BATCH*64/256), 256, 0, stream>>>(
        pooled_f, pooled_f, cnt_fb, BATCH);
    gemm_k<1,float,float><<<dim3(2, BATCH/128), 256, 0, stream>>>(
        pooled_f, fo_W1, fo_b1, tmp, nullptr, nullptr, nullptr, nullptr, BATCH, H, H);
    gemm_k<1,float,float><<<dim3(2, BATCH/128), 256, 0, stream>>>(
        tmp, fo_W2, fo_b2, pooled_f, nullptr, nullptr, nullptr, nullptr, BATCH, H, H);

    hipMemsetAsync(pooled_a, 0, (size_t)BATCH * H * 4, stream);
    scatter_add_rows<ushort_t><<<(int)((long)N_ATOM*64/256), 256, 0, stream>>>(
        a, nullptr, batch, pooled_a, N_ATOM);
    apply_mean<1,float><<<(int)((long)BATCH*64/256), 256, 0, stream>>>(
        pooled_a, pooled_a, cnt_ab, BATCH);
    gemm_k<1,float,float><<<dim3(2, BATCH/128), 256, 0, stream>>>(
        pooled_a, ao_W1, ao_b1, tmp, nullptr, nullptr, nullptr, nullptr, BATCH, H, H);
    gemm_k<1,float,float><<<dim3(2, BATCH/128), 256, 0, stream>>>(
        tmp, ao_W2, ao_b2, pooled_a, nullptr, nullptr, nullptr, nullptr, BATCH, H, H);

    vadd<<<(int)CDIV((long)BATCH*H/4,256), 256, 0, stream>>>(
        pooled_a, pooled_f, (long)BATCH * H / 4);
    gemm_k<1,float,float><<<dim3(2, BATCH/128), 256, 0, stream>>>(
        pooled_a, out_W1, out_b1, tmp, nullptr, nullptr, nullptr, nullptr, BATCH, H, H);
    gemm_k<0,float,float><<<dim3(1, BATCH/128), 256, 0, stream>>>(
        tmp, out_W2, out_b2, (float*)d_out, nullptr, nullptr, nullptr, nullptr, BATCH, H, 1);
}

// Round 5
// 11644.118 us; speedup vs baseline: 2.2962x; 2.2962x over previous
//
#include <hip/hip_runtime.h>

#define CDIV(a,b) (((a)+(b)-1)/(b))

static const int N_ATOM = 131072, N_FRAG = 32768, N_EDGE = 262144,
                 N_FEDGE = 65536, N_MEM = 196608, BATCH = 4096, H = 256;

typedef unsigned short ushort_t;
typedef _Float16 half8_t __attribute__((ext_vector_type(8)));
typedef float    floatx4 __attribute__((ext_vector_type(4)));

__device__ __forceinline__ float h2f(ushort_t u) {
    _Float16 h; __builtin_memcpy(&h, &u, 2); return (float)h;
}
__device__ __forceinline__ ushort_t f2h(float f) {
    _Float16 h = (_Float16)f; ushort_t u; __builtin_memcpy(&u, &h, 2); return u;
}

// diagnostic: if workspace too small, d_out = ws_size/1024 (KB)
__global__ void fill_const(float* p, long n, float v) {
    long t = (long)blockIdx.x * blockDim.x + threadIdx.x;
    long stride = (long)gridDim.x * blockDim.x;
    for (; t < n; t += stride) p[t] = v;
}

// ---------------------------------------------------------------------------
// Weight prep: f32 W[K][M] -> frag-ready f16 hi/lo, layout [K/32][M][32]
// (inner 32 = k&31). 6 groups, 4 matrices each.
// ---------------------------------------------------------------------------
__global__ void prep_w(const float* __restrict__ s0, const float* __restrict__ s1,
                       const float* __restrict__ s2, const float* __restrict__ s3,
                       const float* __restrict__ s4, const float* __restrict__ s5,
                       ushort_t* __restrict__ hi, ushort_t* __restrict__ lo)
{
    long gid = (long)blockIdx.x * 256 + threadIdx.x;
    const float* src; int K, M; long base, loc;
    if      (gid < 524288)  { src=s0; K=256; M=512; base=0;       loc=gid; }
    else if (gid < 1048576) { src=s1; K=512; M=256; base=524288;  loc=gid-524288; }
    else if (gid < 1572864) { src=s2; K=256; M=512; base=1048576; loc=gid-1048576; }
    else if (gid < 2097152) { src=s3; K=512; M=256; base=1572864; loc=gid-1572864; }
    else if (gid < 2359296) { src=s4; K=256; M=256; base=2097152; loc=gid-2097152; }
    else if (gid < 2621440) { src=s5; K=256; M=256; base=2359296; loc=gid-2359296; }
    else return;
    long msz = (long)K * M;
    int  mat = (int)(loc / msz); long rem = loc - (long)mat * msz;
    int  k = (int)(rem / M);     int  n = (int)(rem - (long)k * M);
    float v = src[loc];
    ushort_t hu = f2h(v);
    ushort_t lu = f2h(v - h2f(hu));
    long dst = base + (long)mat * msz + ((long)(k >> 5) * M + n) * 32 + (k & 31);
    hi[dst] = hu;
    if (lo) lo[dst] = lu;
}

// ---------------------------------------------------------------------------
// MFMA f16 GEMM: C[N,M](f16) = [relu/mu-shift]( op(A)[N,K](f16) @ W + bias )
// W given as frag-ready hi(+lo) f16. 128x128 tile, 4 waves (2x2), each wave
// 64x64 via 4x4 16x16x32 frags. aidx: A row gather. cstat: fused col sum/ssq.
// Requires N%128==0, K%32==0, M%128==0.
// ---------------------------------------------------------------------------
template<int RELU>
__global__ __launch_bounds__(256)
void mfma_gemm(const ushort_t* __restrict__ A, const ushort_t* __restrict__ Wh,
               const ushort_t* __restrict__ Wl, const float* __restrict__ bias,
               ushort_t* __restrict__ C, const int* __restrict__ aidx,
               const float* __restrict__ mu, float* __restrict__ cstat,
               int N, int K, int M)
{
    __shared__ uint4 Asm4[512];   // A tile 128x32 f16, chunk (m,g) at (m>>4)*64+g*16+(m&15)
    __shared__ uint4 Bh4[512];    // W hi tile: linear copy of Wp slice (n-local*4+g)
    __shared__ uint4 Bl4[512];
    const int tid = threadIdx.x;
    const int brow = blockIdx.y * 128, bcol = blockIdx.x * 128;
    const int wid = tid >> 6, lane = tid & 63;
    const int wm = wid >> 1, wn = wid & 1;
    const int lg = lane >> 4, lr = lane & 15;

    // staging assignment (fixed rows across K loop)
    const int m0 = tid >> 2, g0 = tid & 3;            // chunk tid -> (m0,g0); +256 -> m0+64
    long r0 = aidx ? (long)aidx[brow + m0]      : (long)(brow + m0);
    long r1 = aidx ? (long)aidx[brow + m0 + 64] : (long)(brow + m0 + 64);
    const int ci0 = ((m0 >> 4) << 6) + (g0 << 4) + (m0 & 15);
    const int ci1 = (((m0 + 64) >> 4) << 6) + (g0 << 4) + (m0 & 15);

    floatx4 acc[4][4];
    #pragma unroll
    for (int i = 0; i < 4; ++i)
        #pragma unroll
        for (int j = 0; j < 4; ++j) acc[i][j] = (floatx4){0.f, 0.f, 0.f, 0.f};

    const int nkt = K >> 5;
    for (int kt = 0; kt < nkt; ++kt) {
        const int k0 = kt << 5;
        Asm4[ci0] = *(const uint4*)(A + r0 * K + k0 + g0 * 8);
        Asm4[ci1] = *(const uint4*)(A + r1 * K + k0 + g0 * 8);
        const uint4* ph = (const uint4*)(Wh + (((size_t)kt * M + bcol) << 5));
        Bh4[tid] = ph[tid]; Bh4[tid + 256] = ph[tid + 256];
        if (Wl) {
            const uint4* pl = (const uint4*)(Wl + (((size_t)kt * M + bcol) << 5));
            Bl4[tid] = pl[tid]; Bl4[tid + 256] = pl[tid + 256];
        }
        __syncthreads();

        half8_t af[4], bh[4], bl[4];
        #pragma unroll
        for (int i = 0; i < 4; ++i)
            af[i] = __builtin_bit_cast(half8_t, Asm4[((wm << 2) + i) * 64 + (lg << 4) + lr]);
        #pragma unroll
        for (int j = 0; j < 4; ++j) {
            int nb = wn * 64 + j * 16 + lr;
            bh[j] = __builtin_bit_cast(half8_t, Bh4[(nb << 2) + lg]);
            if (Wl) bl[j] = __builtin_bit_cast(half8_t, Bl4[(nb << 2) + lg]);
        }
        #pragma unroll
        for (int i = 0; i < 4; ++i)
            #pragma unroll
            for (int j = 0; j < 4; ++j) {
                acc[i][j] = __builtin_amdgcn_mfma_f32_16x16x32_f16(af[i], bh[j], acc[i][j], 0, 0, 0);
                if (Wl)
                    acc[i][j] = __builtin_amdgcn_mfma_f32_16x16x32_f16(af[i], bl[j], acc[i][j], 0, 0, 0);
            }
        __syncthreads();
    }

    // epilogue: D[row=brow+wm*64+i*16+lg*4+r][col=bcol+wn*64+j*16+lr]
    float csl[4], cql[4];
    #pragma unroll
    for (int j = 0; j < 4; ++j) { csl[j] = 0.f; cql[j] = 0.f; }
    #pragma unroll
    for (int j = 0; j < 4; ++j) {
        int col = bcol + wn * 64 + j * 16 + lr;
        float bia = bias[col];
        float muv = mu ? mu[col] : 0.f;
        #pragma unroll
        for (int i = 0; i < 4; ++i) {
            #pragma unroll
            for (int r = 0; r < 4; ++r) {
                int row = brow + wm * 64 + i * 16 + (lg << 2) + r;
                float v = acc[i][j][r] + bia - muv;
                if (RELU) v = fmaxf(v, 0.f);
                ushort_t uo = f2h(v);
                C[(long)row * M + col] = uo;
                if (cstat) {
                    float vq = h2f(uo);
                    csl[j] += vq; cql[j] = fmaf(vq, vq, cql[j]);
                }
            }
        }
    }
    if (cstat) {
        __syncthreads();
        float* cs = (float*)Asm4;   // 128 floats
        float* cq = (float*)Bh4;
        if (tid < 128) { cs[tid] = 0.f; cq[tid] = 0.f; }
        __syncthreads();
        #pragma unroll
        for (int j = 0; j < 4; ++j) {
            int cl = wn * 64 + j * 16 + lr;
            atomicAdd(&cs[cl], csl[j]);
            atomicAdd(&cq[cl], cql[j]);
        }
        __syncthreads();
        if (tid < 128) {
            atomicAdd(&cstat[bcol + tid], cs[tid]);
            atomicAdd(&cstat[M + bcol + tid], cq[tid]);
        }
    }
}

// ---------------------------------------------------------------------------
// Old fp32-FMA GEMM (float A) for encoders/readout/final. TC float or f16.
// ---------------------------------------------------------------------------
template<int RELU, typename TC>
__global__ __launch_bounds__(256)
void gemm_k(const float* __restrict__ A, const float* __restrict__ W,
            const float* __restrict__ bias, TC* __restrict__ C,
            int N, int K, int M)
{
    const int BK = 16, LDA = 132;
    __shared__ float As[BK * LDA];
    __shared__ float Bs[BK * LDA];
    const int brow = blockIdx.y * 128;
    const int bcol = blockIdx.x * 128;
    const int tid  = threadIdx.x;
    const int tr = tid >> 4, tc = tid & 15;

    float acc[8][8];
    #pragma unroll
    for (int i = 0; i < 8; ++i)
        #pragma unroll
        for (int j = 0; j < 8; ++j) acc[i][j] = 0.f;

    for (int k0 = 0; k0 < K; k0 += BK) {
        #pragma unroll
        for (int u = 0; u < 8; ++u) {
            int idx = tid + u * 256;
            int m = idx >> 4, kk = idx & 15;
            As[kk * LDA + m] = A[(long)(brow + m) * K + k0 + kk];
        }
        #pragma unroll
        for (int u = 0; u < 8; ++u) {
            int idx = tid + u * 256;
            int kk = idx >> 7, n = idx & 127;
            int col = bcol + n;
            Bs[kk * LDA + n] = (col < M) ? W[(long)(k0 + kk) * M + col] : 0.f;
        }
        __syncthreads();
        #pragma unroll
        for (int kk = 0; kk < BK; ++kk) {
            float av[8], bv[8];
            float4 a0 = *(const float4*)&As[kk * LDA + tr * 8];
            float4 a1 = *(const float4*)&As[kk * LDA + tr * 8 + 4];
            float4 b0 = *(const float4*)&Bs[kk * LDA + tc * 8];
            float4 b1 = *(const float4*)&Bs[kk * LDA + tc * 8 + 4];
            av[0]=a0.x; av[1]=a0.y; av[2]=a0.z; av[3]=a0.w;
            av[4]=a1.x; av[5]=a1.y; av[6]=a1.z; av[7]=a1.w;
            bv[0]=b0.x; bv[1]=b0.y; bv[2]=b0.z; bv[3]=b0.w;
            bv[4]=b1.x; bv[5]=b1.y; bv[6]=b1.z; bv[7]=b1.w;
            #pragma unroll
            for (int i = 0; i < 8; ++i)
                #pragma unroll
                for (int j = 0; j < 8; ++j)
                    acc[i][j] = fmaf(av[i], bv[j], acc[i][j]);
        }
        __syncthreads();
    }
    #pragma unroll
    for (int i = 0; i < 8; ++i) {
        int row = brow + tr * 8 + i;
        #pragma unroll
        for (int j = 0; j < 8; ++j) {
            int col = bcol + tc * 8 + j;
            if (col < M) {
                float v = acc[i][j] + bias[col];
                if (RELU) v = fmaxf(v, 0.f);
                if constexpr (sizeof(TC) == 2) ((ushort_t*)C)[(long)row * M + col] = f2h(v);
                else                           ((float*)C)[(long)row * M + col] = v;
            }
        }
    }
}

// mu[c] = (colsum_x dot W[:,c]) * invN + bias[c]
__global__ void mu_gemv(const float* __restrict__ colsum_x, const float* __restrict__ W,
                        const float* __restrict__ bias, float* __restrict__ mu,
                        int K, int M, float invN)
{
    int c = blockIdx.x * blockDim.x + threadIdx.x;
    if (c >= M) return;
    float acc = 0.f;
    for (int k = 0; k < K; ++k) acc = fmaf(colsum_x[k], W[(long)k * M + c], acc);
    mu[c] = acc * invN + bias[c];
}

// ---------------------------------------------------------------------------
// GINE: agg[dst[i]] += relu(a[src[i]] + edge_attr[i] @ Wb + bb), a f16.
// ---------------------------------------------------------------------------
__global__ __launch_bounds__(256)
void gine_scatter(const ushort_t* __restrict__ a, const float* __restrict__ eattr,
                  const float* __restrict__ Wb, const float* __restrict__ bb,
                  const int* __restrict__ src, const int* __restrict__ dst,
                  float* __restrict__ agg, long nE)
{
    __shared__ float Ws[16][256];
    __shared__ float bs[256];
    for (int i = threadIdx.x; i < 16 * 256; i += 256) Ws[i >> 8][i & 255] = Wb[i];
    bs[threadIdx.x] = bb[threadIdx.x];
    __syncthreads();

    long t = (long)blockIdx.x * 256 + threadIdx.x;
    if (t >= nE * 64) return;
    long i = t >> 6; int lane = (int)(t & 63);
    int s = src[i], d = dst[i];

    float ev[16];
    const float4* ea = (const float4*)(eattr + i * 16);
    float4 e0 = ea[0], e1 = ea[1], e2 = ea[2], e3 = ea[3];
    ev[0]=e0.x; ev[1]=e0.y; ev[2]=e0.z; ev[3]=e0.w;
    ev[4]=e1.x; ev[5]=e1.y; ev[6]=e1.z; ev[7]=e1.w;
    ev[8]=e2.x; ev[9]=e2.y; ev[10]=e2.z; ev[11]=e2.w;
    ev[12]=e3.x; ev[13]=e3.y; ev[14]=e3.z; ev[15]=e3.w;

    #pragma unroll
    for (int j = 0; j < 4; ++j) {
        int c = lane + j * 64;
        float r = bs[c];
        #pragma unroll
        for (int k = 0; k < 16; ++k) r = fmaf(ev[k], Ws[k][c], r);
        r += h2f(a[(long)s * 256 + c]);
        r = fmaxf(r, 0.f);
        atomicAdd(&agg[(long)d * 256 + c], r);
    }
}

// F1[sidx[i]] += T[gidx[i]]  (f16 rows of 256, f32 atomic out)  [frag GIN agg]
__global__ __launch_bounds__(256)
void scatter_add_rows(const ushort_t* __restrict__ T, const int* __restrict__ gidx,
                      const int* __restrict__ sidx, float* __restrict__ out, long nrows)
{
    long t = (long)blockIdx.x * 256 + threadIdx.x;
    if (t >= nrows * 64) return;
    long i = t >> 6; int c4 = (int)(t & 63);
    long srow = (long)gidx[i];
    ushort4 u = *(const ushort4*)(T + srow * 256 + c4 * 4);
    float* o = out + (long)sidx[i] * 256 + c4 * 4;
    atomicAdd(o + 0, h2f(u.x)); atomicAdd(o + 1, h2f(u.y));
    atomicAdd(o + 2, h2f(u.z)); atomicAdd(o + 3, h2f(u.w));
}

// a(f16) <- (1+eps)*a + agg(f32); fused col-sum of result (256 cols).
__global__ __launch_bounds__(256)
void combine_eps_h(ushort_t* __restrict__ a, const float* __restrict__ agg,
                   const float* __restrict__ eps, long n4, float* __restrict__ colsum)
{
    __shared__ float ls[1024];
    float s = 1.f + eps[0];
    int tid = threadIdx.x;
    long stride = (long)gridDim.x * 256;
    float loc[4] = {0.f, 0.f, 0.f, 0.f};
    for (long t = (long)blockIdx.x * 256 + tid; t < n4; t += stride) {
        ushort4 av = ((const ushort4*)a)[t];
        float4 gv = ((const float4*)agg)[t];
        ushort4 r;
        r.x = f2h(fmaf(s, h2f(av.x), gv.x));
        r.y = f2h(fmaf(s, h2f(av.y), gv.y));
        r.z = f2h(fmaf(s, h2f(av.z), gv.z));
        r.w = f2h(fmaf(s, h2f(av.w), gv.w));
        ((ushort4*)a)[t] = r;
        loc[0] += h2f(r.x); loc[1] += h2f(r.y);
        loc[2] += h2f(r.z); loc[3] += h2f(r.w);
    }
    #pragma unroll
    for (int j = 0; j < 4; ++j) ls[tid * 4 + j] = loc[j];
    __syncthreads();
    if (tid < 64) {
        #pragma unroll
        for (int j = 0; j < 4; ++j) {
            float v = ls[tid*4+j] + ls[(tid+64)*4+j] + ls[(tid+128)*4+j] + ls[(tid+192)*4+j];
            atomicAdd(&colsum[tid * 4 + j], v);
        }
    }
}

// y = relu((x)*sc + sb) with BN stats from cstat; optional fused col-sum of y.
template<int RELU>
__global__ __launch_bounds__(256)
void bn_apply_v(const ushort_t* __restrict__ X, ushort_t* __restrict__ Y, long nq, int MqMask,
                const float* __restrict__ cstat, int M,
                const float* __restrict__ g, const float* __restrict__ b, float invN,
                float* __restrict__ colsum_out)
{
    int tid = threadIdx.x;
    long t0 = (long)blockIdx.x * 256 + tid;
    int cq = (int)(t0 & MqMask);
    float sa[4], sb[4], loc[4] = {0.f, 0.f, 0.f, 0.f};
    #pragma unroll
    for (int j = 0; j < 4; ++j) {
        int c = cq * 4 + j;
        float m = cstat[c] * invN;
        float var = cstat[M + c] * invN - m * m;
        float sc = rsqrtf(var + 1e-5f) * g[c];
        sa[j] = sc; sb[j] = b[c] - m * sc;
    }
    long stride = (long)gridDim.x * 256;
    for (long t = t0; t < nq; t += stride) {
        ushort4 xv = ((const ushort4*)X)[t];
        float y0 = h2f(xv.x) * sa[0] + sb[0];
        float y1 = h2f(xv.y) * sa[1] + sb[1];
        float y2 = h2f(xv.z) * sa[2] + sb[2];
        float y3 = h2f(xv.w) * sa[3] + sb[3];
        if (RELU) { y0=fmaxf(y0,0.f); y1=fmaxf(y1,0.f); y2=fmaxf(y2,0.f); y3=fmaxf(y3,0.f); }
        ushort4 r; r.x=f2h(y0); r.y=f2h(y1); r.z=f2h(y2); r.w=f2h(y3);
        ((ushort4*)Y)[t] = r;
        loc[0]+=h2f(r.x); loc[1]+=h2f(r.y); loc[2]+=h2f(r.z); loc[3]+=h2f(r.w);
    }
    if (colsum_out) {
        #pragma unroll
        for (int j = 0; j < 4; ++j) atomicAdd(&colsum_out[cq * 4 + j], loc[j]);
    }
}

__global__ void count_idx(const int* __restrict__ idx, int n, int* __restrict__ cnt)
{
    int i = blockIdx.x * blockDim.x + threadIdx.x;
    if (i < n) atomicAdd(&cnt[idx[i]], 1);
}

// single-block exclusive scan; off[n]=total; cursor may alias cnt.
__global__ void scan_excl(const int* __restrict__ cnt, int n,
                          int* __restrict__ off, int* __restrict__ cursor)
{
    __shared__ int part[1024];
    int t = threadIdx.x;
    int chunk = (n + 1023) / 1024;
    int s0 = t * chunk, s1 = s0 + chunk; if (s1 > n) s1 = n; if (s0 > n) s0 = n;
    int sum = 0;
    for (int i = s0; i < s1; ++i) sum += cnt[i];
    part[t] = sum;
    __syncthreads();
    if (t == 0) {
        int run = 0;
        for (int i = 0; i < 1024; ++i) { int v = part[i]; part[i] = run; run += v; }
        off[n] = run;
    }
    __syncthreads();
    int run = part[t];
    for (int i = s0; i < s1; ++i) {
        int c = cnt[i];            // read before cursor possibly overwrites
        off[i] = run; cursor[i] = run; run += c;
    }
}

__global__ void csr_fill(const int* __restrict__ idx, int n,
                         int* __restrict__ cursor, int* __restrict__ elist)
{
    int i = blockIdx.x * blockDim.x + threadIdx.x;
    if (i < n) { int p = atomicAdd(&cursor[idx[i]], 1); elist[p] = i; }
}

// out[row](f16) += mean over CSR list of T rows (f16, 256 ch). 128 thr/blk.
__global__ __launch_bounds__(128)
void csr_mean_add(const ushort_t* __restrict__ T, const int* __restrict__ elist,
                  const int* __restrict__ off, ushort_t* __restrict__ out)
{
    int row = blockIdx.x, t = threadIdx.x;
    int s = off[row], e = off[row + 1];
    if (s == e) return;
    float ax = 0.f, ay = 0.f;
    for (int i = s; i < e; ++i) {
        long r = elist[i];
        ushort2 v = *(const ushort2*)(T + r * 256 + t * 2);
        ax += h2f(v.x); ay += h2f(v.y);
    }
    float inv = 1.f / (float)(e - s);
    ushort2 o = *(ushort2*)(out + (long)row * 256 + t * 2);
    o.x = f2h(h2f(o.x) + ax * inv);
    o.y = f2h(h2f(o.y) + ay * inv);
    *(ushort2*)(out + (long)row * 256 + t * 2) = o;
}

// pooled[b] = mean of X rows with sorted bidx==b (binary search). 256 thr/blk.
__global__ __launch_bounds__(256)
void seg_pool(const ushort_t* __restrict__ X, const int* __restrict__ bidx,
              int nrows, float* __restrict__ pooled)
{
    int b = blockIdx.x, t = threadIdx.x;
    int lo = 0, hi = nrows;
    while (lo < hi) { int mid = (lo + hi) >> 1; if (bidx[mid] < b) lo = mid + 1; else hi = mid; }
    int s = lo; hi = nrows;
    while (lo < hi) { int mid = (lo + hi) >> 1; if (bidx[mid] < b + 1) lo = mid + 1; else hi = mid; }
    int e = lo;
    float acc = 0.f;
    for (int r = s; r < e; ++r) acc += h2f(X[(long)r * 256 + t]);
    pooled[(long)b * 256 + t] = acc / fmaxf((float)(e - s), 1.f);
}

__global__ void vadd(float* __restrict__ out, const float* __restrict__ in, long n4)
{
    long t = (long)blockIdx.x * blockDim.x + threadIdx.x;
    if (t >= n4) return;
    float4 a = ((float4*)out)[t];
    float4 b = ((const float4*)in)[t];
    a.x += b.x; a.y += b.y; a.z += b.z; a.w += b.w;
    ((float4*)out)[t] = a;
}

// ---------------------------------------------------------------------------
extern "C" void kernel_launch(void* const* d_in, const int* in_sizes, int n_in,
                              void* d_out, int out_size, void* d_ws, size_t ws_size,
                              hipStream_t stream)
{
    (void)in_sizes; (void)n_in;
    const float* x          = (const float*)d_in[0];
    const float* fragments  = (const float*)d_in[1];
    const float* edge_attr  = (const float*)d_in[2];
    const float* atom_enc_W = (const float*)d_in[3];
    const float* atom_enc_b = (const float*)d_in[4];
    const float* frag_enc_W = (const float*)d_in[5];
    const float* frag_enc_b = (const float*)d_in[6];
    const float* bond_W     = (const float*)d_in[7];
    const float* bond_b     = (const float*)d_in[8];
    const float* gine_eps   = (const float*)d_in[9];
    const float* gine_W1    = (const float*)d_in[10];
    const float* gine_b1    = (const float*)d_in[11];
    const float* gine_bn_g  = (const float*)d_in[12];
    const float* gine_bn_b  = (const float*)d_in[13];
    const float* gine_W2    = (const float*)d_in[14];
    const float* gine_b2    = (const float*)d_in[15];
    const float* atom_bn_g  = (const float*)d_in[16];
    const float* atom_bn_b  = (const float*)d_in[17];
    const float* gin_eps    = (const float*)d_in[18];
    const float* gin_W1     = (const float*)d_in[19];
    const float* gin_b1     = (const float*)d_in[20];
    const float* gin_bn_g   = (const float*)d_in[21];
    const float* gin_bn_b   = (const float*)d_in[22];
    const float* gin_W2     = (const float*)d_in[23];
    const float* gin_b2     = (const float*)d_in[24];
    const float* frag_bn_g  = (const float*)d_in[25];
    const float* frag_bn_b  = (const float*)d_in[26];
    const float* a2f_W      = (const float*)d_in[27];
    const float* a2f_b      = (const float*)d_in[28];
    const float* f2a_W      = (const float*)d_in[29];
    const float* f2a_b      = (const float*)d_in[30];
    const float* fo_W1      = (const float*)d_in[31];
    const float* fo_b1      = (const float*)d_in[32];
    const float* fo_W2      = (const float*)d_in[33];
    const float* fo_b2      = (const float*)d_in[34];
    const float* ao_W1      = (const float*)d_in[35];
    const float* ao_b1      = (const float*)d_in[36];
    const float* ao_W2      = (const float*)d_in[37];
    const float* ao_b2      = (const float*)d_in[38];
    const float* out_W1     = (const float*)d_in[39];
    const float* out_b1     = (const float*)d_in[40];
    const float* out_W2     = (const float*)d_in[41];
    const float* out_b2     = (const float*)d_in[42];
    const int* edge_index   = (const int*)d_in[43];
    const int* fedge_index  = (const int*)d_in[44];
    const int* batch        = (const int*)d_in[45];
    const int* fbatch       = (const int*)d_in[46];
    const int* mem_atom     = (const int*)d_in[47];
    const int* mem_frag     = (const int*)d_in[48];

    const int* src  = edge_index;
    const int* dst  = edge_index + N_EDGE;
    const int* fsrc = fedge_index;
    const int* fdst = fedge_index + N_FEDGE;

    // ---- arena ----
    size_t off = 0;
    auto take = [&](size_t b) -> size_t { size_t p = off; off = (off + b + 255) & ~(size_t)255; return p; };
    size_t o_big   = take((size_t)N_ATOM * 512 * 2);     // 134 MB multi-purpose
    size_t o_a     = take((size_t)N_ATOM * H * 2);       // 67 MB f16 atom state
    size_t o_f     = take((size_t)N_FRAG * H * 2);       // 17 MB f16 frag state
    size_t o_elf   = take((size_t)N_MEM * 4);            // elist frag
    size_t o_ela   = take((size_t)N_MEM * 4);            // elist atom
    size_t o_offf  = take((size_t)(N_FRAG + 1) * 4);
    size_t o_offa  = take((size_t)(N_ATOM + 1) * 4);
    size_t o_cntf  = take((size_t)N_FRAG * 4);           // also cursor
    size_t o_cnta  = take((size_t)N_ATOM * 4);
    size_t o_stats = take(8192 * 4);
    size_t o_hi    = take((size_t)2621440 * 2);          // Wp hi
    size_t need_nolo = off;
    size_t o_lo    = take((size_t)2621440 * 2);          // Wp lo
    size_t need_full = off;

    bool use_lo = (need_full <= ws_size);
    if (!use_lo && need_nolo > ws_size) {
        fill_const<<<64, 256, 0, stream>>>((float*)d_out, out_size,
                                           (float)((double)ws_size / 1024.0));
        return;
    }
    char* base = (char*)d_ws;
    char*     big      = base + o_big;
    ushort_t* a        = (ushort_t*)(base + o_a);
    ushort_t* f        = (ushort_t*)(base + o_f);
    int*      elist_f  = (int*)(base + o_elf);
    int*      elist_a  = (int*)(base + o_ela);
    int*      off_f    = (int*)(base + o_offf);
    int*      off_a    = (int*)(base + o_offa);
    int*      cnt_f    = (int*)(base + o_cntf);
    int*      cnt_a    = (int*)(base + o_cnta);
    float*    stats    = (float*)(base + o_stats);
    ushort_t* Wp_hi    = (ushort_t*)(base + o_hi);
    ushort_t* Wp_lo    = use_lo ? (ushort_t*)(base + o_lo) : nullptr;

    // stats arena layout
    float* csh_a  = stats + 0;      // 256
    float* cst1_a = stats + 256;    // 1024
    float* csy_a  = stats + 1280;   // 512
    float* cst2_a = stats + 1792;   // 512
    float* csh_f  = stats + 2304;   // 256
    float* cst1_f = stats + 2560;   // 1024
    float* csy_f  = stats + 3584;   // 512
    float* cst2_f = stats + 4096;   // 512
    float* muB    = stats + 4608;   // 512
    // aliases inside big (disjoint lifetimes)
    float*    A1       = (float*)big;                       // atom GINE agg (134 MB)
    ushort_t* Hb       = (ushort_t*)big;                    // atom 512-mid (134 MB)
    float*    F1       = (float*)big;                       // frag agg (34 MB)
    ushort_t* Hbf      = (ushort_t*)big;                    // frag 512-mid
    ushort_t* T        = (ushort_t*)big;                    // interMP T (100 MB)
    float*    pooled_f = (float*)big;
    float*    pooled_a = (float*)(big + (size_t)8 * 1024 * 1024);
    float*    tmp      = (float*)(big + (size_t)16 * 1024 * 1024);

    // Wp per-group offsets (ushort elems)
    const long WG0 = 0, WG1 = 524288, WG2 = 1048576, WG3 = 1572864,
               WG4 = 2097152, WG5 = 2359296;

    // ---- weight prep + CSR build ----
    prep_w<<<CDIV(2621440L, 256), 256, 0, stream>>>(gine_W1, gine_W2, gin_W1, gin_W2,
                                                    a2f_W, f2a_W, Wp_hi, Wp_lo);
    hipMemsetAsync(cnt_f, 0, (size_t)N_FRAG * 4, stream);
    hipMemsetAsync(cnt_a, 0, (size_t)N_ATOM * 4, stream);
    count_idx<<<CDIV(N_MEM,256),256,0,stream>>>(mem_frag, N_MEM, cnt_f);
    count_idx<<<CDIV(N_MEM,256),256,0,stream>>>(mem_atom, N_MEM, cnt_a);
    scan_excl<<<1, 1024, 0, stream>>>(cnt_f, N_FRAG, off_f, cnt_f);
    scan_excl<<<1, 1024, 0, stream>>>(cnt_a, N_ATOM, off_a, cnt_a);
    csr_fill<<<CDIV(N_MEM,256),256,0,stream>>>(mem_frag, N_MEM, cnt_f, elist_f);
    csr_fill<<<CDIV(N_MEM,256),256,0,stream>>>(mem_atom, N_MEM, cnt_a, elist_a);

    // ---- encoders (fp32 in -> f16 state) ----
    gemm_k<0,ushort_t><<<dim3(2, N_ATOM/128), 256, 0, stream>>>(
        x, atom_enc_W, atom_enc_b, a, N_ATOM, 64, H);
    gemm_k<0,ushort_t><<<dim3(2, N_FRAG/128), 256, 0, stream>>>(
        fragments, frag_enc_W, frag_enc_b, f, N_FRAG, 32, H);

    const float invNA = 1.f / N_ATOM, invNF = 1.f / N_FRAG;

    for (int l = 0; l < 4; ++l) {
        hipMemsetAsync(stats, 0, 4608 * 4, stream);

        // ===== GINE on atoms =====
        hipMemsetAsync(A1, 0, (size_t)N_ATOM * H * 4, stream);
        gine_scatter<<<(int)((long)N_EDGE*64/256), 256, 0, stream>>>(
            a, edge_attr, bond_W + (long)l*16*H, bond_b + l*H, src, dst, A1, N_EDGE);
        combine_eps_h<<<1024, 256, 0, stream>>>(a, A1, gine_eps + l,
                                                (long)N_ATOM * H / 4, csh_a);
        mu_gemv<<<2, 256, 0, stream>>>(csh_a, gine_W1 + (long)l*H*512,
                                       gine_b1 + l*512, muB, H, 512, invNA);
        mfma_gemm<0><<<dim3(4, N_ATOM/128), 256, 0, stream>>>(
            a, Wp_hi + WG0 + (long)l*131072, Wp_lo ? Wp_lo + WG0 + (long)l*131072 : nullptr,
            gine_b1 + l*512, Hb, nullptr, muB, cst1_a, N_ATOM, 256, 512);
        bn_apply_v<1><<<2048, 256, 0, stream>>>(Hb, Hb, (long)N_ATOM*512/4, 127,
            cst1_a, 512, gine_bn_g + l*512, gine_bn_b + l*512, invNA, csy_a);
        mu_gemv<<<1, 256, 0, stream>>>(csy_a, gine_W2 + (long)l*512*H,
                                       gine_b2 + l*H, muB, 512, H, invNA);
        mfma_gemm<0><<<dim3(2, N_ATOM/128), 256, 0, stream>>>(
            Hb, Wp_hi + WG1 + (long)l*131072, Wp_lo ? Wp_lo + WG1 + (long)l*131072 : nullptr,
            gine_b2 + l*H, a, nullptr, muB, cst2_a, N_ATOM, 512, 256);
        bn_apply_v<1><<<2048, 256, 0, stream>>>(a, a, (long)N_ATOM*H/4, 63,
            cst2_a, H, atom_bn_g + l*H, atom_bn_b + l*H, invNA, nullptr);

        // ===== GIN on fragments =====
        hipMemsetAsync(F1, 0, (size_t)N_FRAG * H * 4, stream);
        scatter_add_rows<<<(int)((long)N_FEDGE*64/256), 256, 0, stream>>>(
            f, fsrc, fdst, F1, N_FEDGE);
        combine_eps_h<<<512, 256, 0, stream>>>(f, F1, gin_eps + l,
                                               (long)N_FRAG * H / 4, csh_f);
        mu_gemv<<<2, 256, 0, stream>>>(csh_f, gin_W1 + (long)l*H*512,
                                       gin_b1 + l*512, muB, H, 512, invNF);
        mfma_gemm<0><<<dim3(4, N_FRAG/128), 256, 0, stream>>>(
            f, Wp_hi + WG2 + (long)l*131072, Wp_lo ? Wp_lo + WG2 + (long)l*131072 : nullptr,
            gin_b1 + l*512, Hbf, nullptr, muB, cst1_f, N_FRAG, 256, 512);
        bn_apply_v<1><<<1024, 256, 0, stream>>>(Hbf, Hbf, (long)N_FRAG*512/4, 127,
            cst1_f, 512, gin_bn_g + l*512, gin_bn_b + l*512, invNF, csy_f);
        mu_gemv<<<1, 256, 0, stream>>>(csy_f, gin_W2 + (long)l*512*H,
                                       gin_b2 + l*H, muB, 512, H, invNF);
        mfma_gemm<0><<<dim3(2, N_FRAG/128), 256, 0, stream>>>(
            Hbf, Wp_hi + WG3 + (long)l*131072, Wp_lo ? Wp_lo + WG3 + (long)l*131072 : nullptr,
            gin_b2 + l*H, f, nullptr, muB, cst2_f, N_FRAG, 512, 256);
        bn_apply_v<1><<<512, 256, 0, stream>>>(f, f, (long)N_FRAG*H/4, 63,
            cst2_f, H, frag_bn_g + l*H, frag_bn_b + l*H, invNF, nullptr);

        // ===== inter MP: atoms -> fragments (T = relu(a[mem_atom]@W+b)) =====
        mfma_gemm<1><<<dim3(2, N_MEM/128), 256, 0, stream>>>(
            a, Wp_hi + WG4 + (long)l*65536, Wp_lo ? Wp_lo + WG4 + (long)l*65536 : nullptr,
            a2f_b + l*H, T, mem_atom, nullptr, nullptr, N_MEM, 256, 256);
        csr_mean_add<<<N_FRAG, 128, 0, stream>>>(T, elist_f, off_f, f);

        // ===== fragments -> atoms =====
        mfma_gemm<1><<<dim3(2, N_MEM/128), 256, 0, stream>>>(
            f, Wp_hi + WG5 + (long)l*65536, Wp_lo ? Wp_lo + WG5 + (long)l*65536 : nullptr,
            f2a_b + l*H, T, mem_frag, nullptr, nullptr, N_MEM, 256, 256);
        csr_mean_add<<<N_ATOM, 128, 0, stream>>>(T, elist_a, off_a, a);
    }

    // ===== readout (big free now) =====
    seg_pool<<<BATCH, 256, 0, stream>>>(f, fbatch, N_FRAG, pooled_f);
    gemm_k<1,float><<<dim3(2, BATCH/128), 256, 0, stream>>>(
        pooled_f, fo_W1, fo_b1, tmp, BATCH, H, H);
    gemm_k<1,float><<<dim3(2, BATCH/128), 256, 0, stream>>>(
        tmp, fo_W2, fo_b2, pooled_f, BATCH, H, H);

    seg_pool<<<BATCH, 256, 0, stream>>>(a, batch, N_ATOM, pooled_a);
    gemm_k<1,float><<<dim3(2, BATCH/128), 256, 0, stream>>>(
        pooled_a, ao_W1, ao_b1, tmp, BATCH, H, H);
    gemm_k<1,float><<<dim3(2, BATCH/128), 256, 0, stream>>>(
        tmp, ao_W2, ao_b2, pooled_a, BATCH, H, H);

    vadd<<<(int)CDIV((long)BATCH*H/4,256), 256, 0, stream>>>(
        pooled_a, pooled_f, (long)BATCH * H / 4);
    gemm_k<1,float><<<dim3(2, BATCH/128), 256, 0, stream>>>(
        pooled_a, out_W1, out_b1, tmp, BATCH, H, H);
    gemm_k<0,float><<<dim3(1, BATCH/128), 256, 0, stream>>>(
        tmp, out_W2, out_b2, (float*)d_out, BATCH, H, 1);
}

// Round 6
// 4885.051 us; speedup vs baseline: 5.4732x; 2.3836x over previous
//
#include <hip/hip_runtime.h>

#define CDIV(a,b) (((a)+(b)-1)/(b))

static const int N_ATOM = 131072, N_FRAG = 32768, N_EDGE = 262144,
                 N_FEDGE = 65536, N_MEM = 196608, BATCH = 4096, H = 256;
static const int NREP = 16;   // stat atomic replicas

typedef unsigned short ushort_t;
typedef _Float16 half8_t __attribute__((ext_vector_type(8)));
typedef float    floatx4 __attribute__((ext_vector_type(4)));

struct PanelsIn  { const ushort_t* p[4]; };
struct PanelsOut { ushort_t* p[4]; };

__device__ __forceinline__ float h2f(ushort_t u) {
    _Float16 h; __builtin_memcpy(&h, &u, 2); return (float)h;
}
__device__ __forceinline__ ushort_t f2h(float f) {
    _Float16 h = (_Float16)f; ushort_t u; __builtin_memcpy(&u, &h, 2); return u;
}

__global__ void fill_const(float* p, long n, float v) {
    long t = (long)blockIdx.x * blockDim.x + threadIdx.x;
    long stride = (long)gridDim.x * blockDim.x;
    for (; t < n; t += stride) p[t] = v;
}

// ---------------------------------------------------------------------------
// Weight prep: f32 W[K][M] -> frag-ready f16 hi/lo, layout [K/32][M][32].
// ---------------------------------------------------------------------------
__global__ void prep_w(const float* __restrict__ s0, const float* __restrict__ s1,
                       const float* __restrict__ s2, const float* __restrict__ s3,
                       const float* __restrict__ s4, const float* __restrict__ s5,
                       ushort_t* __restrict__ hi, ushort_t* __restrict__ lo)
{
    long gid = (long)blockIdx.x * 256 + threadIdx.x;
    const float* src; int K, M; long base, loc;
    if      (gid < 524288)  { src=s0; K=256; M=512; base=0;       loc=gid; }
    else if (gid < 1048576) { src=s1; K=512; M=256; base=524288;  loc=gid-524288; }
    else if (gid < 1572864) { src=s2; K=256; M=512; base=1048576; loc=gid-1048576; }
    else if (gid < 2097152) { src=s3; K=512; M=256; base=1572864; loc=gid-1572864; }
    else if (gid < 2359296) { src=s4; K=256; M=256; base=2097152; loc=gid-2097152; }
    else if (gid < 2621440) { src=s5; K=256; M=256; base=2359296; loc=gid-2359296; }
    else return;
    long msz = (long)K * M;
    int  mat = (int)(loc / msz); long rem = loc - (long)mat * msz;
    int  k = (int)(rem / M);     int  n = (int)(rem - (long)k * M);
    float v = src[loc];
    ushort_t hu = f2h(v);
    ushort_t lu = f2h(v - h2f(hu));
    long dst = base + (long)mat * msz + ((long)(k >> 5) * M + n) * 32 + (k & 31);
    hi[dst] = hu;
    if (lo) lo[dst] = lu;
}

__device__ __forceinline__ uint4 aff_relu8(uint4 v, const float* __restrict__ Aff,
                                           int kb, int K)
{
    ushort_t u[8]; __builtin_memcpy(u, &v, 16);
    #pragma unroll
    for (int i = 0; i < 8; ++i) {
        float y = fmaxf(h2f(u[i]) * Aff[kb + i] + Aff[K + kb + i], 0.f);
        u[i] = f2h(y);
    }
    uint4 r; __builtin_memcpy(&r, u, 16);
    return r;
}

// ---------------------------------------------------------------------------
// MFMA f16 GEMM with panel I/O.
// C = [relu]( op(A) @ W + bias ), A optionally transformed by per-k affine+relu
// (fused BN of the previous stage). Optional replicated column sum/ssq stats.
// A panels: addr p[k>>7] + row*astride + (k&127). C: p[blockIdx.x] + row*cstride
// + (col&127). 128x128 tile, 4 waves, 16x16x32 f16 frags.
// ---------------------------------------------------------------------------
template<int RELU>
__global__ __launch_bounds__(256)
void mfma_gemm(PanelsIn Ap, int astride, const ushort_t* __restrict__ Wh,
               const ushort_t* __restrict__ Wl, const float* __restrict__ bias,
               PanelsOut Cp, int cstride, const float* __restrict__ Aff,
               float* __restrict__ cstatR, int N, int K, int M)
{
    __shared__ uint4 Asm4[512];
    __shared__ uint4 Bh4[512];
    __shared__ uint4 Bl4[512];
    const int tid = threadIdx.x;
    const int brow = blockIdx.y * 128, bcol = blockIdx.x * 128;
    const int wid = tid >> 6, lane = tid & 63;
    const int wm = wid >> 1, wn = wid & 1;
    const int lg = lane >> 4, lr = lane & 15;

    const int m0 = tid >> 2, g0 = tid & 3;
    const int ci0 = ((m0 >> 4) << 6) + (g0 << 4) + (m0 & 15);
    const int ci1 = (((m0 + 64) >> 4) << 6) + (g0 << 4) + (m0 & 15);

    floatx4 acc[4][4];
    #pragma unroll
    for (int i = 0; i < 4; ++i)
        #pragma unroll
        for (int j = 0; j < 4; ++j) acc[i][j] = (floatx4){0.f, 0.f, 0.f, 0.f};

    const int nkt = K >> 5;
    for (int kt = 0; kt < nkt; ++kt) {
        const int kb = (kt << 5) + g0 * 8;
        const ushort_t* pa = Ap.p[kb >> 7];
        const int kloc = kb & 127;
        uint4 v0 = *(const uint4*)(pa + (long)(brow + m0) * astride + kloc);
        uint4 v1 = *(const uint4*)(pa + (long)(brow + m0 + 64) * astride + kloc);
        if (Aff) { v0 = aff_relu8(v0, Aff, kb, K); v1 = aff_relu8(v1, Aff, kb, K); }
        Asm4[ci0] = v0;
        Asm4[ci1] = v1;
        const uint4* ph = (const uint4*)(Wh + (((size_t)kt * M + bcol) << 5));
        Bh4[tid] = ph[tid]; Bh4[tid + 256] = ph[tid + 256];
        if (Wl) {
            const uint4* pl = (const uint4*)(Wl + (((size_t)kt * M + bcol) << 5));
            Bl4[tid] = pl[tid]; Bl4[tid + 256] = pl[tid + 256];
        }
        __syncthreads();

        half8_t af[4], bh[4], bl[4];
        #pragma unroll
        for (int i = 0; i < 4; ++i)
            af[i] = __builtin_bit_cast(half8_t, Asm4[((wm << 2) + i) * 64 + (lg << 4) + lr]);
        #pragma unroll
        for (int j = 0; j < 4; ++j) {
            int nb = wn * 64 + j * 16 + lr;
            bh[j] = __builtin_bit_cast(half8_t, Bh4[(nb << 2) + lg]);
            if (Wl) bl[j] = __builtin_bit_cast(half8_t, Bl4[(nb << 2) + lg]);
        }
        #pragma unroll
        for (int i = 0; i < 4; ++i)
            #pragma unroll
            for (int j = 0; j < 4; ++j) {
                acc[i][j] = __builtin_amdgcn_mfma_f32_16x16x32_f16(af[i], bh[j], acc[i][j], 0, 0, 0);
                if (Wl)
                    acc[i][j] = __builtin_amdgcn_mfma_f32_16x16x32_f16(af[i], bl[j], acc[i][j], 0, 0, 0);
            }
        __syncthreads();
    }

    ushort_t* cb = Cp.p[blockIdx.x];
    float csl[4], cql[4];
    #pragma unroll
    for (int j = 0; j < 4; ++j) { csl[j] = 0.f; cql[j] = 0.f; }
    #pragma unroll
    for (int j = 0; j < 4; ++j) {
        int lcol = wn * 64 + j * 16 + lr;
        float bia = bias[bcol + lcol];
        #pragma unroll
        for (int i = 0; i < 4; ++i) {
            #pragma unroll
            for (int r = 0; r < 4; ++r) {
                int row = brow + wm * 64 + i * 16 + (lg << 2) + r;
                float v = acc[i][j][r] + bia;
                if (RELU) v = fmaxf(v, 0.f);
                ushort_t uo = f2h(v);
                cb[(long)row * cstride + lcol] = uo;
                if (cstatR) {
                    float vq = h2f(uo);
                    csl[j] += vq; cql[j] = fmaf(vq, vq, cql[j]);
                }
            }
        }
    }
    if (cstatR) {
        __syncthreads();
        float* cs = (float*)Asm4;
        float* cq = (float*)Bh4;
        if (tid < 128) { cs[tid] = 0.f; cq[tid] = 0.f; }
        __syncthreads();
        #pragma unroll
        for (int j = 0; j < 4; ++j) {
            int cl = wn * 64 + j * 16 + lr;
            atomicAdd(&cs[cl], csl[j]);
            atomicAdd(&cq[cl], cql[j]);
        }
        __syncthreads();
        if (tid < 128) {
            int rep = blockIdx.y & (NREP - 1);
            atomicAdd(&cstatR[(long)rep * 2 * M + bcol + tid], cs[tid]);
            atomicAdd(&cstatR[(long)rep * 2 * M + M + bcol + tid], cq[tid]);
        }
    }
}

// aff[c] = sa, aff[M+c] = sb from replicated stats + BN params
__global__ void finalize_aff(const float* __restrict__ cstatR, int M, float invN,
                             const float* __restrict__ g, const float* __restrict__ b,
                             float* __restrict__ aff)
{
    int c = blockIdx.x * blockDim.x + threadIdx.x;
    if (c >= M) return;
    float s = 0.f, q = 0.f;
    for (int r = 0; r < NREP; ++r) {
        s += cstatR[(long)r * 2 * M + c];
        q += cstatR[(long)r * 2 * M + M + c];
    }
    float m = s * invN, var = q * invN - m * m;
    float sa = rsqrtf(var + 1e-5f) * g[c];
    aff[c] = sa; aff[M + c] = b[c] - m * sa;
}

// ---------------------------------------------------------------------------
// CSR aggregation (one wave per node, grid-stride):
// EB=1 (GINE): out[u] = (1+eps)*in[u] + sum_e relu(in[src[e]] + eattr[e]@Wb+bb)
// EB=0 (GIN):  out[u] = (1+eps)*in[u] + sum_e in[src[e]]
// ---------------------------------------------------------------------------
template<int EB>
__global__ __launch_bounds__(256)
void csr_agg(const ushort_t* __restrict__ in, ushort_t* __restrict__ out,
             const int* __restrict__ offs, const int* __restrict__ elist,
             const int* __restrict__ esrc, const float* __restrict__ eattr,
             const float* __restrict__ Wb, const float* __restrict__ bb,
             const float* __restrict__ eps_p, int n_nodes)
{
    __shared__ float Ws[EB ? 4096 : 1];
    __shared__ float bs[EB ? 256 : 1];
    if (EB) {
        for (int i = threadIdx.x; i < 4096; i += 256) Ws[i] = Wb[i];
        bs[threadIdx.x] = bb[threadIdx.x];
        __syncthreads();
    }
    float epsv = 1.f + eps_p[0];
    int lane = threadIdx.x & 63;
    int gw = (blockIdx.x * 256 + threadIdx.x) >> 6;
    int nw = (gridDim.x * 256) >> 6;
    for (int u = gw; u < n_nodes; u += nw) {
        const ushort_t* own = in + (long)u * 256;
        float acc[4];
        #pragma unroll
        for (int j = 0; j < 4; ++j) acc[j] = epsv * h2f(own[lane + 64 * j]);
        int s = offs[u], e = offs[u + 1];
        for (int i = s; i < e; ++i) {
            int eid = elist[i];
            int sid = esrc[eid];
            const ushort_t* row = in + (long)sid * 256;
            if (EB) {
                float ev[16];
                const float4* ea = (const float4*)(eattr + (long)eid * 16);
                float4 e0 = ea[0], e1 = ea[1], e2 = ea[2], e3 = ea[3];
                ev[0]=e0.x; ev[1]=e0.y; ev[2]=e0.z; ev[3]=e0.w;
                ev[4]=e1.x; ev[5]=e1.y; ev[6]=e1.z; ev[7]=e1.w;
                ev[8]=e2.x; ev[9]=e2.y; ev[10]=e2.z; ev[11]=e2.w;
                ev[12]=e3.x; ev[13]=e3.y; ev[14]=e3.z; ev[15]=e3.w;
                #pragma unroll
                for (int j = 0; j < 4; ++j) {
                    int c = lane + 64 * j;
                    float m = bs[c];
                    #pragma unroll
                    for (int k = 0; k < 16; ++k) m = fmaf(ev[k], Ws[k * 256 + c], m);
                    acc[j] += fmaxf(h2f(row[c]) + m, 0.f);
                }
            } else {
                #pragma unroll
                for (int j = 0; j < 4; ++j) acc[j] += h2f(row[lane + 64 * j]);
            }
        }
        ushort_t* o = out + (long)u * 256;
        #pragma unroll
        for (int j = 0; j < 4; ++j) o[lane + 64 * j] = f2h(acc[j]);
    }
}

// out[u] = relu(aff(raw[u])) + mean_{i in csr[u]} U[midx[elist[i]]]   (256 ch)
__global__ __launch_bounds__(128)
void csr_mean_aff(const ushort_t* __restrict__ raw, const ushort_t* __restrict__ U,
                  const int* __restrict__ midx, const int* __restrict__ elist,
                  const int* __restrict__ offs, const float* __restrict__ Aff,
                  ushort_t* __restrict__ outp)
{
    int u = blockIdx.x, t = threadIdx.x;
    int c0 = t * 2;
    float sa0 = Aff[c0], sa1 = Aff[c0 + 1], sb0 = Aff[256 + c0], sb1 = Aff[256 + c0 + 1];
    ushort2 b = *(const ushort2*)(raw + (long)u * 256 + c0);
    float x0 = fmaxf(h2f(b.x) * sa0 + sb0, 0.f);
    float x1 = fmaxf(h2f(b.y) * sa1 + sb1, 0.f);
    int s = offs[u], e = offs[u + 1];
    float a0 = 0.f, a1 = 0.f;
    for (int i = s; i < e; ++i) {
        long r = midx[elist[i]];
        ushort2 v = *(const ushort2*)(U + r * 256 + c0);
        a0 += h2f(v.x); a1 += h2f(v.y);
    }
    if (e > s) { float inv = 1.f / (float)(e - s); x0 += a0 * inv; x1 += a1 * inv; }
    ushort2 o; o.x = f2h(x0); o.y = f2h(x1);
    *(ushort2*)(outp + (long)u * 256 + c0) = o;
}

// ---------------------------------------------------------------------------
// fp32 GEMM for encoders/readout (small).
// ---------------------------------------------------------------------------
template<int RELU, typename TC>
__global__ __launch_bounds__(256)
void gemm_k(const float* __restrict__ A, const float* __restrict__ W,
            const float* __restrict__ bias, TC* __restrict__ C,
            int N, int K, int M)
{
    const int BK = 16, LDA = 132;
    __shared__ float As[BK * LDA];
    __shared__ float Bs[BK * LDA];
    const int brow = blockIdx.y * 128;
    const int bcol = blockIdx.x * 128;
    const int tid  = threadIdx.x;
    const int tr = tid >> 4, tc = tid & 15;

    float acc[8][8];
    #pragma unroll
    for (int i = 0; i < 8; ++i)
        #pragma unroll
        for (int j = 0; j < 8; ++j) acc[i][j] = 0.f;

    for (int k0 = 0; k0 < K; k0 += BK) {
        #pragma unroll
        for (int u = 0; u < 8; ++u) {
            int idx = tid + u * 256;
            int m = idx >> 4, kk = idx & 15;
            As[kk * LDA + m] = A[(long)(brow + m) * K + k0 + kk];
        }
        #pragma unroll
        for (int u = 0; u < 8; ++u) {
            int idx = tid + u * 256;
            int kk = idx >> 7, n = idx & 127;
            int col = bcol + n;
            Bs[kk * LDA + n] = (col < M) ? W[(long)(k0 + kk) * M + col] : 0.f;
        }
        __syncthreads();
        #pragma unroll
        for (int kk = 0; kk < BK; ++kk) {
            float av[8], bv[8];
            float4 a0 = *(const float4*)&As[kk * LDA + tr * 8];
            float4 a1 = *(const float4*)&As[kk * LDA + tr * 8 + 4];
            float4 b0 = *(const float4*)&Bs[kk * LDA + tc * 8];
            float4 b1 = *(const float4*)&Bs[kk * LDA + tc * 8 + 4];
            av[0]=a0.x; av[1]=a0.y; av[2]=a0.z; av[3]=a0.w;
            av[4]=a1.x; av[5]=a1.y; av[6]=a1.z; av[7]=a1.w;
            bv[0]=b0.x; bv[1]=b0.y; bv[2]=b0.z; bv[3]=b0.w;
            bv[4]=b1.x; bv[5]=b1.y; bv[6]=b1.z; bv[7]=b1.w;
            #pragma unroll
            for (int i = 0; i < 8; ++i)
                #pragma unroll
                for (int j = 0; j < 8; ++j)
                    acc[i][j] = fmaf(av[i], bv[j], acc[i][j]);
        }
        __syncthreads();
    }
    #pragma unroll
    for (int i = 0; i < 8; ++i) {
        int row = brow + tr * 8 + i;
        #pragma unroll
        for (int j = 0; j < 8; ++j) {
            int col = bcol + tc * 8 + j;
            if (col < M) {
                float v = acc[i][j] + bias[col];
                if (RELU) v = fmaxf(v, 0.f);
                if constexpr (sizeof(TC) == 2) ((ushort_t*)C)[(long)row * M + col] = f2h(v);
                else                           ((float*)C)[(long)row * M + col] = v;
            }
        }
    }
}

__global__ void count_idx(const int* __restrict__ idx, int n, int* __restrict__ cnt)
{
    int i = blockIdx.x * blockDim.x + threadIdx.x;
    if (i < n) atomicAdd(&cnt[idx[i]], 1);
}

__global__ void scan_excl(const int* __restrict__ cnt, int n,
                          int* __restrict__ off, int* __restrict__ cursor)
{
    __shared__ int part[1024];
    int t = threadIdx.x;
    int chunk = (n + 1023) / 1024;
    int s0 = t * chunk, s1 = s0 + chunk; if (s1 > n) s1 = n; if (s0 > n) s0 = n;
    int sum = 0;
    for (int i = s0; i < s1; ++i) sum += cnt[i];
    part[t] = sum;
    __syncthreads();
    if (t == 0) {
        int run = 0;
        for (int i = 0; i < 1024; ++i) { int v = part[i]; part[i] = run; run += v; }
        off[n] = run;
    }
    __syncthreads();
    int run = part[t];
    for (int i = s0; i < s1; ++i) {
        int c = cnt[i];
        off[i] = run; cursor[i] = run; run += c;
    }
}

__global__ void csr_fill(const int* __restrict__ idx, int n,
                         int* __restrict__ cursor, int* __restrict__ elist)
{
    int i = blockIdx.x * blockDim.x + threadIdx.x;
    if (i < n) { int p = atomicAdd(&cursor[idx[i]], 1); elist[p] = i; }
}

// pooled[b] = mean of f16 X rows with sorted bidx==b (binary search)
__global__ __launch_bounds__(256)
void seg_pool(const ushort_t* __restrict__ X, const int* __restrict__ bidx,
              int nrows, float* __restrict__ pooled)
{
    int b = blockIdx.x, t = threadIdx.x;
    int lo = 0, hi = nrows;
    while (lo < hi) { int mid = (lo + hi) >> 1; if (bidx[mid] < b) lo = mid + 1; else hi = mid; }
    int s = lo; hi = nrows;
    while (lo < hi) { int mid = (lo + hi) >> 1; if (bidx[mid] < b + 1) lo = mid + 1; else hi = mid; }
    int e = lo;
    float acc = 0.f;
    for (int r = s; r < e; ++r) acc += h2f(X[(long)r * 256 + t]);
    pooled[(long)b * 256 + t] = acc / fmaxf((float)(e - s), 1.f);
}

__global__ void vadd(float* __restrict__ out, const float* __restrict__ in, long n4)
{
    long t = (long)blockIdx.x * blockDim.x + threadIdx.x;
    if (t >= n4) return;
    float4 a = ((float4*)out)[t];
    float4 b = ((const float4*)in)[t];
    a.x += b.x; a.y += b.y; a.z += b.z; a.w += b.w;
    ((float4*)out)[t] = a;
}

// ---------------------------------------------------------------------------
extern "C" void kernel_launch(void* const* d_in, const int* in_sizes, int n_in,
                              void* d_out, int out_size, void* d_ws, size_t ws_size,
                              hipStream_t stream)
{
    (void)in_sizes; (void)n_in;
    const float* x          = (const float*)d_in[0];
    const float* fragments  = (const float*)d_in[1];
    const float* edge_attr  = (const float*)d_in[2];
    const float* atom_enc_W = (const float*)d_in[3];
    const float* atom_enc_b = (const float*)d_in[4];
    const float* frag_enc_W = (const float*)d_in[5];
    const float* frag_enc_b = (const float*)d_in[6];
    const float* bond_W     = (const float*)d_in[7];
    const float* bond_b     = (const float*)d_in[8];
    const float* gine_eps   = (const float*)d_in[9];
    const float* gine_W1    = (const float*)d_in[10];
    const float* gine_b1    = (const float*)d_in[11];
    const float* gine_bn_g  = (const float*)d_in[12];
    const float* gine_bn_b  = (const float*)d_in[13];
    const float* gine_W2    = (const float*)d_in[14];
    const float* gine_b2    = (const float*)d_in[15];
    const float* atom_bn_g  = (const float*)d_in[16];
    const float* atom_bn_b  = (const float*)d_in[17];
    const float* gin_eps    = (const float*)d_in[18];
    const float* gin_W1     = (const float*)d_in[19];
    const float* gin_b1     = (const float*)d_in[20];
    const float* gin_bn_g   = (const float*)d_in[21];
    const float* gin_bn_b   = (const float*)d_in[22];
    const float* gin_W2     = (const float*)d_in[23];
    const float* gin_b2     = (const float*)d_in[24];
    const float* frag_bn_g  = (const float*)d_in[25];
    const float* frag_bn_b  = (const float*)d_in[26];
    const float* a2f_W      = (const float*)d_in[27];
    const float* a2f_b      = (const float*)d_in[28];
    const float* f2a_W      = (const float*)d_in[29];
    const float* f2a_b      = (const float*)d_in[30];
    const float* fo_W1      = (const float*)d_in[31];
    const float* fo_b1      = (const float*)d_in[32];
    const float* fo_W2      = (const float*)d_in[33];
    const float* fo_b2      = (const float*)d_in[34];
    const float* ao_W1      = (const float*)d_in[35];
    const float* ao_b1      = (const float*)d_in[36];
    const float* ao_W2      = (const float*)d_in[37];
    const float* ao_b2      = (const float*)d_in[38];
    const float* out_W1     = (const float*)d_in[39];
    const float* out_b1     = (const float*)d_in[40];
    const float* out_W2     = (const float*)d_in[41];
    const float* out_b2     = (const float*)d_in[42];
    const int* edge_index   = (const int*)d_in[43];
    const int* fedge_index  = (const int*)d_in[44];
    const int* batch        = (const int*)d_in[45];
    const int* fbatch       = (const int*)d_in[46];
    const int* mem_atom     = (const int*)d_in[47];
    const int* mem_frag     = (const int*)d_in[48];

    const int* src  = edge_index;
    const int* dst  = edge_index + N_EDGE;
    const int* fsrc = fedge_index;
    const int* fdst = fedge_index + N_FEDGE;

    // ---- arena (~251 MB) ----
    size_t off = 0;
    auto take = [&](size_t b) -> size_t { size_t p = off; off = (off + b + 255) & ~(size_t)255; return p; };
    size_t o_big   = take((size_t)N_ATOM * 512 * 2);     // 134 MB
    size_t o_a     = take((size_t)N_ATOM * H * 2);       // 67 MB (state / Hb panels 0-1)
    size_t o_f     = take((size_t)N_FRAG * H * 2);       // 17 MB frag state
    size_t o_f2    = take((size_t)N_FRAG * H * 2);       // 17 MB frag scratch
    size_t o_offea = take((size_t)(N_ATOM + 1) * 4);
    size_t o_elea  = take((size_t)N_EDGE * 4);
    size_t o_offef = take((size_t)(N_FRAG + 1) * 4);
    size_t o_elef  = take((size_t)N_FEDGE * 4);
    size_t o_offma = take((size_t)(N_ATOM + 1) * 4);
    size_t o_elma  = take((size_t)N_MEM * 4);
    size_t o_offmf = take((size_t)(N_FRAG + 1) * 4);
    size_t o_elmf  = take((size_t)N_MEM * 4);
    size_t o_cnta  = take((size_t)N_ATOM * 4);
    size_t o_cntf  = take((size_t)N_FRAG * 4);
    size_t o_stats = take((size_t)NREP * 3072 * 4);      // replicated stats
    size_t o_aff   = take(3072 * 4);                     // aff1_a,aff2_a,aff1_f,aff2_f
    size_t o_hi    = take((size_t)2621440 * 2);
    size_t need_nolo = off;
    size_t o_lo    = take((size_t)2621440 * 2);
    size_t need_full = off;

    bool use_lo = (need_full <= ws_size);
    if (!use_lo && need_nolo > ws_size) {
        fill_const<<<64, 256, 0, stream>>>((float*)d_out, out_size,
                                           (float)((double)ws_size / 1024.0));
        return;
    }
    char* base = (char*)d_ws;
    char*     big     = base + o_big;
    ushort_t* a       = (ushort_t*)(base + o_a);
    ushort_t* f       = (ushort_t*)(base + o_f);
    ushort_t* f2      = (ushort_t*)(base + o_f2);
    int* off_ea = (int*)(base + o_offea);
    int* el_ea  = (int*)(base + o_elea);
    int* off_ef = (int*)(base + o_offef);
    int* el_ef  = (int*)(base + o_elef);
    int* off_ma = (int*)(base + o_offma);
    int* el_ma  = (int*)(base + o_elma);
    int* off_mf = (int*)(base + o_offmf);
    int* el_mf  = (int*)(base + o_elmf);
    int* cnt_a  = (int*)(base + o_cnta);
    int* cnt_f  = (int*)(base + o_cntf);
    float* statsR = (float*)(base + o_stats);
    float* affs   = (float*)(base + o_aff);
    ushort_t* Wp_hi = (ushort_t*)(base + o_hi);
    ushort_t* Wp_lo = use_lo ? (ushort_t*)(base + o_lo) : nullptr;

    // stats sub-arrays (per-replica stride = 2*M)
    float* cst1a = statsR;                          // NREP * 1024
    float* cst2a = statsR + (size_t)NREP * 1024;    // NREP * 512
    float* cst1f = statsR + (size_t)NREP * 1536;    // NREP * 1024
    float* cst2f = statsR + (size_t)NREP * 2560;    // NREP * 512
    float* aff1_a = affs;            // 1024 (sa512|sb512)
    float* aff2_a = affs + 1024;     // 512
    float* aff1_f = affs + 1536;     // 1024
    float* aff2_f = affs + 2560;     // 512

    // big-region aliases
    ushort_t* big_u = (ushort_t*)big;
    const size_t HALF_U = (size_t)N_ATOM * 256;          // 33.5M ushorts = 67 MB
    ushort_t* ha  = big_u + HALF_U;                      // h / raw (atoms), big[67:134]
    const size_t PAN_A = (size_t)N_ATOM * 128;
    const size_t PAN_F = (size_t)N_FRAG * 128;
    ushort_t* Ua = big_u;                                // U_a, big[0:67]
    float* pooled_f = (float*)big;
    float* pooled_a = (float*)(big + (size_t)8 * 1024 * 1024);
    float* tmp      = (float*)(big + (size_t)16 * 1024 * 1024);

    const long WG0 = 0, WG1 = 524288, WG2 = 1048576, WG3 = 1572864,
               WG4 = 2097152, WG5 = 2359296;

    // ---- weight prep + CSR builds ----
    prep_w<<<CDIV(2621440L, 256), 256, 0, stream>>>(gine_W1, gine_W2, gin_W1, gin_W2,
                                                    a2f_W, f2a_W, Wp_hi, Wp_lo);
    hipMemsetAsync(cnt_a, 0, (size_t)N_ATOM * 4, stream);
    count_idx<<<CDIV(N_EDGE,256),256,0,stream>>>(dst, N_EDGE, cnt_a);
    scan_excl<<<1, 1024, 0, stream>>>(cnt_a, N_ATOM, off_ea, cnt_a);
    csr_fill<<<CDIV(N_EDGE,256),256,0,stream>>>(dst, N_EDGE, cnt_a, el_ea);

    hipMemsetAsync(cnt_f, 0, (size_t)N_FRAG * 4, stream);
    count_idx<<<CDIV(N_FEDGE,256),256,0,stream>>>(fdst, N_FEDGE, cnt_f);
    scan_excl<<<1, 1024, 0, stream>>>(cnt_f, N_FRAG, off_ef, cnt_f);
    csr_fill<<<CDIV(N_FEDGE,256),256,0,stream>>>(fdst, N_FEDGE, cnt_f, el_ef);

    hipMemsetAsync(cnt_a, 0, (size_t)N_ATOM * 4, stream);
    count_idx<<<CDIV(N_MEM,256),256,0,stream>>>(mem_atom, N_MEM, cnt_a);
    scan_excl<<<1, 1024, 0, stream>>>(cnt_a, N_ATOM, off_ma, cnt_a);
    csr_fill<<<CDIV(N_MEM,256),256,0,stream>>>(mem_atom, N_MEM, cnt_a, el_ma);

    hipMemsetAsync(cnt_f, 0, (size_t)N_FRAG * 4, stream);
    count_idx<<<CDIV(N_MEM,256),256,0,stream>>>(mem_frag, N_MEM, cnt_f);
    scan_excl<<<1, 1024, 0, stream>>>(cnt_f, N_FRAG, off_mf, cnt_f);
    csr_fill<<<CDIV(N_MEM,256),256,0,stream>>>(mem_frag, N_MEM, cnt_f, el_mf);

    // ---- encoders ----
    gemm_k<0,ushort_t><<<dim3(2, N_ATOM/128), 256, 0, stream>>>(
        x, atom_enc_W, atom_enc_b, a, N_ATOM, 64, H);
    gemm_k<0,ushort_t><<<dim3(2, N_FRAG/128), 256, 0, stream>>>(
        fragments, frag_enc_W, frag_enc_b, f, N_FRAG, 32, H);

    const float invNA = 1.f / N_ATOM, invNF = 1.f / N_FRAG;

    for (int l = 0; l < 4; ++l) {
        hipMemsetAsync(statsR, 0, (size_t)NREP * 3072 * 4, stream);

        // ===== atoms: GINE + MLP =====
        csr_agg<1><<<2048, 256, 0, stream>>>(a, ha, off_ea, el_ea, src, edge_attr,
            bond_W + (long)l*16*H, bond_b + l*H, gine_eps + l, N_ATOM);

        PanelsIn A1in; PanelsOut A1out;
        for (int i = 0; i < 4; ++i) A1in.p[i] = ha + i * 128;        // contig K=256
        A1out.p[0] = a;          A1out.p[1] = a + PAN_A;
        A1out.p[2] = big_u;      A1out.p[3] = big_u + PAN_A;
        mfma_gemm<0><<<dim3(4, N_ATOM/128), 256, 0, stream>>>(
            A1in, 256, Wp_hi + WG0 + (long)l*131072,
            Wp_lo ? Wp_lo + WG0 + (long)l*131072 : nullptr,
            gine_b1 + l*512, A1out, 128, nullptr, cst1a, N_ATOM, 256, 512);
        finalize_aff<<<2, 256, 0, stream>>>(cst1a, 512, invNA,
            gine_bn_g + l*512, gine_bn_b + l*512, aff1_a);

        PanelsIn A2in; PanelsOut A2out;
        A2in.p[0] = a;       A2in.p[1] = a + PAN_A;
        A2in.p[2] = big_u;   A2in.p[3] = big_u + PAN_A;
        A2out.p[0] = ha; A2out.p[1] = ha + 128; A2out.p[2] = ha; A2out.p[3] = ha;
        mfma_gemm<0><<<dim3(2, N_ATOM/128), 256, 0, stream>>>(
            A2in, 128, Wp_hi + WG1 + (long)l*131072,
            Wp_lo ? Wp_lo + WG1 + (long)l*131072 : nullptr,
            gine_b2 + l*H, A2out, 256, aff1_a, cst2a, N_ATOM, 512, 256);
        finalize_aff<<<1, 256, 0, stream>>>(cst2a, 256, invNA,
            atom_bn_g + l*H, atom_bn_b + l*H, aff2_a);

        // ===== fragments: GIN + MLP =====
        csr_agg<0><<<512, 256, 0, stream>>>(f, f2, off_ef, el_ef, fsrc, nullptr,
            nullptr, nullptr, gin_eps + l, N_FRAG);

        PanelsIn F1in; PanelsOut F1out;
        for (int i = 0; i < 4; ++i) F1in.p[i] = f2 + i * 128;
        for (int i = 0; i < 4; ++i) F1out.p[i] = big_u + i * PAN_F;
        mfma_gemm<0><<<dim3(4, N_FRAG/128), 256, 0, stream>>>(
            F1in, 256, Wp_hi + WG2 + (long)l*131072,
            Wp_lo ? Wp_lo + WG2 + (long)l*131072 : nullptr,
            gin_b1 + l*512, F1out, 128, nullptr, cst1f, N_FRAG, 256, 512);
        finalize_aff<<<2, 256, 0, stream>>>(cst1f, 512, invNF,
            gin_bn_g + l*512, gin_bn_b + l*512, aff1_f);

        PanelsIn F2in; PanelsOut F2out;
        for (int i = 0; i < 4; ++i) F2in.p[i] = big_u + i * PAN_F;
        F2out.p[0] = f2; F2out.p[1] = f2 + 128; F2out.p[2] = f2; F2out.p[3] = f2;
        mfma_gemm<0><<<dim3(2, N_FRAG/128), 256, 0, stream>>>(
            F2in, 128, Wp_hi + WG3 + (long)l*131072,
            Wp_lo ? Wp_lo + WG3 + (long)l*131072 : nullptr,
            gin_b2 + l*H, F2out, 256, aff1_f, cst2f, N_FRAG, 512, 256);
        finalize_aff<<<1, 256, 0, stream>>>(cst2f, 256, invNF,
            frag_bn_g + l*H, frag_bn_b + l*H, aff2_f);

        // ===== inter MP =====
        // U_a = relu( relu(BN(raw_a)) @ a2f_W + b )   [per-source-node]
        PanelsIn UAin; PanelsOut UAout;
        for (int i = 0; i < 4; ++i) UAin.p[i] = ha + i * 128;
        UAout.p[0] = Ua; UAout.p[1] = Ua + 128; UAout.p[2] = Ua; UAout.p[3] = Ua;
        mfma_gemm<1><<<dim3(2, N_ATOM/128), 256, 0, stream>>>(
            UAin, 256, Wp_hi + WG4 + (long)l*65536,
            Wp_lo ? Wp_lo + WG4 + (long)l*65536 : nullptr,
            a2f_b + l*H, UAout, 256, aff2_a, nullptr, N_ATOM, 256, 256);
        // f_new = relu(BN(raw_f)) + csr-mean(U_a)
        csr_mean_aff<<<N_FRAG, 128, 0, stream>>>(f2, Ua, mem_atom, el_mf, off_mf,
                                                 aff2_f, f);
        // U_f = relu( f_new @ f2a_W + b )
        PanelsIn UFin; PanelsOut UFout;
        for (int i = 0; i < 4; ++i) UFin.p[i] = f + i * 128;
        UFout.p[0] = f2; UFout.p[1] = f2 + 128; UFout.p[2] = f2; UFout.p[3] = f2;
        mfma_gemm<1><<<dim3(2, N_FRAG/128), 256, 0, stream>>>(
            UFin, 256, Wp_hi + WG5 + (long)l*65536,
            Wp_lo ? Wp_lo + WG5 + (long)l*65536 : nullptr,
            f2a_b + l*H, UFout, 256, nullptr, nullptr, N_FRAG, 256, 256);
        // a_new = relu(BN(raw_a)) + csr-mean(U_f)
        csr_mean_aff<<<N_ATOM, 128, 0, stream>>>(ha, f2, mem_frag, el_ma, off_ma,
                                                 aff2_a, a);
    }

    // ===== readout (big region free) =====
    seg_pool<<<BATCH, 256, 0, stream>>>(f, fbatch, N_FRAG, pooled_f);
    gemm_k<1,float><<<dim3(2, BATCH/128), 256, 0, stream>>>(
        pooled_f, fo_W1, fo_b1, tmp, BATCH, H, H);
    gemm_k<1,float><<<dim3(2, BATCH/128), 256, 0, stream>>>(
        tmp, fo_W2, fo_b2, pooled_f, BATCH, H, H);

    seg_pool<<<BATCH, 256, 0, stream>>>(a, batch, N_ATOM, pooled_a);
    gemm_k<1,float><<<dim3(2, BATCH/128), 256, 0, stream>>>(
        pooled_a, ao_W1, ao_b1, tmp, BATCH, H, H);
    gemm_k<1,float><<<dim3(2, BATCH/128), 256, 0, stream>>>(
        tmp, ao_W2, ao_b2, pooled_a, BATCH, H, H);

    vadd<<<(int)CDIV((long)BATCH*H/4,256), 256, 0, stream>>>(
        pooled_a, pooled_f, (long)BATCH * H / 4);
    gemm_k<1,float><<<dim3(2, BATCH/128), 256, 0, stream>>>(
        pooled_a, out_W1, out_b1, tmp, BATCH, H, H);
    gemm_k<0,float><<<dim3(1, BATCH/128), 256, 0, stream>>>(
        tmp, out_W2, out_b2, (float*)d_out, BATCH, H, 1);
}

// Round 7
// 4216.014 us; speedup vs baseline: 6.3418x; 1.1587x over previous
//
#include <hip/hip_runtime.h>

#define CDIV(a,b) (((a)+(b)-1)/(b))

static const int N_ATOM = 131072, N_FRAG = 32768, N_EDGE = 262144,
                 N_FEDGE = 65536, N_MEM = 196608, BATCH = 4096, H = 256;
static const int NREP = 16;   // stat atomic replicas

typedef unsigned short ushort_t;
typedef _Float16 half8_t __attribute__((ext_vector_type(8)));
typedef float    floatx4 __attribute__((ext_vector_type(4)));

struct PanelsIn  { const ushort_t* p[4]; };
struct PanelsOut { ushort_t* p[4]; };

__device__ __forceinline__ float h2f(ushort_t u) {
    _Float16 h; __builtin_memcpy(&h, &u, 2); return (float)h;
}
__device__ __forceinline__ ushort_t f2h(float f) {
    _Float16 h = (_Float16)f; ushort_t u; __builtin_memcpy(&u, &h, 2); return u;
}

__global__ void fill_const(float* p, long n, float v) {
    long t = (long)blockIdx.x * blockDim.x + threadIdx.x;
    long stride = (long)gridDim.x * blockDim.x;
    for (; t < n; t += stride) p[t] = v;
}

// ---------------------------------------------------------------------------
// Weight prep: f32 W[K][M] -> frag-ready f16 hi/lo, layout [K/32][M][32].
// ---------------------------------------------------------------------------
__global__ void prep_w(const float* __restrict__ s0, const float* __restrict__ s1,
                       const float* __restrict__ s2, const float* __restrict__ s3,
                       const float* __restrict__ s4, const float* __restrict__ s5,
                       ushort_t* __restrict__ hi, ushort_t* __restrict__ lo)
{
    long gid = (long)blockIdx.x * 256 + threadIdx.x;
    const float* src; int K, M; long base, loc;
    if      (gid < 524288)  { src=s0; K=256; M=512; base=0;       loc=gid; }
    else if (gid < 1048576) { src=s1; K=512; M=256; base=524288;  loc=gid-524288; }
    else if (gid < 1572864) { src=s2; K=256; M=512; base=1048576; loc=gid-1048576; }
    else if (gid < 2097152) { src=s3; K=512; M=256; base=1572864; loc=gid-1572864; }
    else if (gid < 2359296) { src=s4; K=256; M=256; base=2097152; loc=gid-2097152; }
    else if (gid < 2621440) { src=s5; K=256; M=256; base=2359296; loc=gid-2359296; }
    else return;
    long msz = (long)K * M;
    int  mat = (int)(loc / msz); long rem = loc - (long)mat * msz;
    int  k = (int)(rem / M);     int  n = (int)(rem - (long)k * M);
    float v = src[loc];
    ushort_t hu = f2h(v);
    ushort_t lu = f2h(v - h2f(hu));
    long dst = base + (long)mat * msz + ((long)(k >> 5) * M + n) * 32 + (k & 31);
    hi[dst] = hu;
    if (lo) lo[dst] = lu;
}

__device__ __forceinline__ uint4 aff_relu8(uint4 v, const float* __restrict__ Aff,
                                           int kb, int K)
{
    ushort_t u[8]; __builtin_memcpy(u, &v, 16);
    #pragma unroll
    for (int i = 0; i < 8; ++i) {
        float y = fmaxf(h2f(u[i]) * Aff[kb + i] + Aff[K + kb + i], 0.f);
        u[i] = f2h(y);
    }
    uint4 r; __builtin_memcpy(&r, u, 16);
    return r;
}

// ---------------------------------------------------------------------------
// MFMA f16 GEMM with panel I/O (see round-5 notes).
// ---------------------------------------------------------------------------
template<int RELU>
__global__ __launch_bounds__(256)
void mfma_gemm(PanelsIn Ap, int astride, const ushort_t* __restrict__ Wh,
               const ushort_t* __restrict__ Wl, const float* __restrict__ bias,
               PanelsOut Cp, int cstride, const float* __restrict__ Aff,
               float* __restrict__ cstatR, int N, int K, int M)
{
    __shared__ uint4 Asm4[512];
    __shared__ uint4 Bh4[512];
    __shared__ uint4 Bl4[512];
    const int tid = threadIdx.x;
    const int brow = blockIdx.y * 128, bcol = blockIdx.x * 128;
    const int wid = tid >> 6, lane = tid & 63;
    const int wm = wid >> 1, wn = wid & 1;
    const int lg = lane >> 4, lr = lane & 15;

    const int m0 = tid >> 2, g0 = tid & 3;
    const int ci0 = ((m0 >> 4) << 6) + (g0 << 4) + (m0 & 15);
    const int ci1 = (((m0 + 64) >> 4) << 6) + (g0 << 4) + (m0 & 15);

    floatx4 acc[4][4];
    #pragma unroll
    for (int i = 0; i < 4; ++i)
        #pragma unroll
        for (int j = 0; j < 4; ++j) acc[i][j] = (floatx4){0.f, 0.f, 0.f, 0.f};

    const int nkt = K >> 5;
    for (int kt = 0; kt < nkt; ++kt) {
        const int kb = (kt << 5) + g0 * 8;
        const ushort_t* pa = Ap.p[kb >> 7];
        const int kloc = kb & 127;
        uint4 v0 = *(const uint4*)(pa + (long)(brow + m0) * astride + kloc);
        uint4 v1 = *(const uint4*)(pa + (long)(brow + m0 + 64) * astride + kloc);
        if (Aff) { v0 = aff_relu8(v0, Aff, kb, K); v1 = aff_relu8(v1, Aff, kb, K); }
        Asm4[ci0] = v0;
        Asm4[ci1] = v1;
        const uint4* ph = (const uint4*)(Wh + (((size_t)kt * M + bcol) << 5));
        Bh4[tid] = ph[tid]; Bh4[tid + 256] = ph[tid + 256];
        if (Wl) {
            const uint4* pl = (const uint4*)(Wl + (((size_t)kt * M + bcol) << 5));
            Bl4[tid] = pl[tid]; Bl4[tid + 256] = pl[tid + 256];
        }
        __syncthreads();

        half8_t af[4], bh[4], bl[4];
        #pragma unroll
        for (int i = 0; i < 4; ++i)
            af[i] = __builtin_bit_cast(half8_t, Asm4[((wm << 2) + i) * 64 + (lg << 4) + lr]);
        #pragma unroll
        for (int j = 0; j < 4; ++j) {
            int nb = wn * 64 + j * 16 + lr;
            bh[j] = __builtin_bit_cast(half8_t, Bh4[(nb << 2) + lg]);
            if (Wl) bl[j] = __builtin_bit_cast(half8_t, Bl4[(nb << 2) + lg]);
        }
        #pragma unroll
        for (int i = 0; i < 4; ++i)
            #pragma unroll
            for (int j = 0; j < 4; ++j) {
                acc[i][j] = __builtin_amdgcn_mfma_f32_16x16x32_f16(af[i], bh[j], acc[i][j], 0, 0, 0);
                if (Wl)
                    acc[i][j] = __builtin_amdgcn_mfma_f32_16x16x32_f16(af[i], bl[j], acc[i][j], 0, 0, 0);
            }
        __syncthreads();
    }

    ushort_t* cb = Cp.p[blockIdx.x];
    float csl[4], cql[4];
    #pragma unroll
    for (int j = 0; j < 4; ++j) { csl[j] = 0.f; cql[j] = 0.f; }
    #pragma unroll
    for (int j = 0; j < 4; ++j) {
        int lcol = wn * 64 + j * 16 + lr;
        float bia = bias[bcol + lcol];
        #pragma unroll
        for (int i = 0; i < 4; ++i) {
            #pragma unroll
            for (int r = 0; r < 4; ++r) {
                int row = brow + wm * 64 + i * 16 + (lg << 2) + r;
                float v = acc[i][j][r] + bia;
                if (RELU) v = fmaxf(v, 0.f);
                ushort_t uo = f2h(v);
                cb[(long)row * cstride + lcol] = uo;
                if (cstatR) {
                    float vq = h2f(uo);
                    csl[j] += vq; cql[j] = fmaf(vq, vq, cql[j]);
                }
            }
        }
    }
    if (cstatR) {
        __syncthreads();
        float* cs = (float*)Asm4;
        float* cq = (float*)Bh4;
        if (tid < 128) { cs[tid] = 0.f; cq[tid] = 0.f; }
        __syncthreads();
        #pragma unroll
        for (int j = 0; j < 4; ++j) {
            int cl = wn * 64 + j * 16 + lr;
            atomicAdd(&cs[cl], csl[j]);
            atomicAdd(&cq[cl], cql[j]);
        }
        __syncthreads();
        if (tid < 128) {
            int rep = blockIdx.y & (NREP - 1);
            atomicAdd(&cstatR[(long)rep * 2 * M + bcol + tid], cs[tid]);
            atomicAdd(&cstatR[(long)rep * 2 * M + M + bcol + tid], cq[tid]);
        }
    }
}

// aff[c] = sa, aff[M+c] = sb from replicated stats + BN params
__global__ void finalize_aff(const float* __restrict__ cstatR, int M, float invN,
                             const float* __restrict__ g, const float* __restrict__ b,
                             float* __restrict__ aff)
{
    int c = blockIdx.x * blockDim.x + threadIdx.x;
    if (c >= M) return;
    float s = 0.f, q = 0.f;
    for (int r = 0; r < NREP; ++r) {
        s += cstatR[(long)r * 2 * M + c];
        q += cstatR[(long)r * 2 * M + M + c];
    }
    float m = s * invN, var = q * invN - m * m;
    float sa = rsqrtf(var + 1e-5f) * g[c];
    aff[c] = sa; aff[M + c] = b[c] - m * sa;
}

// ---------------------------------------------------------------------------
// CSR aggregation (one wave per node, grid-stride).
// ---------------------------------------------------------------------------
template<int EB>
__global__ __launch_bounds__(256)
void csr_agg(const ushort_t* __restrict__ in, ushort_t* __restrict__ out,
             const int* __restrict__ offs, const int* __restrict__ elist,
             const int* __restrict__ esrc, const float* __restrict__ eattr,
             const float* __restrict__ Wb, const float* __restrict__ bb,
             const float* __restrict__ eps_p, int n_nodes)
{
    __shared__ float Ws[EB ? 4096 : 1];
    __shared__ float bs[EB ? 256 : 1];
    if (EB) {
        for (int i = threadIdx.x; i < 4096; i += 256) Ws[i] = Wb[i];
        bs[threadIdx.x] = bb[threadIdx.x];
        __syncthreads();
    }
    float epsv = 1.f + eps_p[0];
    int lane = threadIdx.x & 63;
    int gw = (blockIdx.x * 256 + threadIdx.x) >> 6;
    int nw = (gridDim.x * 256) >> 6;
    for (int u = gw; u < n_nodes; u += nw) {
        const ushort_t* own = in + (long)u * 256;
        float acc[4];
        #pragma unroll
        for (int j = 0; j < 4; ++j) acc[j] = epsv * h2f(own[lane + 64 * j]);
        int s = offs[u], e = offs[u + 1];
        for (int i = s; i < e; ++i) {
            int eid = elist[i];
            int sid = esrc[eid];
            const ushort_t* row = in + (long)sid * 256;
            if (EB) {
                float ev[16];
                const float4* ea = (const float4*)(eattr + (long)eid * 16);
                float4 e0 = ea[0], e1 = ea[1], e2 = ea[2], e3 = ea[3];
                ev[0]=e0.x; ev[1]=e0.y; ev[2]=e0.z; ev[3]=e0.w;
                ev[4]=e1.x; ev[5]=e1.y; ev[6]=e1.z; ev[7]=e1.w;
                ev[8]=e2.x; ev[9]=e2.y; ev[10]=e2.z; ev[11]=e2.w;
                ev[12]=e3.x; ev[13]=e3.y; ev[14]=e3.z; ev[15]=e3.w;
                #pragma unroll
                for (int j = 0; j < 4; ++j) {
                    int c = lane + 64 * j;
                    float m = bs[c];
                    #pragma unroll
                    for (int k = 0; k < 16; ++k) m = fmaf(ev[k], Ws[k * 256 + c], m);
                    acc[j] += fmaxf(h2f(row[c]) + m, 0.f);
                }
            } else {
                #pragma unroll
                for (int j = 0; j < 4; ++j) acc[j] += h2f(row[lane + 64 * j]);
            }
        }
        ushort_t* o = out + (long)u * 256;
        #pragma unroll
        for (int j = 0; j < 4; ++j) o[lane + 64 * j] = f2h(acc[j]);
    }
}

// out[u] = relu(aff(raw[u])) + mean_{i in csr[u]} U[midx[elist[i]]]   (256 ch)
__global__ __launch_bounds__(128)
void csr_mean_aff(const ushort_t* __restrict__ raw, const ushort_t* __restrict__ U,
                  const int* __restrict__ midx, const int* __restrict__ elist,
                  const int* __restrict__ offs, const float* __restrict__ Aff,
                  ushort_t* __restrict__ outp)
{
    int u = blockIdx.x, t = threadIdx.x;
    int c0 = t * 2;
    float sa0 = Aff[c0], sa1 = Aff[c0 + 1], sb0 = Aff[256 + c0], sb1 = Aff[256 + c0 + 1];
    ushort2 b = *(const ushort2*)(raw + (long)u * 256 + c0);
    float x0 = fmaxf(h2f(b.x) * sa0 + sb0, 0.f);
    float x1 = fmaxf(h2f(b.y) * sa1 + sb1, 0.f);
    int s = offs[u], e = offs[u + 1];
    float a0 = 0.f, a1 = 0.f;
    for (int i = s; i < e; ++i) {
        long r = midx[elist[i]];
        ushort2 v = *(const ushort2*)(U + r * 256 + c0);
        a0 += h2f(v.x); a1 += h2f(v.y);
    }
    if (e > s) { float inv = 1.f / (float)(e - s); x0 += a0 * inv; x1 += a1 * inv; }
    ushort2 o; o.x = f2h(x0); o.y = f2h(x1);
    *(ushort2*)(outp + (long)u * 256 + c0) = o;
}

// ---------------------------------------------------------------------------
// fp32 GEMM for encoders/readout (small).
// ---------------------------------------------------------------------------
template<int RELU, typename TC>
__global__ __launch_bounds__(256)
void gemm_k(const float* __restrict__ A, const float* __restrict__ W,
            const float* __restrict__ bias, TC* __restrict__ C,
            int N, int K, int M)
{
    const int BK = 16, LDA = 132;
    __shared__ float As[BK * LDA];
    __shared__ float Bs[BK * LDA];
    const int brow = blockIdx.y * 128;
    const int bcol = blockIdx.x * 128;
    const int tid  = threadIdx.x;
    const int tr = tid >> 4, tc = tid & 15;

    float acc[8][8];
    #pragma unroll
    for (int i = 0; i < 8; ++i)
        #pragma unroll
        for (int j = 0; j < 8; ++j) acc[i][j] = 0.f;

    for (int k0 = 0; k0 < K; k0 += BK) {
        #pragma unroll
        for (int u = 0; u < 8; ++u) {
            int idx = tid + u * 256;
            int m = idx >> 4, kk = idx & 15;
            As[kk * LDA + m] = A[(long)(brow + m) * K + k0 + kk];
        }
        #pragma unroll
        for (int u = 0; u < 8; ++u) {
            int idx = tid + u * 256;
            int kk = idx >> 7, n = idx & 127;
            int col = bcol + n;
            Bs[kk * LDA + n] = (col < M) ? W[(long)(k0 + kk) * M + col] : 0.f;
        }
        __syncthreads();
        #pragma unroll
        for (int kk = 0; kk < BK; ++kk) {
            float av[8], bv[8];
            float4 a0 = *(const float4*)&As[kk * LDA + tr * 8];
            float4 a1 = *(const float4*)&As[kk * LDA + tr * 8 + 4];
            float4 b0 = *(const float4*)&Bs[kk * LDA + tc * 8];
            float4 b1 = *(const float4*)&Bs[kk * LDA + tc * 8 + 4];
            av[0]=a0.x; av[1]=a0.y; av[2]=a0.z; av[3]=a0.w;
            av[4]=a1.x; av[5]=a1.y; av[6]=a1.z; av[7]=a1.w;
            bv[0]=b0.x; bv[1]=b0.y; bv[2]=b0.z; bv[3]=b0.w;
            bv[4]=b1.x; bv[5]=b1.y; bv[6]=b1.z; bv[7]=b1.w;
            #pragma unroll
            for (int i = 0; i < 8; ++i)
                #pragma unroll
                for (int j = 0; j < 8; ++j)
                    acc[i][j] = fmaf(av[i], bv[j], acc[i][j]);
        }
        __syncthreads();
    }
    #pragma unroll
    for (int i = 0; i < 8; ++i) {
        int row = brow + tr * 8 + i;
        #pragma unroll
        for (int j = 0; j < 8; ++j) {
            int col = bcol + tc * 8 + j;
            if (col < M) {
                float v = acc[i][j] + bias[col];
                if (RELU) v = fmaxf(v, 0.f);
                if constexpr (sizeof(TC) == 2) ((ushort_t*)C)[(long)row * M + col] = f2h(v);
                else                           ((float*)C)[(long)row * M + col] = v;
            }
        }
    }
}

__global__ void count_idx(const int* __restrict__ idx, int n, int* __restrict__ cnt)
{
    int i = blockIdx.x * blockDim.x + threadIdx.x;
    if (i < n) atomicAdd(&cnt[idx[i]], 1);
}

// ---- parallel exclusive scan (3 phases) ----
__global__ __launch_bounds__(256)
void scan_p1(const int* __restrict__ cnt, int n, int* __restrict__ partials)
{
    __shared__ int sd[256];
    int i = blockIdx.x * 256 + threadIdx.x;
    sd[threadIdx.x] = (i < n) ? cnt[i] : 0;
    __syncthreads();
    #pragma unroll
    for (int s = 128; s > 0; s >>= 1) {
        if (threadIdx.x < s) sd[threadIdx.x] += sd[threadIdx.x + s];
        __syncthreads();
    }
    if (threadIdx.x == 0) partials[blockIdx.x] = sd[0];
}

// single block: exclusive-scan partials[nb] in place; off[n] = total
__global__ __launch_bounds__(1024)
void scan_p2(int* __restrict__ partials, int nb, int* __restrict__ off, int n)
{
    __shared__ int sd[1024];
    int t = threadIdx.x;
    int v = (t < nb) ? partials[t] : 0;
    sd[t] = v;
    __syncthreads();
    for (int d = 1; d < 1024; d <<= 1) {
        int x = (t >= d) ? sd[t - d] : 0;
        __syncthreads();
        sd[t] += x;
        __syncthreads();
    }
    if (t < nb) partials[t] = sd[t] - v;          // exclusive
    if (t == 1023) off[n] = sd[nb - 1];           // total
}

// off[i] = cursor[i] = partials[blk] + exclusive prefix within block.
// cursor may alias cnt (each elem read once by its own thread first).
__global__ __launch_bounds__(256)
void scan_p3(const int* __restrict__ cnt, int n, const int* __restrict__ partials,
             int* __restrict__ off, int* __restrict__ cursor)
{
    __shared__ int sd[256];
    int i = blockIdx.x * 256 + threadIdx.x;
    int v = (i < n) ? cnt[i] : 0;
    sd[threadIdx.x] = v;
    __syncthreads();
    for (int d = 1; d < 256; d <<= 1) {
        int x = (threadIdx.x >= d) ? sd[threadIdx.x - d] : 0;
        __syncthreads();
        sd[threadIdx.x] += x;
        __syncthreads();
    }
    if (i < n) {
        int e = partials[blockIdx.x] + sd[threadIdx.x] - v;
        off[i] = e; cursor[i] = e;
    }
}

__global__ void csr_fill(const int* __restrict__ idx, int n,
                         int* __restrict__ cursor, int* __restrict__ elist)
{
    int i = blockIdx.x * blockDim.x + threadIdx.x;
    if (i < n) { int p = atomicAdd(&cursor[idx[i]], 1); elist[p] = i; }
}

// pooled[b] = mean of f16 X rows with sorted bidx==b (binary search)
__global__ __launch_bounds__(256)
void seg_pool(const ushort_t* __restrict__ X, const int* __restrict__ bidx,
              int nrows, float* __restrict__ pooled)
{
    int b = blockIdx.x, t = threadIdx.x;
    int lo = 0, hi = nrows;
    while (lo < hi) { int mid = (lo + hi) >> 1; if (bidx[mid] < b) lo = mid + 1; else hi = mid; }
    int s = lo; hi = nrows;
    while (lo < hi) { int mid = (lo + hi) >> 1; if (bidx[mid] < b + 1) lo = mid + 1; else hi = mid; }
    int e = lo;
    float acc = 0.f;
    for (int r = s; r < e; ++r) acc += h2f(X[(long)r * 256 + t]);
    pooled[(long)b * 256 + t] = acc / fmaxf((float)(e - s), 1.f);
}

__global__ void vadd(float* __restrict__ out, const float* __restrict__ in, long n4)
{
    long t = (long)blockIdx.x * blockDim.x + threadIdx.x;
    if (t >= n4) return;
    float4 a = ((float4*)out)[t];
    float4 b = ((const float4*)in)[t];
    a.x += b.x; a.y += b.y; a.z += b.z; a.w += b.w;
    ((float4*)out)[t] = a;
}

// ---------------------------------------------------------------------------
extern "C" void kernel_launch(void* const* d_in, const int* in_sizes, int n_in,
                              void* d_out, int out_size, void* d_ws, size_t ws_size,
                              hipStream_t stream)
{
    (void)in_sizes; (void)n_in;
    const float* x          = (const float*)d_in[0];
    const float* fragments  = (const float*)d_in[1];
    const float* edge_attr  = (const float*)d_in[2];
    const float* atom_enc_W = (const float*)d_in[3];
    const float* atom_enc_b = (const float*)d_in[4];
    const float* frag_enc_W = (const float*)d_in[5];
    const float* frag_enc_b = (const float*)d_in[6];
    const float* bond_W     = (const float*)d_in[7];
    const float* bond_b     = (const float*)d_in[8];
    const float* gine_eps   = (const float*)d_in[9];
    const float* gine_W1    = (const float*)d_in[10];
    const float* gine_b1    = (const float*)d_in[11];
    const float* gine_bn_g  = (const float*)d_in[12];
    const float* gine_bn_b  = (const float*)d_in[13];
    const float* gine_W2    = (const float*)d_in[14];
    const float* gine_b2    = (const float*)d_in[15];
    const float* atom_bn_g  = (const float*)d_in[16];
    const float* atom_bn_b  = (const float*)d_in[17];
    const float* gin_eps    = (const float*)d_in[18];
    const float* gin_W1     = (const float*)d_in[19];
    const float* gin_b1     = (const float*)d_in[20];
    const float* gin_bn_g   = (const float*)d_in[21];
    const float* gin_bn_b   = (const float*)d_in[22];
    const float* gin_W2     = (const float*)d_in[23];
    const float* gin_b2     = (const float*)d_in[24];
    const float* frag_bn_g  = (const float*)d_in[25];
    const float* frag_bn_b  = (const float*)d_in[26];
    const float* a2f_W      = (const float*)d_in[27];
    const float* a2f_b      = (const float*)d_in[28];
    const float* f2a_W      = (const float*)d_in[29];
    const float* f2a_b      = (const float*)d_in[30];
    const float* fo_W1      = (const float*)d_in[31];
    const float* fo_b1      = (const float*)d_in[32];
    const float* fo_W2      = (const float*)d_in[33];
    const float* fo_b2      = (const float*)d_in[34];
    const float* ao_W1      = (const float*)d_in[35];
    const float* ao_b1      = (const float*)d_in[36];
    const float* ao_W2      = (const float*)d_in[37];
    const float* ao_b2      = (const float*)d_in[38];
    const float* out_W1     = (const float*)d_in[39];
    const float* out_b1     = (const float*)d_in[40];
    const float* out_W2     = (const float*)d_in[41];
    const float* out_b2     = (const float*)d_in[42];
    const int* edge_index   = (const int*)d_in[43];
    const int* fedge_index  = (const int*)d_in[44];
    const int* batch        = (const int*)d_in[45];
    const int* fbatch       = (const int*)d_in[46];
    const int* mem_atom     = (const int*)d_in[47];
    const int* mem_frag     = (const int*)d_in[48];

    const int* src  = edge_index;
    const int* dst  = edge_index + N_EDGE;
    const int* fsrc = fedge_index;
    const int* fdst = fedge_index + N_FEDGE;

    // ---- arena ----
    size_t off = 0;
    auto take = [&](size_t b) -> size_t { size_t p = off; off = (off + b + 255) & ~(size_t)255; return p; };
    size_t o_big   = take((size_t)N_ATOM * 512 * 2);     // 134 MB
    size_t o_a     = take((size_t)N_ATOM * H * 2);       // 67 MB
    size_t o_f     = take((size_t)N_FRAG * H * 2);
    size_t o_f2    = take((size_t)N_FRAG * H * 2);
    size_t o_offea = take((size_t)(N_ATOM + 1) * 4);
    size_t o_elea  = take((size_t)N_EDGE * 4);
    size_t o_offef = take((size_t)(N_FRAG + 1) * 4);
    size_t o_elef  = take((size_t)N_FEDGE * 4);
    size_t o_offma = take((size_t)(N_ATOM + 1) * 4);
    size_t o_elma  = take((size_t)N_MEM * 4);
    size_t o_offmf = take((size_t)(N_FRAG + 1) * 4);
    size_t o_elmf  = take((size_t)N_MEM * 4);
    size_t o_cnta  = take((size_t)N_ATOM * 4);
    size_t o_cntf  = take((size_t)N_FRAG * 4);
    size_t o_part  = take(1024 * 4);                     // scan partials
    size_t o_stats = take((size_t)NREP * 3072 * 4);
    size_t o_aff   = take(3072 * 4);
    size_t o_hi    = take((size_t)2621440 * 2);
    size_t need_nolo = off;
    size_t o_lo    = take((size_t)2621440 * 2);
    size_t need_full = off;

    bool use_lo = (need_full <= ws_size);
    if (!use_lo && need_nolo > ws_size) {
        fill_const<<<64, 256, 0, stream>>>((float*)d_out, out_size,
                                           (float)((double)ws_size / 1024.0));
        return;
    }
    char* base = (char*)d_ws;
    char*     big     = base + o_big;
    ushort_t* a       = (ushort_t*)(base + o_a);
    ushort_t* f       = (ushort_t*)(base + o_f);
    ushort_t* f2      = (ushort_t*)(base + o_f2);
    int* off_ea = (int*)(base + o_offea);
    int* el_ea  = (int*)(base + o_elea);
    int* off_ef = (int*)(base + o_offef);
    int* el_ef  = (int*)(base + o_elef);
    int* off_ma = (int*)(base + o_offma);
    int* el_ma  = (int*)(base + o_elma);
    int* off_mf = (int*)(base + o_offmf);
    int* el_mf  = (int*)(base + o_elmf);
    int* cnt_a  = (int*)(base + o_cnta);
    int* cnt_f  = (int*)(base + o_cntf);
    int* parts  = (int*)(base + o_part);
    float* statsR = (float*)(base + o_stats);
    float* affs   = (float*)(base + o_aff);
    ushort_t* Wp_hi = (ushort_t*)(base + o_hi);
    ushort_t* Wp_lo = use_lo ? (ushort_t*)(base + o_lo) : nullptr;

    float* cst1a = statsR;
    float* cst2a = statsR + (size_t)NREP * 1024;
    float* cst1f = statsR + (size_t)NREP * 1536;
    float* cst2f = statsR + (size_t)NREP * 2560;
    float* aff1_a = affs;
    float* aff2_a = affs + 1024;
    float* aff1_f = affs + 1536;
    float* aff2_f = affs + 2560;

    ushort_t* big_u = (ushort_t*)big;
    const size_t HALF_U = (size_t)N_ATOM * 256;
    ushort_t* ha  = big_u + HALF_U;
    const size_t PAN_A = (size_t)N_ATOM * 128;
    const size_t PAN_F = (size_t)N_FRAG * 128;
    ushort_t* Ua = big_u;
    float* pooled_f = (float*)big;
    float* pooled_a = (float*)(big + (size_t)8 * 1024 * 1024);
    float* tmp      = (float*)(big + (size_t)16 * 1024 * 1024);

    const long WG0 = 0, WG1 = 524288, WG2 = 1048576, WG3 = 1572864,
               WG4 = 2097152, WG5 = 2359296;

    // helper: parallel CSR build (count -> 3-phase scan -> fill)
    auto build_csr = [&](const int* idx, int n_edges, int n_nodes,
                         int* cnt, int* offs, int* elist) {
        hipMemsetAsync(cnt, 0, (size_t)n_nodes * 4, stream);
        count_idx<<<CDIV(n_edges,256),256,0,stream>>>(idx, n_edges, cnt);
        int nb = CDIV(n_nodes, 256);
        scan_p1<<<nb, 256, 0, stream>>>(cnt, n_nodes, parts);
        scan_p2<<<1, 1024, 0, stream>>>(parts, nb, offs, n_nodes);
        scan_p3<<<nb, 256, 0, stream>>>(cnt, n_nodes, parts, offs, cnt);
        csr_fill<<<CDIV(n_edges,256),256,0,stream>>>(idx, n_edges, cnt, elist);
    };

    // ---- weight prep + CSR builds ----
    prep_w<<<CDIV(2621440L, 256), 256, 0, stream>>>(gine_W1, gine_W2, gin_W1, gin_W2,
                                                    a2f_W, f2a_W, Wp_hi, Wp_lo);
    build_csr(dst,      N_EDGE,  N_ATOM, cnt_a, off_ea, el_ea);
    build_csr(fdst,     N_FEDGE, N_FRAG, cnt_f, off_ef, el_ef);
    build_csr(mem_atom, N_MEM,   N_ATOM, cnt_a, off_ma, el_ma);
    build_csr(mem_frag, N_MEM,   N_FRAG, cnt_f, off_mf, el_mf);

    // ---- encoders ----
    gemm_k<0,ushort_t><<<dim3(2, N_ATOM/128), 256, 0, stream>>>(
        x, atom_enc_W, atom_enc_b, a, N_ATOM, 64, H);
    gemm_k<0,ushort_t><<<dim3(2, N_FRAG/128), 256, 0, stream>>>(
        fragments, frag_enc_W, frag_enc_b, f, N_FRAG, 32, H);

    const float invNA = 1.f / N_ATOM, invNF = 1.f / N_FRAG;

    for (int l = 0; l < 4; ++l) {
        hipMemsetAsync(statsR, 0, (size_t)NREP * 3072 * 4, stream);

        // ===== atoms: GINE + MLP =====
        csr_agg<1><<<2048, 256, 0, stream>>>(a, ha, off_ea, el_ea, src, edge_attr,
            bond_W + (long)l*16*H, bond_b + l*H, gine_eps + l, N_ATOM);

        PanelsIn A1in; PanelsOut A1out;
        for (int i = 0; i < 4; ++i) A1in.p[i] = ha + i * 128;
        A1out.p[0] = a;          A1out.p[1] = a + PAN_A;
        A1out.p[2] = big_u;      A1out.p[3] = big_u + PAN_A;
        mfma_gemm<0><<<dim3(4, N_ATOM/128), 256, 0, stream>>>(
            A1in, 256, Wp_hi + WG0 + (long)l*131072,
            Wp_lo ? Wp_lo + WG0 + (long)l*131072 : nullptr,
            gine_b1 + l*512, A1out, 128, nullptr, cst1a, N_ATOM, 256, 512);
        finalize_aff<<<2, 256, 0, stream>>>(cst1a, 512, invNA,
            gine_bn_g + l*512, gine_bn_b + l*512, aff1_a);

        PanelsIn A2in; PanelsOut A2out;
        A2in.p[0] = a;       A2in.p[1] = a + PAN_A;
        A2in.p[2] = big_u;   A2in.p[3] = big_u + PAN_A;
        A2out.p[0] = ha; A2out.p[1] = ha + 128; A2out.p[2] = ha; A2out.p[3] = ha;
        mfma_gemm<0><<<dim3(2, N_ATOM/128), 256, 0, stream>>>(
            A2in, 128, Wp_hi + WG1 + (long)l*131072,
            Wp_lo ? Wp_lo + WG1 + (long)l*131072 : nullptr,
            gine_b2 + l*H, A2out, 256, aff1_a, cst2a, N_ATOM, 512, 256);
        finalize_aff<<<1, 256, 0, stream>>>(cst2a, 256, invNA,
            atom_bn_g + l*H, atom_bn_b + l*H, aff2_a);

        // ===== fragments: GIN + MLP =====
        csr_agg<0><<<512, 256, 0, stream>>>(f, f2, off_ef, el_ef, fsrc, nullptr,
            nullptr, nullptr, gin_eps + l, N_FRAG);

        PanelsIn F1in; PanelsOut F1out;
        for (int i = 0; i < 4; ++i) F1in.p[i] = f2 + i * 128;
        for (int i = 0; i < 4; ++i) F1out.p[i] = big_u + i * PAN_F;
        mfma_gemm<0><<<dim3(4, N_FRAG/128), 256, 0, stream>>>(
            F1in, 256, Wp_hi + WG2 + (long)l*131072,
            Wp_lo ? Wp_lo + WG2 + (long)l*131072 : nullptr,
            gin_b1 + l*512, F1out, 128, nullptr, cst1f, N_FRAG, 256, 512);
        finalize_aff<<<2, 256, 0, stream>>>(cst1f, 512, invNF,
            gin_bn_g + l*512, gin_bn_b + l*512, aff1_f);

        PanelsIn F2in; PanelsOut F2out;
        for (int i = 0; i < 4; ++i) F2in.p[i] = big_u + i * PAN_F;
        F2out.p[0] = f2; F2out.p[1] = f2 + 128; F2out.p[2] = f2; F2out.p[3] = f2;
        mfma_gemm<0><<<dim3(2, N_FRAG/128), 256, 0, stream>>>(
            F2in, 128, Wp_hi + WG3 + (long)l*131072,
            Wp_lo ? Wp_lo + WG3 + (long)l*131072 : nullptr,
            gin_b2 + l*H, F2out, 256, aff1_f, cst2f, N_FRAG, 512, 256);
        finalize_aff<<<1, 256, 0, stream>>>(cst2f, 256, invNF,
            frag_bn_g + l*H, frag_bn_b + l*H, aff2_f);

        // ===== inter MP =====
        PanelsIn UAin; PanelsOut UAout;
        for (int i = 0; i < 4; ++i) UAin.p[i] = ha + i * 128;
        UAout.p[0] = Ua; UAout.p[1] = Ua + 128; UAout.p[2] = Ua; UAout.p[3] = Ua;
        mfma_gemm<1><<<dim3(2, N_ATOM/128), 256, 0, stream>>>(
            UAin, 256, Wp_hi + WG4 + (long)l*65536,
            Wp_lo ? Wp_lo + WG4 + (long)l*65536 : nullptr,
            a2f_b + l*H, UAout, 256, aff2_a, nullptr, N_ATOM, 256, 256);
        csr_mean_aff<<<N_FRAG, 128, 0, stream>>>(f2, Ua, mem_atom, el_mf, off_mf,
                                                 aff2_f, f);
        PanelsIn UFin; PanelsOut UFout;
        for (int i = 0; i < 4; ++i) UFin.p[i] = f + i * 128;
        UFout.p[0] = f2; UFout.p[1] = f2 + 128; UFout.p[2] = f2; UFout.p[3] = f2;
        mfma_gemm<1><<<dim3(2, N_FRAG/128), 256, 0, stream>>>(
            UFin, 256, Wp_hi + WG5 + (long)l*65536,
            Wp_lo ? Wp_lo + WG5 + (long)l*65536 : nullptr,
            f2a_b + l*H, UFout, 256, nullptr, nullptr, N_FRAG, 256, 256);
        csr_mean_aff<<<N_ATOM, 128, 0, stream>>>(ha, f2, mem_frag, el_ma, off_ma,
                                                 aff2_a, a);
    }

    // ===== readout =====
    seg_pool<<<BATCH, 256, 0, stream>>>(f, fbatch, N_FRAG, pooled_f);
    gemm_k<1,float><<<dim3(2, BATCH/128), 256, 0, stream>>>(
        pooled_f, fo_W1, fo_b1, tmp, BATCH, H, H);
    gemm_k<1,float><<<dim3(2, BATCH/128), 256, 0, stream>>>(
        tmp, fo_W2, fo_b2, pooled_f, BATCH, H, H);

    seg_pool<<<BATCH, 256, 0, stream>>>(a, batch, N_ATOM, pooled_a);
    gemm_k<1,float><<<dim3(2, BATCH/128), 256, 0, stream>>>(
        pooled_a, ao_W1, ao_b1, tmp, BATCH, H, H);
    gemm_k<1,float><<<dim3(2, BATCH/128), 256, 0, stream>>>(
        tmp, ao_W2, ao_b2, pooled_a, BATCH, H, H);

    vadd<<<(int)CDIV((long)BATCH*H/4,256), 256, 0, stream>>>(
        pooled_a, pooled_f, (long)BATCH * H / 4);
    gemm_k<1,float><<<dim3(2, BATCH/128), 256, 0, stream>>>(
        pooled_a, out_W1, out_b1, tmp, BATCH, H, H);
    gemm_k<0,float><<<dim3(1, BATCH/128), 256, 0, stream>>>(
        tmp, out_W2, out_b2, (float*)d_out, BATCH, H, 1);
}

// Round 8
// 3637.830 us; speedup vs baseline: 7.3497x; 1.1589x over previous
//
#include <hip/hip_runtime.h>

#define CDIV(a,b) (((a)+(b)-1)/(b))

static const int N_ATOM = 131072, N_FRAG = 32768, N_EDGE = 262144,
                 N_FEDGE = 65536, N_MEM = 196608, BATCH = 4096, H = 256;
static const int NREP = 16;   // stat atomic replicas

typedef unsigned short ushort_t;
typedef _Float16 half8_t __attribute__((ext_vector_type(8)));
typedef float    floatx4 __attribute__((ext_vector_type(4)));

struct PanelsIn  { const ushort_t* p[4]; };
struct PanelsOut { ushort_t* p[4]; };

__device__ __forceinline__ float h2f(ushort_t u) {
    _Float16 h; __builtin_memcpy(&h, &u, 2); return (float)h;
}
__device__ __forceinline__ ushort_t f2h(float f) {
    _Float16 h = (_Float16)f; ushort_t u; __builtin_memcpy(&u, &h, 2); return u;
}

// async global->LDS, 16B per lane. lds base must be wave-uniform; HW adds lane*16.
__device__ __forceinline__ void load_lds16(const ushort_t* g, ushort_t* l) {
    __builtin_amdgcn_global_load_lds(
        (const __attribute__((address_space(1))) unsigned int*)g,
        (__attribute__((address_space(3))) unsigned int*)l, 16, 0, 0);
}

__global__ void fill_const(float* p, long n, float v) {
    long t = (long)blockIdx.x * blockDim.x + threadIdx.x;
    long stride = (long)gridDim.x * blockDim.x;
    for (; t < n; t += stride) p[t] = v;
}

// ---------------------------------------------------------------------------
// Weight prep: f32 W[K][M] -> f16 hi/lo in LDS-tile order:
// dst = mat + kt*(M*32) + (n>>7)*4096 + p*8 + (k&7),
// p = ((n&127)>>4)*64 + ((k>>3)&3)*16 + (n&15).  (tile = 8KB, DMA-linear)
// ---------------------------------------------------------------------------
__global__ void prep_w(const float* __restrict__ s0, const float* __restrict__ s1,
                       const float* __restrict__ s2, const float* __restrict__ s3,
                       const float* __restrict__ s4, const float* __restrict__ s5,
                       ushort_t* __restrict__ hi, ushort_t* __restrict__ lo)
{
    long gid = (long)blockIdx.x * 256 + threadIdx.x;
    const float* src; int K, M; long base, loc;
    if      (gid < 524288)  { src=s0; K=256; M=512; base=0;       loc=gid; }
    else if (gid < 1048576) { src=s1; K=512; M=256; base=524288;  loc=gid-524288; }
    else if (gid < 1572864) { src=s2; K=256; M=512; base=1048576; loc=gid-1048576; }
    else if (gid < 2097152) { src=s3; K=512; M=256; base=1572864; loc=gid-1572864; }
    else if (gid < 2359296) { src=s4; K=256; M=256; base=2097152; loc=gid-2097152; }
    else if (gid < 2621440) { src=s5; K=256; M=256; base=2359296; loc=gid-2359296; }
    else return;
    long msz = (long)K * M;
    int  mat = (int)(loc / msz); long rem = loc - (long)mat * msz;
    int  k = (int)(rem / M);     int  n = (int)(rem - (long)k * M);
    float v = src[loc];
    ushort_t hu = f2h(v);
    ushort_t lu = f2h(v - h2f(hu));
    int nl = n & 127, g = (k >> 3) & 3;
    long p = (long)((nl >> 4) * 64 + g * 16 + (nl & 15));
    long dst = base + (long)mat * msz + (long)(k >> 5) * ((long)M << 5)
             + ((long)(n >> 7) << 12) + (p << 3) + (k & 7);
    hi[dst] = hu;
    if (lo) lo[dst] = lu;
}

// ---------------------------------------------------------------------------
// MFMA f16 GEMM, m97-style staging: global_load_lds(16B) for A and W hi/lo,
// conflict-free LDS layout p=(m>>4)*64+g*16+(m&15) (A via permuted global src,
// W pre-swizzled by prep_w). BN-affine+relu of A applied on fragments (pk f16).
// 128x128 tile, 4 waves (2x2), 4x4 16x16x32 frags/wave.
// ---------------------------------------------------------------------------
template<int RELU>
__global__ __launch_bounds__(256)
void mfma_gemm(PanelsIn Ap, int astride, const ushort_t* __restrict__ Wh,
               const ushort_t* __restrict__ Wl, const float* __restrict__ bias,
               PanelsOut Cp, int cstride, const float* __restrict__ Aff,
               float* __restrict__ cstatR, int N, int K, int M)
{
    __shared__ ushort_t Asm[4096];   // 8KB A tile
    __shared__ ushort_t Bhs[4096];
    __shared__ ushort_t Bls[4096];
    __shared__ ushort_t AffS[1024];  // f16 sc[K] | sb[K] at +512
    const int tid = threadIdx.x;
    const int brow = blockIdx.y * 128, bcol = blockIdx.x * 128;
    const int wid = tid >> 6, lane = tid & 63;
    const int wm = wid >> 1, wn = wid & 1;
    const int lg = lane >> 4, lr = lane & 15;

    if (Aff) {
        for (int c = tid; c < K; c += 256) {
            AffS[c]       = f2h(Aff[c]);
            AffS[512 + c] = f2h(Aff[K + c]);
        }
        __syncthreads();
    }

    // staging lane mapping: lane l loads the element for LDS uint4 pos w*64+l
    const int mA = lane & 15;            // + (r*4+wid)*16
    const int gA = (lane >> 4) & 3;      // k-chunk

    floatx4 acc[4][4];
    #pragma unroll
    for (int i = 0; i < 4; ++i)
        #pragma unroll
        for (int j = 0; j < 4; ++j) acc[i][j] = (floatx4){0.f, 0.f, 0.f, 0.f};

    const int nkt = K >> 5;
    for (int kt = 0; kt < nkt; ++kt) {
        if (kt) __syncthreads();
        // ---- A stage (2 rounds of 64 rows) ----
        const ushort_t* pa = Ap.p[kt >> 2];
        const ushort_t* ga = pa + (long)(brow + wid * 16 + mA) * astride
                                + ((kt & 3) << 5) + gA * 8;
        load_lds16(ga, Asm + wid * 512);
        load_lds16(ga + (long)64 * astride, Asm + 2048 + wid * 512);
        // ---- W stage (linear: prep_w pre-swizzled) ----
        const ushort_t* gb = Wh + (size_t)kt * ((size_t)M << 5)
                                + ((size_t)bcol << 5) + (wid * 64 + lane) * 8;
        load_lds16(gb, Bhs + wid * 512);
        load_lds16(gb + 2048, Bhs + 2048 + wid * 512);
        if (Wl) {
            const ushort_t* gl = Wl + (size_t)kt * ((size_t)M << 5)
                                    + ((size_t)bcol << 5) + (wid * 64 + lane) * 8;
            load_lds16(gl, Bls + wid * 512);
            load_lds16(gl + 2048, Bls + 2048 + wid * 512);
        }
        __syncthreads();   // drains vmcnt before barrier

        half8_t af[4], bh[4], bl[4];
        #pragma unroll
        for (int i = 0; i < 4; ++i)
            af[i] = *(const half8_t*)(Asm + (((wm * 4 + i) * 64 + lg * 16 + lr) << 3));
        if (Aff) {
            half8_t scv = *(const half8_t*)(AffS + (kt << 5) + lg * 8);
            half8_t sbv = *(const half8_t*)(AffS + 512 + (kt << 5) + lg * 8);
            #pragma unroll
            for (int i = 0; i < 4; ++i) {
                half8_t z = af[i] * scv + sbv;
                #pragma unroll
                for (int e = 0; e < 8; ++e)
                    z[e] = z[e] > (_Float16)0 ? z[e] : (_Float16)0;
                af[i] = z;
            }
        }
        #pragma unroll
        for (int j = 0; j < 4; ++j) {
            bh[j] = *(const half8_t*)(Bhs + (((wn * 4 + j) * 64 + lg * 16 + lr) << 3));
            if (Wl)
                bl[j] = *(const half8_t*)(Bls + (((wn * 4 + j) * 64 + lg * 16 + lr) << 3));
        }
        #pragma unroll
        for (int i = 0; i < 4; ++i)
            #pragma unroll
            for (int j = 0; j < 4; ++j) {
                acc[i][j] = __builtin_amdgcn_mfma_f32_16x16x32_f16(af[i], bh[j], acc[i][j], 0, 0, 0);
                if (Wl)
                    acc[i][j] = __builtin_amdgcn_mfma_f32_16x16x32_f16(af[i], bl[j], acc[i][j], 0, 0, 0);
            }
    }

    ushort_t* cb = Cp.p[blockIdx.x];
    float csl[4], cql[4];
    #pragma unroll
    for (int j = 0; j < 4; ++j) { csl[j] = 0.f; cql[j] = 0.f; }
    #pragma unroll
    for (int j = 0; j < 4; ++j) {
        int lcol = wn * 64 + j * 16 + lr;
        float bia = bias[bcol + lcol];
        #pragma unroll
        for (int i = 0; i < 4; ++i) {
            #pragma unroll
            for (int r = 0; r < 4; ++r) {
                int row = brow + wm * 64 + i * 16 + (lg << 2) + r;
                float v = acc[i][j][r] + bia;
                if (RELU) v = fmaxf(v, 0.f);
                ushort_t uo = f2h(v);
                cb[(long)row * cstride + lcol] = uo;
                if (cstatR) {
                    float vq = h2f(uo);
                    csl[j] += vq; cql[j] = fmaf(vq, vq, cql[j]);
                }
            }
        }
    }
    if (cstatR) {
        __syncthreads();
        float* cs = (float*)Asm;
        float* cq = (float*)Bhs;
        if (tid < 128) { cs[tid] = 0.f; cq[tid] = 0.f; }
        __syncthreads();
        #pragma unroll
        for (int j = 0; j < 4; ++j) {
            int cl = wn * 64 + j * 16 + lr;
            atomicAdd(&cs[cl], csl[j]);
            atomicAdd(&cq[cl], cql[j]);
        }
        __syncthreads();
        if (tid < 128) {
            int rep = blockIdx.y & (NREP - 1);
            atomicAdd(&cstatR[(long)rep * 2 * M + bcol + tid], cs[tid]);
            atomicAdd(&cstatR[(long)rep * 2 * M + M + bcol + tid], cq[tid]);
        }
    }
}

// aff[c] = sa, aff[M+c] = sb from replicated stats + BN params
__global__ void finalize_aff(const float* __restrict__ cstatR, int M, float invN,
                             const float* __restrict__ g, const float* __restrict__ b,
                             float* __restrict__ aff)
{
    int c = blockIdx.x * blockDim.x + threadIdx.x;
    if (c >= M) return;
    float s = 0.f, q = 0.f;
    for (int r = 0; r < NREP; ++r) {
        s += cstatR[(long)r * 2 * M + c];
        q += cstatR[(long)r * 2 * M + M + c];
    }
    float m = s * invN, var = q * invN - m * m;
    float sa = rsqrtf(var + 1e-5f) * g[c];
    aff[c] = sa; aff[M + c] = b[c] - m * sa;
}

// ---------------------------------------------------------------------------
// CSR aggregation (one wave per node, grid-stride).
// ---------------------------------------------------------------------------
template<int EB>
__global__ __launch_bounds__(256)
void csr_agg(const ushort_t* __restrict__ in, ushort_t* __restrict__ out,
             const int* __restrict__ offs, const int* __restrict__ elist,
             const int* __restrict__ esrc, const float* __restrict__ eattr,
             const float* __restrict__ Wb, const float* __restrict__ bb,
             const float* __restrict__ eps_p, int n_nodes)
{
    __shared__ float Ws[EB ? 4096 : 1];
    __shared__ float bs[EB ? 256 : 1];
    if (EB) {
        for (int i = threadIdx.x; i < 4096; i += 256) Ws[i] = Wb[i];
        bs[threadIdx.x] = bb[threadIdx.x];
        __syncthreads();
    }
    float epsv = 1.f + eps_p[0];
    int lane = threadIdx.x & 63;
    int gw = (blockIdx.x * 256 + threadIdx.x) >> 6;
    int nw = (gridDim.x * 256) >> 6;
    for (int u = gw; u < n_nodes; u += nw) {
        const ushort_t* own = in + (long)u * 256;
        float acc[4];
        #pragma unroll
        for (int j = 0; j < 4; ++j) acc[j] = epsv * h2f(own[lane + 64 * j]);
        int s = offs[u], e = offs[u + 1];
        for (int i = s; i < e; ++i) {
            int eid = elist[i];
            int sid = esrc[eid];
            const ushort_t* row = in + (long)sid * 256;
            if (EB) {
                float ev[16];
                const float4* ea = (const float4*)(eattr + (long)eid * 16);
                float4 e0 = ea[0], e1 = ea[1], e2 = ea[2], e3 = ea[3];
                ev[0]=e0.x; ev[1]=e0.y; ev[2]=e0.z; ev[3]=e0.w;
                ev[4]=e1.x; ev[5]=e1.y; ev[6]=e1.z; ev[7]=e1.w;
                ev[8]=e2.x; ev[9]=e2.y; ev[10]=e2.z; ev[11]=e2.w;
                ev[12]=e3.x; ev[13]=e3.y; ev[14]=e3.z; ev[15]=e3.w;
                #pragma unroll
                for (int j = 0; j < 4; ++j) {
                    int c = lane + 64 * j;
                    float m = bs[c];
                    #pragma unroll
                    for (int k = 0; k < 16; ++k) m = fmaf(ev[k], Ws[k * 256 + c], m);
                    acc[j] += fmaxf(h2f(row[c]) + m, 0.f);
                }
            } else {
                #pragma unroll
                for (int j = 0; j < 4; ++j) acc[j] += h2f(row[lane + 64 * j]);
            }
        }
        ushort_t* o = out + (long)u * 256;
        #pragma unroll
        for (int j = 0; j < 4; ++j) o[lane + 64 * j] = f2h(acc[j]);
    }
}

// out[u] = relu(aff(raw[u])) + mean_{i in csr[u]} U[midx[elist[i]]]   (256 ch)
__global__ __launch_bounds__(128)
void csr_mean_aff(const ushort_t* __restrict__ raw, const ushort_t* __restrict__ U,
                  const int* __restrict__ midx, const int* __restrict__ elist,
                  const int* __restrict__ offs, const float* __restrict__ Aff,
                  ushort_t* __restrict__ outp)
{
    int u = blockIdx.x, t = threadIdx.x;
    int c0 = t * 2;
    float sa0 = Aff[c0], sa1 = Aff[c0 + 1], sb0 = Aff[256 + c0], sb1 = Aff[256 + c0 + 1];
    ushort2 b = *(const ushort2*)(raw + (long)u * 256 + c0);
    float x0 = fmaxf(h2f(b.x) * sa0 + sb0, 0.f);
    float x1 = fmaxf(h2f(b.y) * sa1 + sb1, 0.f);
    int s = offs[u], e = offs[u + 1];
    float a0 = 0.f, a1 = 0.f;
    for (int i = s; i < e; ++i) {
        long r = midx[elist[i]];
        ushort2 v = *(const ushort2*)(U + r * 256 + c0);
        a0 += h2f(v.x); a1 += h2f(v.y);
    }
    if (e > s) { float inv = 1.f / (float)(e - s); x0 += a0 * inv; x1 += a1 * inv; }
    ushort2 o; o.x = f2h(x0); o.y = f2h(x1);
    *(ushort2*)(outp + (long)u * 256 + c0) = o;
}

// ---------------------------------------------------------------------------
// fp32 GEMM for encoders/readout (small).
// ---------------------------------------------------------------------------
template<int RELU, typename TC>
__global__ __launch_bounds__(256)
void gemm_k(const float* __restrict__ A, const float* __restrict__ W,
            const float* __restrict__ bias, TC* __restrict__ C,
            int N, int K, int M)
{
    const int BK = 16, LDA = 132;
    __shared__ float As[BK * LDA];
    __shared__ float Bs[BK * LDA];
    const int brow = blockIdx.y * 128;
    const int bcol = blockIdx.x * 128;
    const int tid  = threadIdx.x;
    const int tr = tid >> 4, tc = tid & 15;

    float acc[8][8];
    #pragma unroll
    for (int i = 0; i < 8; ++i)
        #pragma unroll
        for (int j = 0; j < 8; ++j) acc[i][j] = 0.f;

    for (int k0 = 0; k0 < K; k0 += BK) {
        #pragma unroll
        for (int u = 0; u < 8; ++u) {
            int idx = tid + u * 256;
            int m = idx >> 4, kk = idx & 15;
            As[kk * LDA + m] = A[(long)(brow + m) * K + k0 + kk];
        }
        #pragma unroll
        for (int u = 0; u < 8; ++u) {
            int idx = tid + u * 256;
            int kk = idx >> 7, n = idx & 127;
            int col = bcol + n;
            Bs[kk * LDA + n] = (col < M) ? W[(long)(k0 + kk) * M + col] : 0.f;
        }
        __syncthreads();
        #pragma unroll
        for (int kk = 0; kk < BK; ++kk) {
            float av[8], bv[8];
            float4 a0 = *(const float4*)&As[kk * LDA + tr * 8];
            float4 a1 = *(const float4*)&As[kk * LDA + tr * 8 + 4];
            float4 b0 = *(const float4*)&Bs[kk * LDA + tc * 8];
            float4 b1 = *(const float4*)&Bs[kk * LDA + tc * 8 + 4];
            av[0]=a0.x; av[1]=a0.y; av[2]=a0.z; av[3]=a0.w;
            av[4]=a1.x; av[5]=a1.y; av[6]=a1.z; av[7]=a1.w;
            bv[0]=b0.x; bv[1]=b0.y; bv[2]=b0.z; bv[3]=b0.w;
            bv[4]=b1.x; bv[5]=b1.y; bv[6]=b1.z; bv[7]=b1.w;
            #pragma unroll
            for (int i = 0; i < 8; ++i)
                #pragma unroll
                for (int j = 0; j < 8; ++j)
                    acc[i][j] = fmaf(av[i], bv[j], acc[i][j]);
        }
        __syncthreads();
    }
    #pragma unroll
    for (int i = 0; i < 8; ++i) {
        int row = brow + tr * 8 + i;
        #pragma unroll
        for (int j = 0; j < 8; ++j) {
            int col = bcol + tc * 8 + j;
            if (col < M) {
                float v = acc[i][j] + bias[col];
                if (RELU) v = fmaxf(v, 0.f);
                if constexpr (sizeof(TC) == 2) ((ushort_t*)C)[(long)row * M + col] = f2h(v);
                else                           ((float*)C)[(long)row * M + col] = v;
            }
        }
    }
}

__global__ void count_idx(const int* __restrict__ idx, int n, int* __restrict__ cnt)
{
    int i = blockIdx.x * blockDim.x + threadIdx.x;
    if (i < n) atomicAdd(&cnt[idx[i]], 1);
}

// ---- parallel exclusive scan (3 phases) ----
__global__ __launch_bounds__(256)
void scan_p1(const int* __restrict__ cnt, int n, int* __restrict__ partials)
{
    __shared__ int sd[256];
    int i = blockIdx.x * 256 + threadIdx.x;
    sd[threadIdx.x] = (i < n) ? cnt[i] : 0;
    __syncthreads();
    #pragma unroll
    for (int s = 128; s > 0; s >>= 1) {
        if (threadIdx.x < s) sd[threadIdx.x] += sd[threadIdx.x + s];
        __syncthreads();
    }
    if (threadIdx.x == 0) partials[blockIdx.x] = sd[0];
}

__global__ __launch_bounds__(1024)
void scan_p2(int* __restrict__ partials, int nb, int* __restrict__ off, int n)
{
    __shared__ int sd[1024];
    int t = threadIdx.x;
    int v = (t < nb) ? partials[t] : 0;
    sd[t] = v;
    __syncthreads();
    for (int d = 1; d < 1024; d <<= 1) {
        int x = (t >= d) ? sd[t - d] : 0;
        __syncthreads();
        sd[t] += x;
        __syncthreads();
    }
    if (t < nb) partials[t] = sd[t] - v;
    if (t == 1023) off[n] = sd[nb - 1];
}

__global__ __launch_bounds__(256)
void scan_p3(const int* __restrict__ cnt, int n, const int* __restrict__ partials,
             int* __restrict__ off, int* __restrict__ cursor)
{
    __shared__ int sd[256];
    int i = blockIdx.x * 256 + threadIdx.x;
    int v = (i < n) ? cnt[i] : 0;
    sd[threadIdx.x] = v;
    __syncthreads();
    for (int d = 1; d < 256; d <<= 1) {
        int x = (threadIdx.x >= d) ? sd[threadIdx.x - d] : 0;
        __syncthreads();
        sd[threadIdx.x] += x;
        __syncthreads();
    }
    if (i < n) {
        int e = partials[blockIdx.x] + sd[threadIdx.x] - v;
        off[i] = e; cursor[i] = e;
    }
}

__global__ void csr_fill(const int* __restrict__ idx, int n,
                         int* __restrict__ cursor, int* __restrict__ elist)
{
    int i = blockIdx.x * blockDim.x + threadIdx.x;
    if (i < n) { int p = atomicAdd(&cursor[idx[i]], 1); elist[p] = i; }
}

__global__ __launch_bounds__(256)
void seg_pool(const ushort_t* __restrict__ X, const int* __restrict__ bidx,
              int nrows, float* __restrict__ pooled)
{
    int b = blockIdx.x, t = threadIdx.x;
    int lo = 0, hi = nrows;
    while (lo < hi) { int mid = (lo + hi) >> 1; if (bidx[mid] < b) lo = mid + 1; else hi = mid; }
    int s = lo; hi = nrows;
    while (lo < hi) { int mid = (lo + hi) >> 1; if (bidx[mid] < b + 1) lo = mid + 1; else hi = mid; }
    int e = lo;
    float acc = 0.f;
    for (int r = s; r < e; ++r) acc += h2f(X[(long)r * 256 + t]);
    pooled[(long)b * 256 + t] = acc / fmaxf((float)(e - s), 1.f);
}

__global__ void vadd(float* __restrict__ out, const float* __restrict__ in, long n4)
{
    long t = (long)blockIdx.x * blockDim.x + threadIdx.x;
    if (t >= n4) return;
    float4 a = ((float4*)out)[t];
    float4 b = ((const float4*)in)[t];
    a.x += b.x; a.y += b.y; a.z += b.z; a.w += b.w;
    ((float4*)out)[t] = a;
}

// ---------------------------------------------------------------------------
extern "C" void kernel_launch(void* const* d_in, const int* in_sizes, int n_in,
                              void* d_out, int out_size, void* d_ws, size_t ws_size,
                              hipStream_t stream)
{
    (void)in_sizes; (void)n_in;
    const float* x          = (const float*)d_in[0];
    const float* fragments  = (const float*)d_in[1];
    const float* edge_attr  = (const float*)d_in[2];
    const float* atom_enc_W = (const float*)d_in[3];
    const float* atom_enc_b = (const float*)d_in[4];
    const float* frag_enc_W = (const float*)d_in[5];
    const float* frag_enc_b = (const float*)d_in[6];
    const float* bond_W     = (const float*)d_in[7];
    const float* bond_b     = (const float*)d_in[8];
    const float* gine_eps   = (const float*)d_in[9];
    const float* gine_W1    = (const float*)d_in[10];
    const float* gine_b1    = (const float*)d_in[11];
    const float* gine_bn_g  = (const float*)d_in[12];
    const float* gine_bn_b  = (const float*)d_in[13];
    const float* gine_W2    = (const float*)d_in[14];
    const float* gine_b2    = (const float*)d_in[15];
    const float* atom_bn_g  = (const float*)d_in[16];
    const float* atom_bn_b  = (const float*)d_in[17];
    const float* gin_eps    = (const float*)d_in[18];
    const float* gin_W1     = (const float*)d_in[19];
    const float* gin_b1     = (const float*)d_in[20];
    const float* gin_bn_g   = (const float*)d_in[21];
    const float* gin_bn_b   = (const float*)d_in[22];
    const float* gin_W2     = (const float*)d_in[23];
    const float* gin_b2     = (const float*)d_in[24];
    const float* frag_bn_g  = (const float*)d_in[25];
    const float* frag_bn_b  = (const float*)d_in[26];
    const float* a2f_W      = (const float*)d_in[27];
    const float* a2f_b      = (const float*)d_in[28];
    const float* f2a_W      = (const float*)d_in[29];
    const float* f2a_b      = (const float*)d_in[30];
    const float* fo_W1      = (const float*)d_in[31];
    const float* fo_b1      = (const float*)d_in[32];
    const float* fo_W2      = (const float*)d_in[33];
    const float* fo_b2      = (const float*)d_in[34];
    const float* ao_W1      = (const float*)d_in[35];
    const float* ao_b1      = (const float*)d_in[36];
    const float* ao_W2      = (const float*)d_in[37];
    const float* ao_b2      = (const float*)d_in[38];
    const float* out_W1     = (const float*)d_in[39];
    const float* out_b1     = (const float*)d_in[40];
    const float* out_W2     = (const float*)d_in[41];
    const float* out_b2     = (const float*)d_in[42];
    const int* edge_index   = (const int*)d_in[43];
    const int* fedge_index  = (const int*)d_in[44];
    const int* batch        = (const int*)d_in[45];
    const int* fbatch       = (const int*)d_in[46];
    const int* mem_atom     = (const int*)d_in[47];
    const int* mem_frag     = (const int*)d_in[48];

    const int* src  = edge_index;
    const int* dst  = edge_index + N_EDGE;
    const int* fsrc = fedge_index;
    const int* fdst = fedge_index + N_FEDGE;

    // ---- arena ----
    size_t off = 0;
    auto take = [&](size_t b) -> size_t { size_t p = off; off = (off + b + 255) & ~(size_t)255; return p; };
    size_t o_big   = take((size_t)N_ATOM * 512 * 2);     // 134 MB
    size_t o_a     = take((size_t)N_ATOM * H * 2);       // 67 MB
    size_t o_f     = take((size_t)N_FRAG * H * 2);
    size_t o_f2    = take((size_t)N_FRAG * H * 2);
    size_t o_offea = take((size_t)(N_ATOM + 1) * 4);
    size_t o_elea  = take((size_t)N_EDGE * 4);
    size_t o_offef = take((size_t)(N_FRAG + 1) * 4);
    size_t o_elef  = take((size_t)N_FEDGE * 4);
    size_t o_offma = take((size_t)(N_ATOM + 1) * 4);
    size_t o_elma  = take((size_t)N_MEM * 4);
    size_t o_offmf = take((size_t)(N_FRAG + 1) * 4);
    size_t o_elmf  = take((size_t)N_MEM * 4);
    size_t o_cnta  = take((size_t)N_ATOM * 4);
    size_t o_cntf  = take((size_t)N_FRAG * 4);
    size_t o_part  = take(1024 * 4);
    size_t o_stats = take((size_t)NREP * 3072 * 4);
    size_t o_aff   = take(3072 * 4);
    size_t o_hi    = take((size_t)2621440 * 2);
    size_t need_nolo = off;
    size_t o_lo    = take((size_t)2621440 * 2);
    size_t need_full = off;

    bool use_lo = (need_full <= ws_size);
    if (!use_lo && need_nolo > ws_size) {
        fill_const<<<64, 256, 0, stream>>>((float*)d_out, out_size,
                                           (float)((double)ws_size / 1024.0));
        return;
    }
    char* base = (char*)d_ws;
    char*     big     = base + o_big;
    ushort_t* a       = (ushort_t*)(base + o_a);
    ushort_t* f       = (ushort_t*)(base + o_f);
    ushort_t* f2      = (ushort_t*)(base + o_f2);
    int* off_ea = (int*)(base + o_offea);
    int* el_ea  = (int*)(base + o_elea);
    int* off_ef = (int*)(base + o_offef);
    int* el_ef  = (int*)(base + o_elef);
    int* off_ma = (int*)(base + o_offma);
    int* el_ma  = (int*)(base + o_elma);
    int* off_mf = (int*)(base + o_offmf);
    int* el_mf  = (int*)(base + o_elmf);
    int* cnt_a  = (int*)(base + o_cnta);
    int* cnt_f  = (int*)(base + o_cntf);
    int* parts  = (int*)(base + o_part);
    float* statsR = (float*)(base + o_stats);
    float* affs   = (float*)(base + o_aff);
    ushort_t* Wp_hi = (ushort_t*)(base + o_hi);
    ushort_t* Wp_lo = use_lo ? (ushort_t*)(base + o_lo) : nullptr;

    float* cst1a = statsR;
    float* cst2a = statsR + (size_t)NREP * 1024;
    float* cst1f = statsR + (size_t)NREP * 1536;
    float* cst2f = statsR + (size_t)NREP * 2560;
    float* aff1_a = affs;
    float* aff2_a = affs + 1024;
    float* aff1_f = affs + 1536;
    float* aff2_f = affs + 2560;

    ushort_t* big_u = (ushort_t*)big;
    const size_t HALF_U = (size_t)N_ATOM * 256;
    ushort_t* ha  = big_u + HALF_U;
    const size_t PAN_A = (size_t)N_ATOM * 128;
    const size_t PAN_F = (size_t)N_FRAG * 128;
    ushort_t* Ua = big_u;
    float* pooled_f = (float*)big;
    float* pooled_a = (float*)(big + (size_t)8 * 1024 * 1024);
    float* tmp      = (float*)(big + (size_t)16 * 1024 * 1024);

    const long WG0 = 0, WG1 = 524288, WG2 = 1048576, WG3 = 1572864,
               WG4 = 2097152, WG5 = 2359296;

    auto build_csr = [&](const int* idx, int n_edges, int n_nodes,
                         int* cnt, int* offs, int* elist) {
        hipMemsetAsync(cnt, 0, (size_t)n_nodes * 4, stream);
        count_idx<<<CDIV(n_edges,256),256,0,stream>>>(idx, n_edges, cnt);
        int nb = CDIV(n_nodes, 256);
        scan_p1<<<nb, 256, 0, stream>>>(cnt, n_nodes, parts);
        scan_p2<<<1, 1024, 0, stream>>>(parts, nb, offs, n_nodes);
        scan_p3<<<nb, 256, 0, stream>>>(cnt, n_nodes, parts, offs, cnt);
        csr_fill<<<CDIV(n_edges,256),256,0,stream>>>(idx, n_edges, cnt, elist);
    };

    // ---- weight prep + CSR builds ----
    prep_w<<<CDIV(2621440L, 256), 256, 0, stream>>>(gine_W1, gine_W2, gin_W1, gin_W2,
                                                    a2f_W, f2a_W, Wp_hi, Wp_lo);
    build_csr(dst,      N_EDGE,  N_ATOM, cnt_a, off_ea, el_ea);
    build_csr(fdst,     N_FEDGE, N_FRAG, cnt_f, off_ef, el_ef);
    build_csr(mem_atom, N_MEM,   N_ATOM, cnt_a, off_ma, el_ma);
    build_csr(mem_frag, N_MEM,   N_FRAG, cnt_f, off_mf, el_mf);

    // ---- encoders ----
    gemm_k<0,ushort_t><<<dim3(2, N_ATOM/128), 256, 0, stream>>>(
        x, atom_enc_W, atom_enc_b, a, N_ATOM, 64, H);
    gemm_k<0,ushort_t><<<dim3(2, N_FRAG/128), 256, 0, stream>>>(
        fragments, frag_enc_W, frag_enc_b, f, N_FRAG, 32, H);

    const float invNA = 1.f / N_ATOM, invNF = 1.f / N_FRAG;

    for (int l = 0; l < 4; ++l) {
        hipMemsetAsync(statsR, 0, (size_t)NREP * 3072 * 4, stream);

        // ===== atoms: GINE + MLP =====
        csr_agg<1><<<2048, 256, 0, stream>>>(a, ha, off_ea, el_ea, src, edge_attr,
            bond_W + (long)l*16*H, bond_b + l*H, gine_eps + l, N_ATOM);

        PanelsIn A1in; PanelsOut A1out;
        for (int i = 0; i < 4; ++i) A1in.p[i] = ha + i * 128;
        A1out.p[0] = a;          A1out.p[1] = a + PAN_A;
        A1out.p[2] = big_u;      A1out.p[3] = big_u + PAN_A;
        mfma_gemm<0><<<dim3(4, N_ATOM/128), 256, 0, stream>>>(
            A1in, 256, Wp_hi + WG0 + (long)l*131072,
            Wp_lo ? Wp_lo + WG0 + (long)l*131072 : nullptr,
            gine_b1 + l*512, A1out, 128, nullptr, cst1a, N_ATOM, 256, 512);
        finalize_aff<<<2, 256, 0, stream>>>(cst1a, 512, invNA,
            gine_bn_g + l*512, gine_bn_b + l*512, aff1_a);

        PanelsIn A2in; PanelsOut A2out;
        A2in.p[0] = a;       A2in.p[1] = a + PAN_A;
        A2in.p[2] = big_u;   A2in.p[3] = big_u + PAN_A;
        A2out.p[0] = ha; A2out.p[1] = ha + 128; A2out.p[2] = ha; A2out.p[3] = ha;
        mfma_gemm<0><<<dim3(2, N_ATOM/128), 256, 0, stream>>>(
            A2in, 128, Wp_hi + WG1 + (long)l*131072,
            Wp_lo ? Wp_lo + WG1 + (long)l*131072 : nullptr,
            gine_b2 + l*H, A2out, 256, aff1_a, cst2a, N_ATOM, 512, 256);
        finalize_aff<<<1, 256, 0, stream>>>(cst2a, 256, invNA,
            atom_bn_g + l*H, atom_bn_b + l*H, aff2_a);

        // ===== fragments: GIN + MLP =====
        csr_agg<0><<<512, 256, 0, stream>>>(f, f2, off_ef, el_ef, fsrc, nullptr,
            nullptr, nullptr, gin_eps + l, N_FRAG);

        PanelsIn F1in; PanelsOut F1out;
        for (int i = 0; i < 4; ++i) F1in.p[i] = f2 + i * 128;
        for (int i = 0; i < 4; ++i) F1out.p[i] = big_u + i * PAN_F;
        mfma_gemm<0><<<dim3(4, N_FRAG/128), 256, 0, stream>>>(
            F1in, 256, Wp_hi + WG2 + (long)l*131072,
            Wp_lo ? Wp_lo + WG2 + (long)l*131072 : nullptr,
            gin_b1 + l*512, F1out, 128, nullptr, cst1f, N_FRAG, 256, 512);
        finalize_aff<<<2, 256, 0, stream>>>(cst1f, 512, invNF,
            gin_bn_g + l*512, gin_bn_b + l*512, aff1_f);

        PanelsIn F2in; PanelsOut F2out;
        for (int i = 0; i < 4; ++i) F2in.p[i] = big_u + i * PAN_F;
        F2out.p[0] = f2; F2out.p[1] = f2 + 128; F2out.p[2] = f2; F2out.p[3] = f2;
        mfma_gemm<0><<<dim3(2, N_FRAG/128), 256, 0, stream>>>(
            F2in, 128, Wp_hi + WG3 + (long)l*131072,
            Wp_lo ? Wp_lo + WG3 + (long)l*131072 : nullptr,
            gin_b2 + l*H, F2out, 256, aff1_f, cst2f, N_FRAG, 512, 256);
        finalize_aff<<<1, 256, 0, stream>>>(cst2f, 256, invNF,
            frag_bn_g + l*H, frag_bn_b + l*H, aff2_f);

        // ===== inter MP =====
        PanelsIn UAin; PanelsOut UAout;
        for (int i = 0; i < 4; ++i) UAin.p[i] = ha + i * 128;
        UAout.p[0] = Ua; UAout.p[1] = Ua + 128; UAout.p[2] = Ua; UAout.p[3] = Ua;
        mfma_gemm<1><<<dim3(2, N_ATOM/128), 256, 0, stream>>>(
            UAin, 256, Wp_hi + WG4 + (long)l*65536,
            Wp_lo ? Wp_lo + WG4 + (long)l*65536 : nullptr,
            a2f_b + l*H, UAout, 256, aff2_a, nullptr, N_ATOM, 256, 256);
        csr_mean_aff<<<N_FRAG, 128, 0, stream>>>(f2, Ua, mem_atom, el_mf, off_mf,
                                                 aff2_f, f);
        PanelsIn UFin; PanelsOut UFout;
        for (int i = 0; i < 4; ++i) UFin.p[i] = f + i * 128;
        UFout.p[0] = f2; UFout.p[1] = f2 + 128; UFout.p[2] = f2; UFout.p[3] = f2;
        mfma_gemm<1><<<dim3(2, N_FRAG/128), 256, 0, stream>>>(
            UFin, 256, Wp_hi + WG5 + (long)l*65536,
            Wp_lo ? Wp_lo + WG5 + (long)l*65536 : nullptr,
            f2a_b + l*H, UFout, 256, nullptr, nullptr, N_FRAG, 256, 256);
        csr_mean_aff<<<N_ATOM, 128, 0, stream>>>(ha, f2, mem_frag, el_ma, off_ma,
                                                 aff2_a, a);
    }

    // ===== readout =====
    seg_pool<<<BATCH, 256, 0, stream>>>(f, fbatch, N_FRAG, pooled_f);
    gemm_k<1,float><<<dim3(2, BATCH/128), 256, 0, stream>>>(
        pooled_f, fo_W1, fo_b1, tmp, BATCH, H, H);
    gemm_k<1,float><<<dim3(2, BATCH/128), 256, 0, stream>>>(
        tmp, fo_W2, fo_b2, pooled_f, BATCH, H, H);

    seg_pool<<<BATCH, 256, 0, stream>>>(a, batch, N_ATOM, pooled_a);
    gemm_k<1,float><<<dim3(2, BATCH/128), 256, 0, stream>>>(
        pooled_a, ao_W1, ao_b1, tmp, BATCH, H, H);
    gemm_k<1,float><<<dim3(2, BATCH/128), 256, 0, stream>>>(
        tmp, ao_W2, ao_b2, pooled_a, BATCH, H, H);

    vadd<<<(int)CDIV((long)BATCH*H/4,256), 256, 0, stream>>>(
        pooled_a, pooled_f, (long)BATCH * H / 4);
    gemm_k<1,float><<<dim3(2, BATCH/128), 256, 0, stream>>>(
        pooled_a, out_W1, out_b1, tmp, BATCH, H, H);
    gemm_k<0,float><<<dim3(1, BATCH/128), 256, 0, stream>>>(
        tmp, out_W2, out_b2, (float*)d_out, BATCH, H, 1);
}

// Round 9
// 3474.677 us; speedup vs baseline: 7.6948x; 1.0470x over previous
//
#include <hip/hip_runtime.h>

#define CDIV(a,b) (((a)+(b)-1)/(b))

static const int N_ATOM = 131072, N_FRAG = 32768, N_EDGE = 262144,
                 N_FEDGE = 65536, N_MEM = 196608, BATCH = 4096, H = 256;
static const int NREP = 16;   // stat atomic replicas

typedef unsigned short ushort_t;
typedef _Float16 half8_t __attribute__((ext_vector_type(8)));
typedef float    floatx4 __attribute__((ext_vector_type(4)));

struct PanelsIn  { const ushort_t* p[4]; };
struct PanelsOut { ushort_t* p[4]; };

__device__ __forceinline__ float h2f(ushort_t u) {
    _Float16 h; __builtin_memcpy(&h, &u, 2); return (float)h;
}
__device__ __forceinline__ ushort_t f2h(float f) {
    _Float16 h = (_Float16)f; ushort_t u; __builtin_memcpy(&u, &h, 2); return u;
}

// async global->LDS, 16B per lane. lds base must be wave-uniform; HW adds lane*16.
__device__ __forceinline__ void load_lds16(const ushort_t* g, ushort_t* l) {
    __builtin_amdgcn_global_load_lds(
        (const __attribute__((address_space(1))) unsigned int*)g,
        (__attribute__((address_space(3))) unsigned int*)l, 16, 0, 0);
}

__global__ void fill_const(float* p, long n, float v) {
    long t = (long)blockIdx.x * blockDim.x + threadIdx.x;
    long stride = (long)gridDim.x * blockDim.x;
    for (; t < n; t += stride) p[t] = v;
}

// f32 -> f16 bulk convert (n % 4 == 0)
__global__ void conv_f2h(const float* __restrict__ in, ushort_t* __restrict__ out, long n)
{
    long t = (long)blockIdx.x * 256 + threadIdx.x;
    long stride = (long)gridDim.x * 256;
    for (long i = t; i < n / 4; i += stride) {
        float4 v = ((const float4*)in)[i];
        ushort4 o; o.x = f2h(v.x); o.y = f2h(v.y); o.z = f2h(v.z); o.w = f2h(v.w);
        ((ushort4*)out)[i] = o;
    }
}

// ---------------------------------------------------------------------------
// Weight prep: f32 W[K][M] -> f16 hi/lo in LDS-tile order:
// dst = mat + kt*(M*32) + (n>>7)*4096 + p*8 + (k&7),
// p = ((n&127)>>4)*64 + ((k>>3)&3)*16 + (n&15).  (tile = 8KB, DMA-linear)
// Groups 6/7: encoder weights.
// ---------------------------------------------------------------------------
__global__ void prep_w(const float* __restrict__ s0, const float* __restrict__ s1,
                       const float* __restrict__ s2, const float* __restrict__ s3,
                       const float* __restrict__ s4, const float* __restrict__ s5,
                       const float* __restrict__ s6, const float* __restrict__ s7,
                       ushort_t* __restrict__ hi, ushort_t* __restrict__ lo)
{
    long gid = (long)blockIdx.x * 256 + threadIdx.x;
    const float* src; int K, M; long base, loc;
    if      (gid < 524288)  { src=s0; K=256; M=512; base=0;       loc=gid; }
    else if (gid < 1048576) { src=s1; K=512; M=256; base=524288;  loc=gid-524288; }
    else if (gid < 1572864) { src=s2; K=256; M=512; base=1048576; loc=gid-1048576; }
    else if (gid < 2097152) { src=s3; K=512; M=256; base=1572864; loc=gid-1572864; }
    else if (gid < 2359296) { src=s4; K=256; M=256; base=2097152; loc=gid-2097152; }
    else if (gid < 2621440) { src=s5; K=256; M=256; base=2359296; loc=gid-2359296; }
    else if (gid < 2637824) { src=s6; K=64;  M=256; base=2621440; loc=gid-2621440; }
    else if (gid < 2646016) { src=s7; K=32;  M=256; base=2637824; loc=gid-2637824; }
    else return;
    long msz = (long)K * M;
    int  mat = (int)(loc / msz); long rem = loc - (long)mat * msz;
    int  k = (int)(rem / M);     int  n = (int)(rem - (long)k * M);
    float v = src[loc];
    ushort_t hu = f2h(v);
    ushort_t lu = f2h(v - h2f(hu));
    int nl = n & 127, g = (k >> 3) & 3;
    long p = (long)((nl >> 4) * 64 + g * 16 + (nl & 15));
    long dst = base + (long)mat * msz + (long)(k >> 5) * ((long)M << 5)
             + ((long)(n >> 7) << 12) + (p << 3) + (k & 7);
    hi[dst] = hu;
    if (lo) lo[dst] = lu;
}

// ---------------------------------------------------------------------------
// MFMA f16 GEMM, m97-style staging: global_load_lds(16B) for A and W hi/lo,
// conflict-free LDS layout p=(m>>4)*64+g*16+(m&15) (A via permuted global src,
// W pre-swizzled by prep_w). BN-affine+relu of A applied on fragments (pk f16).
// 128x128 tile, 4 waves (2x2), 4x4 16x16x32 frags/wave.
// ---------------------------------------------------------------------------
template<int RELU>
__global__ __launch_bounds__(256)
void mfma_gemm(PanelsIn Ap, int astride, const ushort_t* __restrict__ Wh,
               const ushort_t* __restrict__ Wl, const float* __restrict__ bias,
               PanelsOut Cp, int cstride, const float* __restrict__ Aff,
               float* __restrict__ cstatR, int N, int K, int M)
{
    __shared__ ushort_t Asm[4096];   // 8KB A tile
    __shared__ ushort_t Bhs[4096];
    __shared__ ushort_t Bls[4096];
    __shared__ ushort_t AffS[1024];  // f16 sc[K] | sb[K] at +512
    const int tid = threadIdx.x;
    const int brow = blockIdx.y * 128, bcol = blockIdx.x * 128;
    const int wid = tid >> 6, lane = tid & 63;
    const int wm = wid >> 1, wn = wid & 1;
    const int lg = lane >> 4, lr = lane & 15;

    if (Aff) {
        for (int c = tid; c < K; c += 256) {
            AffS[c]       = f2h(Aff[c]);
            AffS[512 + c] = f2h(Aff[K + c]);
        }
        __syncthreads();
    }

    const int mA = lane & 15;
    const int gA = (lane >> 4) & 3;

    floatx4 acc[4][4];
    #pragma unroll
    for (int i = 0; i < 4; ++i)
        #pragma unroll
        for (int j = 0; j < 4; ++j) acc[i][j] = (floatx4){0.f, 0.f, 0.f, 0.f};

    const int nkt = K >> 5;
    for (int kt = 0; kt < nkt; ++kt) {
        if (kt) __syncthreads();
        const ushort_t* pa = Ap.p[kt >> 2];
        const ushort_t* ga = pa + (long)(brow + wid * 16 + mA) * astride
                                + ((kt & 3) << 5) + gA * 8;
        load_lds16(ga, Asm + wid * 512);
        load_lds16(ga + (long)64 * astride, Asm + 2048 + wid * 512);
        const ushort_t* gb = Wh + (size_t)kt * ((size_t)M << 5)
                                + ((size_t)bcol << 5) + (wid * 64 + lane) * 8;
        load_lds16(gb, Bhs + wid * 512);
        load_lds16(gb + 2048, Bhs + 2048 + wid * 512);
        if (Wl) {
            const ushort_t* gl = Wl + (size_t)kt * ((size_t)M << 5)
                                    + ((size_t)bcol << 5) + (wid * 64 + lane) * 8;
            load_lds16(gl, Bls + wid * 512);
            load_lds16(gl + 2048, Bls + 2048 + wid * 512);
        }
        __syncthreads();

        half8_t af[4], bh[4], bl[4];
        #pragma unroll
        for (int i = 0; i < 4; ++i)
            af[i] = *(const half8_t*)(Asm + (((wm * 4 + i) * 64 + lg * 16 + lr) << 3));
        if (Aff) {
            half8_t scv = *(const half8_t*)(AffS + (kt << 5) + lg * 8);
            half8_t sbv = *(const half8_t*)(AffS + 512 + (kt << 5) + lg * 8);
            #pragma unroll
            for (int i = 0; i < 4; ++i) {
                half8_t z = af[i] * scv + sbv;
                #pragma unroll
                for (int e = 0; e < 8; ++e)
                    z[e] = z[e] > (_Float16)0 ? z[e] : (_Float16)0;
                af[i] = z;
            }
        }
        #pragma unroll
        for (int j = 0; j < 4; ++j) {
            bh[j] = *(const half8_t*)(Bhs + (((wn * 4 + j) * 64 + lg * 16 + lr) << 3));
            if (Wl)
                bl[j] = *(const half8_t*)(Bls + (((wn * 4 + j) * 64 + lg * 16 + lr) << 3));
        }
        #pragma unroll
        for (int i = 0; i < 4; ++i)
            #pragma unroll
            for (int j = 0; j < 4; ++j) {
                acc[i][j] = __builtin_amdgcn_mfma_f32_16x16x32_f16(af[i], bh[j], acc[i][j], 0, 0, 0);
                if (Wl)
                    acc[i][j] = __builtin_amdgcn_mfma_f32_16x16x32_f16(af[i], bl[j], acc[i][j], 0, 0, 0);
            }
    }

    ushort_t* cb = Cp.p[blockIdx.x];
    float csl[4], cql[4];
    #pragma unroll
    for (int j = 0; j < 4; ++j) { csl[j] = 0.f; cql[j] = 0.f; }
    #pragma unroll
    for (int j = 0; j < 4; ++j) {
        int lcol = wn * 64 + j * 16 + lr;
        float bia = bias[bcol + lcol];
        #pragma unroll
        for (int i = 0; i < 4; ++i) {
            #pragma unroll
            for (int r = 0; r < 4; ++r) {
                int row = brow + wm * 64 + i * 16 + (lg << 2) + r;
                float v = acc[i][j][r] + bia;
                if (RELU) v = fmaxf(v, 0.f);
                ushort_t uo = f2h(v);
                cb[(long)row * cstride + lcol] = uo;
                if (cstatR) {
                    float vq = h2f(uo);
                    csl[j] += vq; cql[j] = fmaf(vq, vq, cql[j]);
                }
            }
        }
    }
    if (cstatR) {
        __syncthreads();
        float* cs = (float*)Asm;
        float* cq = (float*)Bhs;
        if (tid < 128) { cs[tid] = 0.f; cq[tid] = 0.f; }
        __syncthreads();
        #pragma unroll
        for (int j = 0; j < 4; ++j) {
            int cl = wn * 64 + j * 16 + lr;
            atomicAdd(&cs[cl], csl[j]);
            atomicAdd(&cq[cl], cql[j]);
        }
        __syncthreads();
        if (tid < 128) {
            int rep = blockIdx.y & (NREP - 1);
            atomicAdd(&cstatR[(long)rep * 2 * M + bcol + tid], cs[tid]);
            atomicAdd(&cstatR[(long)rep * 2 * M + M + bcol + tid], cq[tid]);
        }
    }
}

// aff[c] = sa, aff[M+c] = sb from replicated stats + BN params
__global__ void finalize_aff(const float* __restrict__ cstatR, int M, float invN,
                             const float* __restrict__ g, const float* __restrict__ b,
                             float* __restrict__ aff)
{
    int c = blockIdx.x * blockDim.x + threadIdx.x;
    if (c >= M) return;
    float s = 0.f, q = 0.f;
    for (int r = 0; r < NREP; ++r) {
        s += cstatR[(long)r * 2 * M + c];
        q += cstatR[(long)r * 2 * M + M + c];
    }
    float m = s * invN, var = q * invN - m * m;
    float sa = rsqrtf(var + 1e-5f) * g[c];
    aff[c] = sa; aff[M + c] = b[c] - m * sa;
}

// ---------------------------------------------------------------------------
// CSR aggregation (one wave per node, grid-stride).
// ---------------------------------------------------------------------------
template<int EB>
__global__ __launch_bounds__(256)
void csr_agg(const ushort_t* __restrict__ in, ushort_t* __restrict__ out,
             const int* __restrict__ offs, const int* __restrict__ elist,
             const int* __restrict__ esrc, const float* __restrict__ eattr,
             const float* __restrict__ Wb, const float* __restrict__ bb,
             const float* __restrict__ eps_p, int n_nodes)
{
    __shared__ float Ws[EB ? 4096 : 1];
    __shared__ float bs[EB ? 256 : 1];
    if (EB) {
        for (int i = threadIdx.x; i < 4096; i += 256) Ws[i] = Wb[i];
        bs[threadIdx.x] = bb[threadIdx.x];
        __syncthreads();
    }
    float epsv = 1.f + eps_p[0];
    int lane = threadIdx.x & 63;
    int gw = (blockIdx.x * 256 + threadIdx.x) >> 6;
    int nw = (gridDim.x * 256) >> 6;
    for (int u = gw; u < n_nodes; u += nw) {
        const ushort_t* own = in + (long)u * 256;
        float acc[4];
        #pragma unroll
        for (int j = 0; j < 4; ++j) acc[j] = epsv * h2f(own[lane + 64 * j]);
        int s = offs[u], e = offs[u + 1];
        for (int i = s; i < e; ++i) {
            int eid = elist[i];
            int sid = esrc[eid];
            const ushort_t* row = in + (long)sid * 256;
            if (EB) {
                float ev[16];
                const float4* ea = (const float4*)(eattr + (long)eid * 16);
                float4 e0 = ea[0], e1 = ea[1], e2 = ea[2], e3 = ea[3];
                ev[0]=e0.x; ev[1]=e0.y; ev[2]=e0.z; ev[3]=e0.w;
                ev[4]=e1.x; ev[5]=e1.y; ev[6]=e1.z; ev[7]=e1.w;
                ev[8]=e2.x; ev[9]=e2.y; ev[10]=e2.z; ev[11]=e2.w;
                ev[12]=e3.x; ev[13]=e3.y; ev[14]=e3.z; ev[15]=e3.w;
                #pragma unroll
                for (int j = 0; j < 4; ++j) {
                    int c = lane + 64 * j;
                    float m = bs[c];
                    #pragma unroll
                    for (int k = 0; k < 16; ++k) m = fmaf(ev[k], Ws[k * 256 + c], m);
                    acc[j] += fmaxf(h2f(row[c]) + m, 0.f);
                }
            } else {
                #pragma unroll
                for (int j = 0; j < 4; ++j) acc[j] += h2f(row[lane + 64 * j]);
            }
        }
        ushort_t* o = out + (long)u * 256;
        #pragma unroll
        for (int j = 0; j < 4; ++j) o[lane + 64 * j] = f2h(acc[j]);
    }
}

// out[u] = relu(aff(raw[u])) + mean_{i in csr[u]} U[midx[elist[i]]]   (256 ch)
__global__ __launch_bounds__(128)
void csr_mean_aff(const ushort_t* __restrict__ raw, const ushort_t* __restrict__ U,
                  const int* __restrict__ midx, const int* __restrict__ elist,
                  const int* __restrict__ offs, const float* __restrict__ Aff,
                  ushort_t* __restrict__ outp)
{
    int u = blockIdx.x, t = threadIdx.x;
    int c0 = t * 2;
    float sa0 = Aff[c0], sa1 = Aff[c0 + 1], sb0 = Aff[256 + c0], sb1 = Aff[256 + c0 + 1];
    ushort2 b = *(const ushort2*)(raw + (long)u * 256 + c0);
    float x0 = fmaxf(h2f(b.x) * sa0 + sb0, 0.f);
    float x1 = fmaxf(h2f(b.y) * sa1 + sb1, 0.f);
    int s = offs[u], e = offs[u + 1];
    float a0 = 0.f, a1 = 0.f;
    for (int i = s; i < e; ++i) {
        long r = midx[elist[i]];
        ushort2 v = *(const ushort2*)(U + r * 256 + c0);
        a0 += h2f(v.x); a1 += h2f(v.y);
    }
    if (e > s) { float inv = 1.f / (float)(e - s); x0 += a0 * inv; x1 += a1 * inv; }
    ushort2 o; o.x = f2h(x0); o.y = f2h(x1);
    *(ushort2*)(outp + (long)u * 256 + c0) = o;
}

// ---------------------------------------------------------------------------
// fp32 GEMM for readout (small). LDA=133: conflict-free A-tile writes.
// ---------------------------------------------------------------------------
template<int RELU, typename TC>
__global__ __launch_bounds__(256)
void gemm_k(const float* __restrict__ A, const float* __restrict__ W,
            const float* __restrict__ bias, TC* __restrict__ C,
            int N, int K, int M)
{
    const int BK = 16, LDA = 133;
    __shared__ float As[BK * LDA];
    __shared__ float Bs[BK * LDA];
    const int brow = blockIdx.y * 128;
    const int bcol = blockIdx.x * 128;
    const int tid  = threadIdx.x;
    const int tr = tid >> 4, tc = tid & 15;

    float acc[8][8];
    #pragma unroll
    for (int i = 0; i < 8; ++i)
        #pragma unroll
        for (int j = 0; j < 8; ++j) acc[i][j] = 0.f;

    for (int k0 = 0; k0 < K; k0 += BK) {
        #pragma unroll
        for (int u = 0; u < 8; ++u) {
            int idx = tid + u * 256;
            int m = idx >> 4, kk = idx & 15;
            As[kk * LDA + m] = A[(long)(brow + m) * K + k0 + kk];
        }
        #pragma unroll
        for (int u = 0; u < 8; ++u) {
            int idx = tid + u * 256;
            int kk = idx >> 7, n = idx & 127;
            int col = bcol + n;
            Bs[kk * LDA + n] = (col < M) ? W[(long)(k0 + kk) * M + col] : 0.f;
        }
        __syncthreads();
        #pragma unroll
        for (int kk = 0; kk < BK; ++kk) {
            float av[8], bv[8];
            float4 a0 = *(const float4*)&As[kk * LDA + tr * 8];
            float4 a1 = *(const float4*)&As[kk * LDA + tr * 8 + 4];
            float4 b0 = *(const float4*)&Bs[kk * LDA + tc * 8];
            float4 b1 = *(const float4*)&Bs[kk * LDA + tc * 8 + 4];
            av[0]=a0.x; av[1]=a0.y; av[2]=a0.z; av[3]=a0.w;
            av[4]=a1.x; av[5]=a1.y; av[6]=a1.z; av[7]=a1.w;
            bv[0]=b0.x; bv[1]=b0.y; bv[2]=b0.z; bv[3]=b0.w;
            bv[4]=b1.x; bv[5]=b1.y; bv[6]=b1.z; bv[7]=b1.w;
            #pragma unroll
            for (int i = 0; i < 8; ++i)
                #pragma unroll
                for (int j = 0; j < 8; ++j)
                    acc[i][j] = fmaf(av[i], bv[j], acc[i][j]);
        }
        __syncthreads();
    }
    #pragma unroll
    for (int i = 0; i < 8; ++i) {
        int row = brow + tr * 8 + i;
        #pragma unroll
        for (int j = 0; j < 8; ++j) {
            int col = bcol + tc * 8 + j;
            if (col < M) {
                float v = acc[i][j] + bias[col];
                if (RELU) v = fmaxf(v, 0.f);
                if constexpr (sizeof(TC) == 2) ((ushort_t*)C)[(long)row * M + col] = f2h(v);
                else                           ((float*)C)[(long)row * M + col] = v;
            }
        }
    }
}

__global__ void count_idx(const int* __restrict__ idx, int n, int* __restrict__ cnt)
{
    int i = blockIdx.x * blockDim.x + threadIdx.x;
    if (i < n) atomicAdd(&cnt[idx[i]], 1);
}

// ---- parallel exclusive scan (3 phases) ----
__global__ __launch_bounds__(256)
void scan_p1(const int* __restrict__ cnt, int n, int* __restrict__ partials)
{
    __shared__ int sd[256];
    int i = blockIdx.x * 256 + threadIdx.x;
    sd[threadIdx.x] = (i < n) ? cnt[i] : 0;
    __syncthreads();
    #pragma unroll
    for (int s = 128; s > 0; s >>= 1) {
        if (threadIdx.x < s) sd[threadIdx.x] += sd[threadIdx.x + s];
        __syncthreads();
    }
    if (threadIdx.x == 0) partials[blockIdx.x] = sd[0];
}

__global__ __launch_bounds__(1024)
void scan_p2(int* __restrict__ partials, int nb, int* __restrict__ off, int n)
{
    __shared__ int sd[1024];
    int t = threadIdx.x;
    int v = (t < nb) ? partials[t] : 0;
    sd[t] = v;
    __syncthreads();
    for (int d = 1; d < 1024; d <<= 1) {
        int x = (t >= d) ? sd[t - d] : 0;
        __syncthreads();
        sd[t] += x;
        __syncthreads();
    }
    if (t < nb) partials[t] = sd[t] - v;
    if (t == 1023) off[n] = sd[nb - 1];
}

__global__ __launch_bounds__(256)
void scan_p3(const int* __restrict__ cnt, int n, const int* __restrict__ partials,
             int* __restrict__ off, int* __restrict__ cursor)
{
    __shared__ int sd[256];
    int i = blockIdx.x * 256 + threadIdx.x;
    int v = (i < n) ? cnt[i] : 0;
    sd[threadIdx.x] = v;
    __syncthreads();
    for (int d = 1; d < 256; d <<= 1) {
        int x = (threadIdx.x >= d) ? sd[threadIdx.x - d] : 0;
        __syncthreads();
        sd[threadIdx.x] += x;
        __syncthreads();
    }
    if (i < n) {
        int e = partials[blockIdx.x] + sd[threadIdx.x] - v;
        off[i] = e; cursor[i] = e;
    }
}

__global__ void csr_fill(const int* __restrict__ idx, int n,
                         int* __restrict__ cursor, int* __restrict__ elist)
{
    int i = blockIdx.x * blockDim.x + threadIdx.x;
    if (i < n) { int p = atomicAdd(&cursor[idx[i]], 1); elist[p] = i; }
}

__global__ __launch_bounds__(256)
void seg_pool(const ushort_t* __restrict__ X, const int* __restrict__ bidx,
              int nrows, float* __restrict__ pooled)
{
    int b = blockIdx.x, t = threadIdx.x;
    int lo = 0, hi = nrows;
    while (lo < hi) { int mid = (lo + hi) >> 1; if (bidx[mid] < b) lo = mid + 1; else hi = mid; }
    int s = lo; hi = nrows;
    while (lo < hi) { int mid = (lo + hi) >> 1; if (bidx[mid] < b + 1) lo = mid + 1; else hi = mid; }
    int e = lo;
    float acc = 0.f;
    for (int r = s; r < e; ++r) acc += h2f(X[(long)r * 256 + t]);
    pooled[(long)b * 256 + t] = acc / fmaxf((float)(e - s), 1.f);
}

__global__ void vadd(float* __restrict__ out, const float* __restrict__ in, long n4)
{
    long t = (long)blockIdx.x * blockDim.x + threadIdx.x;
    if (t >= n4) return;
    float4 a = ((float4*)out)[t];
    float4 b = ((const float4*)in)[t];
    a.x += b.x; a.y += b.y; a.z += b.z; a.w += b.w;
    ((float4*)out)[t] = a;
}

// ---------------------------------------------------------------------------
extern "C" void kernel_launch(void* const* d_in, const int* in_sizes, int n_in,
                              void* d_out, int out_size, void* d_ws, size_t ws_size,
                              hipStream_t stream)
{
    (void)in_sizes; (void)n_in;
    const float* x          = (const float*)d_in[0];
    const float* fragments  = (const float*)d_in[1];
    const float* edge_attr  = (const float*)d_in[2];
    const float* atom_enc_W = (const float*)d_in[3];
    const float* atom_enc_b = (const float*)d_in[4];
    const float* frag_enc_W = (const float*)d_in[5];
    const float* frag_enc_b = (const float*)d_in[6];
    const float* bond_W     = (const float*)d_in[7];
    const float* bond_b     = (const float*)d_in[8];
    const float* gine_eps   = (const float*)d_in[9];
    const float* gine_W1    = (const float*)d_in[10];
    const float* gine_b1    = (const float*)d_in[11];
    const float* gine_bn_g  = (const float*)d_in[12];
    const float* gine_bn_b  = (const float*)d_in[13];
    const float* gine_W2    = (const float*)d_in[14];
    const float* gine_b2    = (const float*)d_in[15];
    const float* atom_bn_g  = (const float*)d_in[16];
    const float* atom_bn_b  = (const float*)d_in[17];
    const float* gin_eps    = (const float*)d_in[18];
    const float* gin_W1     = (const float*)d_in[19];
    const float* gin_b1     = (const float*)d_in[20];
    const float* gin_bn_g   = (const float*)d_in[21];
    const float* gin_bn_b   = (const float*)d_in[22];
    const float* gin_W2     = (const float*)d_in[23];
    const float* gin_b2     = (const float*)d_in[24];
    const float* frag_bn_g  = (const float*)d_in[25];
    const float* frag_bn_b  = (const float*)d_in[26];
    const float* a2f_W      = (const float*)d_in[27];
    const float* a2f_b      = (const float*)d_in[28];
    const float* f2a_W      = (const float*)d_in[29];
    const float* f2a_b      = (const float*)d_in[30];
    const float* fo_W1      = (const float*)d_in[31];
    const float* fo_b1      = (const float*)d_in[32];
    const float* fo_W2      = (const float*)d_in[33];
    const float* fo_b2      = (const float*)d_in[34];
    const float* ao_W1      = (const float*)d_in[35];
    const float* ao_b1      = (const float*)d_in[36];
    const float* ao_W2      = (const float*)d_in[37];
    const float* ao_b2      = (const float*)d_in[38];
    const float* out_W1     = (const float*)d_in[39];
    const float* out_b1     = (const float*)d_in[40];
    const float* out_W2     = (const float*)d_in[41];
    const float* out_b2     = (const float*)d_in[42];
    const int* edge_index   = (const int*)d_in[43];
    const int* fedge_index  = (const int*)d_in[44];
    const int* batch        = (const int*)d_in[45];
    const int* fbatch       = (const int*)d_in[46];
    const int* mem_atom     = (const int*)d_in[47];
    const int* mem_frag     = (const int*)d_in[48];

    const int* src  = edge_index;
    const int* dst  = edge_index + N_EDGE;
    const int* fsrc = fedge_index;
    const int* fdst = fedge_index + N_FEDGE;

    // ---- arena ----
    const size_t WPN = 2646016;   // total prepped-weight elems (incl. encoders)
    size_t off = 0;
    auto take = [&](size_t b) -> size_t { size_t p = off; off = (off + b + 255) & ~(size_t)255; return p; };
    size_t o_big   = take((size_t)N_ATOM * 512 * 2);     // 134 MB
    size_t o_a     = take((size_t)N_ATOM * H * 2);       // 67 MB
    size_t o_f     = take((size_t)N_FRAG * H * 2);
    size_t o_f2    = take((size_t)N_FRAG * H * 2);
    size_t o_offea = take((size_t)(N_ATOM + 1) * 4);
    size_t o_elea  = take((size_t)N_EDGE * 4);
    size_t o_offef = take((size_t)(N_FRAG + 1) * 4);
    size_t o_elef  = take((size_t)N_FEDGE * 4);
    size_t o_offma = take((size_t)(N_ATOM + 1) * 4);
    size_t o_elma  = take((size_t)N_MEM * 4);
    size_t o_offmf = take((size_t)(N_FRAG + 1) * 4);
    size_t o_elmf  = take((size_t)N_MEM * 4);
    size_t o_cnta  = take((size_t)N_ATOM * 4);
    size_t o_cntf  = take((size_t)N_FRAG * 4);
    size_t o_part  = take(1024 * 4);
    size_t o_stats = take((size_t)NREP * 3072 * 4);
    size_t o_aff   = take(3072 * 4);
    size_t o_hi    = take(WPN * 2);
    size_t need_nolo = off;
    size_t o_lo    = take(WPN * 2);
    size_t need_full = off;

    bool use_lo = (need_full <= ws_size);
    if (!use_lo && need_nolo > ws_size) {
        fill_const<<<64, 256, 0, stream>>>((float*)d_out, out_size,
                                           (float)((double)ws_size / 1024.0));
        return;
    }
    char* base = (char*)d_ws;
    char*     big     = base + o_big;
    ushort_t* a       = (ushort_t*)(base + o_a);
    ushort_t* f       = (ushort_t*)(base + o_f);
    ushort_t* f2      = (ushort_t*)(base + o_f2);
    int* off_ea = (int*)(base + o_offea);
    int* el_ea  = (int*)(base + o_elea);
    int* off_ef = (int*)(base + o_offef);
    int* el_ef  = (int*)(base + o_elef);
    int* off_ma = (int*)(base + o_offma);
    int* el_ma  = (int*)(base + o_elma);
    int* off_mf = (int*)(base + o_offmf);
    int* el_mf  = (int*)(base + o_elmf);
    int* cnt_a  = (int*)(base + o_cnta);
    int* cnt_f  = (int*)(base + o_cntf);
    int* parts  = (int*)(base + o_part);
    float* statsR = (float*)(base + o_stats);
    float* affs   = (float*)(base + o_aff);
    ushort_t* Wp_hi = (ushort_t*)(base + o_hi);
    ushort_t* Wp_lo = use_lo ? (ushort_t*)(base + o_lo) : nullptr;

    float* cst1a = statsR;
    float* cst2a = statsR + (size_t)NREP * 1024;
    float* cst1f = statsR + (size_t)NREP * 1536;
    float* cst2f = statsR + (size_t)NREP * 2560;
    float* aff1_a = affs;
    float* aff2_a = affs + 1024;
    float* aff1_f = affs + 1536;
    float* aff2_f = affs + 2560;

    ushort_t* big_u = (ushort_t*)big;
    const size_t HALF_U = (size_t)N_ATOM * 256;
    ushort_t* ha  = big_u + HALF_U;
    const size_t PAN_A = (size_t)N_ATOM * 128;
    const size_t PAN_F = (size_t)N_FRAG * 128;
    ushort_t* Ua = big_u;
    float* pooled_f = (float*)big;
    float* pooled_a = (float*)(big + (size_t)8 * 1024 * 1024);
    float* tmp      = (float*)(big + (size_t)16 * 1024 * 1024);
    // encoder-time aliases of big (consumed before layer loop writes big)
    ushort_t* xh = big_u;                                 // 131072*64 f16
    ushort_t* fh = big_u + (size_t)N_ATOM * 64;           // 32768*32 f16

    const long WG0 = 0, WG1 = 524288, WG2 = 1048576, WG3 = 1572864,
               WG4 = 2097152, WG5 = 2359296, WG6 = 2621440, WG7 = 2637824;

    auto build_csr = [&](const int* idx, int n_edges, int n_nodes,
                         int* cnt, int* offs, int* elist) {
        hipMemsetAsync(cnt, 0, (size_t)n_nodes * 4, stream);
        count_idx<<<CDIV(n_edges,256),256,0,stream>>>(idx, n_edges, cnt);
        int nb = CDIV(n_nodes, 256);
        scan_p1<<<nb, 256, 0, stream>>>(cnt, n_nodes, parts);
        scan_p2<<<1, 1024, 0, stream>>>(parts, nb, offs, n_nodes);
        scan_p3<<<nb, 256, 0, stream>>>(cnt, n_nodes, parts, offs, cnt);
        csr_fill<<<CDIV(n_edges,256),256,0,stream>>>(idx, n_edges, cnt, elist);
    };

    // ---- weight prep + CSR builds ----
    prep_w<<<CDIV((long)WPN, 256), 256, 0, stream>>>(gine_W1, gine_W2, gin_W1, gin_W2,
                                                     a2f_W, f2a_W, atom_enc_W, frag_enc_W,
                                                     Wp_hi, Wp_lo);
    build_csr(dst,      N_EDGE,  N_ATOM, cnt_a, off_ea, el_ea);
    build_csr(fdst,     N_FEDGE, N_FRAG, cnt_f, off_ef, el_ef);
    build_csr(mem_atom, N_MEM,   N_ATOM, cnt_a, off_ma, el_ma);
    build_csr(mem_frag, N_MEM,   N_FRAG, cnt_f, off_mf, el_mf);

    // ---- encoders via MFMA (f16 inputs staged in big) ----
    conv_f2h<<<2048, 256, 0, stream>>>(x, xh, (long)N_ATOM * 64);
    conv_f2h<<<512, 256, 0, stream>>>(fragments, fh, (long)N_FRAG * 32);
    {
        PanelsIn Ein; PanelsOut Eout;
        for (int i = 0; i < 4; ++i) Ein.p[i] = xh;
        Eout.p[0] = a; Eout.p[1] = a + 128; Eout.p[2] = a; Eout.p[3] = a;
        mfma_gemm<0><<<dim3(2, N_ATOM/128), 256, 0, stream>>>(
            Ein, 64, Wp_hi + WG6, Wp_lo ? Wp_lo + WG6 : nullptr,
            atom_enc_b, Eout, 256, nullptr, nullptr, N_ATOM, 64, 256);
        PanelsIn Fin; PanelsOut Fout;
        for (int i = 0; i < 4; ++i) Fin.p[i] = fh;
        Fout.p[0] = f; Fout.p[1] = f + 128; Fout.p[2] = f; Fout.p[3] = f;
        mfma_gemm<0><<<dim3(2, N_FRAG/128), 256, 0, stream>>>(
            Fin, 32, Wp_hi + WG7, Wp_lo ? Wp_lo + WG7 : nullptr,
            frag_enc_b, Fout, 256, nullptr, nullptr, N_FRAG, 32, 256);
    }

    const float invNA = 1.f / N_ATOM, invNF = 1.f / N_FRAG;

    for (int l = 0; l < 4; ++l) {
        hipMemsetAsync(statsR, 0, (size_t)NREP * 3072 * 4, stream);

        // ===== atoms: GINE + MLP =====
        csr_agg<1><<<2048, 256, 0, stream>>>(a, ha, off_ea, el_ea, src, edge_attr,
            bond_W + (long)l*16*H, bond_b + l*H, gine_eps + l, N_ATOM);

        PanelsIn A1in; PanelsOut A1out;
        for (int i = 0; i < 4; ++i) A1in.p[i] = ha + i * 128;
        A1out.p[0] = a;          A1out.p[1] = a + PAN_A;
        A1out.p[2] = big_u;      A1out.p[3] = big_u + PAN_A;
        mfma_gemm<0><<<dim3(4, N_ATOM/128), 256, 0, stream>>>(
            A1in, 256, Wp_hi + WG0 + (long)l*131072,
            Wp_lo ? Wp_lo + WG0 + (long)l*131072 : nullptr,
            gine_b1 + l*512, A1out, 128, nullptr, cst1a, N_ATOM, 256, 512);
        finalize_aff<<<2, 256, 0, stream>>>(cst1a, 512, invNA,
            gine_bn_g + l*512, gine_bn_b + l*512, aff1_a);

        PanelsIn A2in; PanelsOut A2out;
        A2in.p[0] = a;       A2in.p[1] = a + PAN_A;
        A2in.p[2] = big_u;   A2in.p[3] = big_u + PAN_A;
        A2out.p[0] = ha; A2out.p[1] = ha + 128; A2out.p[2] = ha; A2out.p[3] = ha;
        mfma_gemm<0><<<dim3(2, N_ATOM/128), 256, 0, stream>>>(
            A2in, 128, Wp_hi + WG1 + (long)l*131072,
            Wp_lo ? Wp_lo + WG1 + (long)l*131072 : nullptr,
            gine_b2 + l*H, A2out, 256, aff1_a, cst2a, N_ATOM, 512, 256);
        finalize_aff<<<1, 256, 0, stream>>>(cst2a, 256, invNA,
            atom_bn_g + l*H, atom_bn_b + l*H, aff2_a);

        // ===== fragments: GIN + MLP =====
        csr_agg<0><<<512, 256, 0, stream>>>(f, f2, off_ef, el_ef, fsrc, nullptr,
            nullptr, nullptr, gin_eps + l, N_FRAG);

        PanelsIn F1in; PanelsOut F1out;
        for (int i = 0; i < 4; ++i) F1in.p[i] = f2 + i * 128;
        for (int i = 0; i < 4; ++i) F1out.p[i] = big_u + i * PAN_F;
        mfma_gemm<0><<<dim3(4, N_FRAG/128), 256, 0, stream>>>(
            F1in, 256, Wp_hi + WG2 + (long)l*131072,
            Wp_lo ? Wp_lo + WG2 + (long)l*131072 : nullptr,
            gin_b1 + l*512, F1out, 128, nullptr, cst1f, N_FRAG, 256, 512);
        finalize_aff<<<2, 256, 0, stream>>>(cst1f, 512, invNF,
            gin_bn_g + l*512, gin_bn_b + l*512, aff1_f);

        PanelsIn F2in; PanelsOut F2out;
        for (int i = 0; i < 4; ++i) F2in.p[i] = big_u + i * PAN_F;
        F2out.p[0] = f2; F2out.p[1] = f2 + 128; F2out.p[2] = f2; F2out.p[3] = f2;
        mfma_gemm<0><<<dim3(2, N_FRAG/128), 256, 0, stream>>>(
            F2in, 128, Wp_hi + WG3 + (long)l*131072,
            Wp_lo ? Wp_lo + WG3 + (long)l*131072 : nullptr,
            gin_b2 + l*H, F2out, 256, aff1_f, cst2f, N_FRAG, 512, 256);
        finalize_aff<<<1, 256, 0, stream>>>(cst2f, 256, invNF,
            frag_bn_g + l*H, frag_bn_b + l*H, aff2_f);

        // ===== inter MP (hi-only weights) =====
        PanelsIn UAin; PanelsOut UAout;
        for (int i = 0; i < 4; ++i) UAin.p[i] = ha + i * 128;
        UAout.p[0] = Ua; UAout.p[1] = Ua + 128; UAout.p[2] = Ua; UAout.p[3] = Ua;
        mfma_gemm<1><<<dim3(2, N_ATOM/128), 256, 0, stream>>>(
            UAin, 256, Wp_hi + WG4 + (long)l*65536, nullptr,
            a2f_b + l*H, UAout, 256, aff2_a, nullptr, N_ATOM, 256, 256);
        csr_mean_aff<<<N_FRAG, 128, 0, stream>>>(f2, Ua, mem_atom, el_mf, off_mf,
                                                 aff2_f, f);
        PanelsIn UFin; PanelsOut UFout;
        for (int i = 0; i < 4; ++i) UFin.p[i] = f + i * 128;
        UFout.p[0] = f2; UFout.p[1] = f2 + 128; UFout.p[2] = f2; UFout.p[3] = f2;
        mfma_gemm<1><<<dim3(2, N_FRAG/128), 256, 0, stream>>>(
            UFin, 256, Wp_hi + WG5 + (long)l*65536, nullptr,
            f2a_b + l*H, UFout, 256, nullptr, nullptr, N_FRAG, 256, 256);
        csr_mean_aff<<<N_ATOM, 128, 0, stream>>>(ha, f2, mem_frag, el_ma, off_ma,
                                                 aff2_a, a);
    }

    // ===== readout =====
    seg_pool<<<BATCH, 256, 0, stream>>>(f, fbatch, N_FRAG, pooled_f);
    gemm_k<1,float><<<dim3(2, BATCH/128), 256, 0, stream>>>(
        pooled_f, fo_W1, fo_b1, tmp, BATCH, H, H);
    gemm_k<1,float><<<dim3(2, BATCH/128), 256, 0, stream>>>(
        tmp, fo_W2, fo_b2, pooled_f, BATCH, H, H);

    seg_pool<<<BATCH, 256, 0, stream>>>(a, batch, N_ATOM, pooled_a);
    gemm_k<1,float><<<dim3(2, BATCH/128), 256, 0, stream>>>(
        pooled_a, ao_W1, ao_b1, tmp, BATCH, H, H);
    gemm_k<1,float><<<dim3(2, BATCH/128), 256, 0, stream>>>(
        tmp, ao_W2, ao_b2, pooled_a, BATCH, H, H);

    vadd<<<(int)CDIV((long)BATCH*H/4,256), 256, 0, stream>>>(
        pooled_a, pooled_f, (long)BATCH * H / 4);
    gemm_k<1,float><<<dim3(2, BATCH/128), 256, 0, stream>>>(
        pooled_a, out_W1, out_b1, tmp, BATCH, H, H);
    gemm_k<0,float><<<dim3(1, BATCH/128), 256, 0, stream>>>(
        tmp, out_W2, out_b2, (float*)d_out, BATCH, H, 1);
}

// Round 10
// 3207.842 us; speedup vs baseline: 8.3349x; 1.0832x over previous
//
#include <hip/hip_runtime.h>

#define CDIV(a,b) (((a)+(b)-1)/(b))

static const int N_ATOM = 131072, N_FRAG = 32768, N_EDGE = 262144,
                 N_FEDGE = 65536, N_MEM = 196608, BATCH = 4096, H = 256;
static const int NREP = 16;   // stat atomic replicas

typedef unsigned short ushort_t;
typedef _Float16 half8_t __attribute__((ext_vector_type(8)));
typedef float    floatx4 __attribute__((ext_vector_type(4)));

struct PanelsIn  { const ushort_t* p[4]; };
struct PanelsOut { ushort_t* p[4]; };

__device__ __forceinline__ float h2f(ushort_t u) {
    _Float16 h; __builtin_memcpy(&h, &u, 2); return (float)h;
}
__device__ __forceinline__ ushort_t f2h(float f) {
    _Float16 h = (_Float16)f; ushort_t u; __builtin_memcpy(&u, &h, 2); return u;
}

// async global->LDS, 16B per lane. lds base must be wave-uniform; HW adds lane*16.
__device__ __forceinline__ void load_lds16(const ushort_t* g, ushort_t* l) {
    __builtin_amdgcn_global_load_lds(
        (const __attribute__((address_space(1))) unsigned int*)g,
        (__attribute__((address_space(3))) unsigned int*)l, 16, 0, 0);
}

__global__ void fill_const(float* p, long n, float v) {
    long t = (long)blockIdx.x * blockDim.x + threadIdx.x;
    long stride = (long)gridDim.x * blockDim.x;
    for (; t < n; t += stride) p[t] = v;
}

// f32 -> f16 bulk convert (n % 4 == 0)
__global__ void conv_f2h(const float* __restrict__ in, ushort_t* __restrict__ out, long n)
{
    long t = (long)blockIdx.x * 256 + threadIdx.x;
    long stride = (long)gridDim.x * 256;
    for (long i = t; i < n / 4; i += stride) {
        float4 v = ((const float4*)in)[i];
        ushort4 o; o.x = f2h(v.x); o.y = f2h(v.y); o.z = f2h(v.z); o.w = f2h(v.w);
        ((ushort4*)out)[i] = o;
    }
}

// ---------------------------------------------------------------------------
// Weight prep: f32 W[K][M] -> f16 in LDS-tile order:
// dst = mat + kt*(M*32) + (n>>7)*4096 + p*8 + (k&7),
// p = ((n&127)>>4)*64 + ((k>>3)&3)*16 + (n&15).  (tile = 8KB, DMA-linear)
// ---------------------------------------------------------------------------
__global__ void prep_w(const float* __restrict__ s0, const float* __restrict__ s1,
                       const float* __restrict__ s2, const float* __restrict__ s3,
                       const float* __restrict__ s4, const float* __restrict__ s5,
                       const float* __restrict__ s6, const float* __restrict__ s7,
                       ushort_t* __restrict__ hi)
{
    long gid = (long)blockIdx.x * 256 + threadIdx.x;
    const float* src; int K, M; long base, loc;
    if      (gid < 524288)  { src=s0; K=256; M=512; base=0;       loc=gid; }
    else if (gid < 1048576) { src=s1; K=512; M=256; base=524288;  loc=gid-524288; }
    else if (gid < 1572864) { src=s2; K=256; M=512; base=1048576; loc=gid-1048576; }
    else if (gid < 2097152) { src=s3; K=512; M=256; base=1572864; loc=gid-1572864; }
    else if (gid < 2359296) { src=s4; K=256; M=256; base=2097152; loc=gid-2097152; }
    else if (gid < 2621440) { src=s5; K=256; M=256; base=2359296; loc=gid-2359296; }
    else if (gid < 2637824) { src=s6; K=64;  M=256; base=2621440; loc=gid-2621440; }
    else if (gid < 2646016) { src=s7; K=32;  M=256; base=2637824; loc=gid-2637824; }
    else return;
    long msz = (long)K * M;
    int  mat = (int)(loc / msz); long rem = loc - (long)mat * msz;
    int  k = (int)(rem / M);     int  n = (int)(rem - (long)k * M);
    int nl = n & 127, g = (k >> 3) & 3;
    long p = (long)((nl >> 4) * 64 + g * 16 + (nl & 15));
    long dst = base + (long)mat * msz + (long)(k >> 5) * ((long)M << 5)
             + ((long)(n >> 7) << 12) + (p << 3) + (k & 7);
    hi[dst] = f2h(src[loc]);
}

// ---------------------------------------------------------------------------
// MFMA f16 GEMM, m97-style staging: global_load_lds(16B) for A and W,
// conflict-free LDS layout p=(m>>4)*64+g*16+(m&15) (A via permuted global src,
// W pre-swizzled by prep_w). BN-affine+relu of A applied on fragments (pk f16).
// 128x128 tile, 4 waves (2x2), 4x4 16x16x32 frags/wave.
// XCD-chunked block swizzle for A-panel L2 reuse (grid % 8 == 0 required).
// ---------------------------------------------------------------------------
template<int RELU>
__global__ __launch_bounds__(256)
void mfma_gemm(PanelsIn Ap, int astride, const ushort_t* __restrict__ Wh,
               const float* __restrict__ bias,
               PanelsOut Cp, int cstride, const float* __restrict__ Aff,
               float* __restrict__ cstatR, int N, int K, int M)
{
    __shared__ ushort_t Asm[4096];   // 8KB A tile
    __shared__ ushort_t Bhs[4096];
    __shared__ ushort_t AffS[1024];  // f16 sc[K] | sb[K] at +512
    const int tid = threadIdx.x;
    // XCD-chunked swizzle: consecutive work-ids on one XCD -> A panel L2 reuse
    const int nwg = gridDim.x * gridDim.y;
    const int bid = blockIdx.y * gridDim.x + blockIdx.x;
    const int cpx = nwg >> 3;
    const int swz = (bid & 7) * cpx + (bid >> 3);
    const int bx = swz % gridDim.x, by = swz / gridDim.x;
    const int brow = by * 128, bcol = bx * 128;
    const int wid = tid >> 6, lane = tid & 63;
    const int wm = wid >> 1, wn = wid & 1;
    const int lg = lane >> 4, lr = lane & 15;

    if (Aff) {
        for (int c = tid; c < K; c += 256) {
            AffS[c]       = f2h(Aff[c]);
            AffS[512 + c] = f2h(Aff[K + c]);
        }
        __syncthreads();
    }

    const int mA = lane & 15;
    const int gA = (lane >> 4) & 3;

    floatx4 acc[4][4];
    #pragma unroll
    for (int i = 0; i < 4; ++i)
        #pragma unroll
        for (int j = 0; j < 4; ++j) acc[i][j] = (floatx4){0.f, 0.f, 0.f, 0.f};

    const int nkt = K >> 5;
    for (int kt = 0; kt < nkt; ++kt) {
        if (kt) __syncthreads();
        const ushort_t* pa = Ap.p[kt >> 2];
        const ushort_t* ga = pa + (long)(brow + wid * 16 + mA) * astride
                                + ((kt & 3) << 5) + gA * 8;
        load_lds16(ga, Asm + wid * 512);
        load_lds16(ga + (long)64 * astride, Asm + 2048 + wid * 512);
        const ushort_t* gb = Wh + (size_t)kt * ((size_t)M << 5)
                                + ((size_t)bcol << 5) + (wid * 64 + lane) * 8;
        load_lds16(gb, Bhs + wid * 512);
        load_lds16(gb + 2048, Bhs + 2048 + wid * 512);
        __syncthreads();

        half8_t af[4], bh[4];
        #pragma unroll
        for (int i = 0; i < 4; ++i)
            af[i] = *(const half8_t*)(Asm + (((wm * 4 + i) * 64 + lg * 16 + lr) << 3));
        if (Aff) {
            half8_t scv = *(const half8_t*)(AffS + (kt << 5) + lg * 8);
            half8_t sbv = *(const half8_t*)(AffS + 512 + (kt << 5) + lg * 8);
            #pragma unroll
            for (int i = 0; i < 4; ++i) {
                half8_t z = af[i] * scv + sbv;
                #pragma unroll
                for (int e = 0; e < 8; ++e)
                    z[e] = z[e] > (_Float16)0 ? z[e] : (_Float16)0;
                af[i] = z;
            }
        }
        #pragma unroll
        for (int j = 0; j < 4; ++j)
            bh[j] = *(const half8_t*)(Bhs + (((wn * 4 + j) * 64 + lg * 16 + lr) << 3));
        #pragma unroll
        for (int i = 0; i < 4; ++i)
            #pragma unroll
            for (int j = 0; j < 4; ++j)
                acc[i][j] = __builtin_amdgcn_mfma_f32_16x16x32_f16(af[i], bh[j], acc[i][j], 0, 0, 0);
    }

    ushort_t* cb = Cp.p[bx];
    float csl[4], cql[4];
    #pragma unroll
    for (int j = 0; j < 4; ++j) { csl[j] = 0.f; cql[j] = 0.f; }
    #pragma unroll
    for (int j = 0; j < 4; ++j) {
        int lcol = wn * 64 + j * 16 + lr;
        float bia = bias[bcol + lcol];
        #pragma unroll
        for (int i = 0; i < 4; ++i) {
            #pragma unroll
            for (int r = 0; r < 4; ++r) {
                int row = brow + wm * 64 + i * 16 + (lg << 2) + r;
                float v = acc[i][j][r] + bia;
                if (RELU) v = fmaxf(v, 0.f);
                ushort_t uo = f2h(v);
                cb[(long)row * cstride + lcol] = uo;
                if (cstatR) {
                    float vq = h2f(uo);
                    csl[j] += vq; cql[j] = fmaf(vq, vq, cql[j]);
                }
            }
        }
    }
    if (cstatR) {
        __syncthreads();
        float* cs = (float*)Asm;
        float* cq = (float*)Bhs;
        if (tid < 128) { cs[tid] = 0.f; cq[tid] = 0.f; }
        __syncthreads();
        #pragma unroll
        for (int j = 0; j < 4; ++j) {
            int cl = wn * 64 + j * 16 + lr;
            atomicAdd(&cs[cl], csl[j]);
            atomicAdd(&cq[cl], cql[j]);
        }
        __syncthreads();
        if (tid < 128) {
            int rep = by & (NREP - 1);
            atomicAdd(&cstatR[(long)rep * 2 * M + bcol + tid], cs[tid]);
            atomicAdd(&cstatR[(long)rep * 2 * M + M + bcol + tid], cq[tid]);
        }
    }
}

// aff[c] = sa, aff[M+c] = sb from replicated stats + BN params
__global__ void finalize_aff(const float* __restrict__ cstatR, int M, float invN,
                             const float* __restrict__ g, const float* __restrict__ b,
                             float* __restrict__ aff)
{
    int c = blockIdx.x * blockDim.x + threadIdx.x;
    if (c >= M) return;
    float s = 0.f, q = 0.f;
    for (int r = 0; r < NREP; ++r) {
        s += cstatR[(long)r * 2 * M + c];
        q += cstatR[(long)r * 2 * M + M + c];
    }
    float m = s * invN, var = q * invN - m * m;
    float sa = rsqrtf(var + 1e-5f) * g[c];
    aff[c] = sa; aff[M + c] = b[c] - m * sa;
}

// ---------------------------------------------------------------------------
// CSR aggregation (one wave per node, grid-stride).
// ---------------------------------------------------------------------------
template<int EB>
__global__ __launch_bounds__(256)
void csr_agg(const ushort_t* __restrict__ in, ushort_t* __restrict__ out,
             const int* __restrict__ offs, const int* __restrict__ elist,
             const int* __restrict__ esrc, const float* __restrict__ eattr,
             const float* __restrict__ Wb, const float* __restrict__ bb,
             const float* __restrict__ eps_p, int n_nodes)
{
    __shared__ float Ws[EB ? 4096 : 1];
    __shared__ float bs[EB ? 256 : 1];
    if (EB) {
        for (int i = threadIdx.x; i < 4096; i += 256) Ws[i] = Wb[i];
        bs[threadIdx.x] = bb[threadIdx.x];
        __syncthreads();
    }
    float epsv = 1.f + eps_p[0];
    int lane = threadIdx.x & 63;
    int gw = (blockIdx.x * 256 + threadIdx.x) >> 6;
    int nw = (gridDim.x * 256) >> 6;
    for (int u = gw; u < n_nodes; u += nw) {
        const ushort_t* own = in + (long)u * 256;
        float acc[4];
        #pragma unroll
        for (int j = 0; j < 4; ++j) acc[j] = epsv * h2f(own[lane + 64 * j]);
        int s = offs[u], e = offs[u + 1];
        for (int i = s; i < e; ++i) {
            int eid = elist[i];
            int sid = esrc[eid];
            const ushort_t* row = in + (long)sid * 256;
            if (EB) {
                float ev[16];
                const float4* ea = (const float4*)(eattr + (long)eid * 16);
                float4 e0 = ea[0], e1 = ea[1], e2 = ea[2], e3 = ea[3];
                ev[0]=e0.x; ev[1]=e0.y; ev[2]=e0.z; ev[3]=e0.w;
                ev[4]=e1.x; ev[5]=e1.y; ev[6]=e1.z; ev[7]=e1.w;
                ev[8]=e2.x; ev[9]=e2.y; ev[10]=e2.z; ev[11]=e2.w;
                ev[12]=e3.x; ev[13]=e3.y; ev[14]=e3.z; ev[15]=e3.w;
                #pragma unroll
                for (int j = 0; j < 4; ++j) {
                    int c = lane + 64 * j;
                    float m = bs[c];
                    #pragma unroll
                    for (int k = 0; k < 16; ++k) m = fmaf(ev[k], Ws[k * 256 + c], m);
                    acc[j] += fmaxf(h2f(row[c]) + m, 0.f);
                }
            } else {
                #pragma unroll
                for (int j = 0; j < 4; ++j) acc[j] += h2f(row[lane + 64 * j]);
            }
        }
        ushort_t* o = out + (long)u * 256;
        #pragma unroll
        for (int j = 0; j < 4; ++j) o[lane + 64 * j] = f2h(acc[j]);
    }
}

// out[u] = relu(aff(raw[u])) + mean_{i in csr[u]} U[midx[elist[i]]]   (256 ch)
__global__ __launch_bounds__(128)
void csr_mean_aff(const ushort_t* __restrict__ raw, const ushort_t* __restrict__ U,
                  const int* __restrict__ midx, const int* __restrict__ elist,
                  const int* __restrict__ offs, const float* __restrict__ Aff,
                  ushort_t* __restrict__ outp)
{
    int u = blockIdx.x, t = threadIdx.x;
    int c0 = t * 2;
    float sa0 = Aff[c0], sa1 = Aff[c0 + 1], sb0 = Aff[256 + c0], sb1 = Aff[256 + c0 + 1];
    ushort2 b = *(const ushort2*)(raw + (long)u * 256 + c0);
    float x0 = fmaxf(h2f(b.x) * sa0 + sb0, 0.f);
    float x1 = fmaxf(h2f(b.y) * sa1 + sb1, 0.f);
    int s = offs[u], e = offs[u + 1];
    float a0 = 0.f, a1 = 0.f;
    for (int i = s; i < e; ++i) {
        long r = midx[elist[i]];
        ushort2 v = *(const ushort2*)(U + r * 256 + c0);
        a0 += h2f(v.x); a1 += h2f(v.y);
    }
    if (e > s) { float inv = 1.f / (float)(e - s); x0 += a0 * inv; x1 += a1 * inv; }
    ushort2 o; o.x = f2h(x0); o.y = f2h(x1);
    *(ushort2*)(outp + (long)u * 256 + c0) = o;
}

// ---------------------------------------------------------------------------
// fp32 GEMM for readout (small). LDA=133: conflict-free A-tile writes.
// ---------------------------------------------------------------------------
template<int RELU, typename TC>
__global__ __launch_bounds__(256)
void gemm_k(const float* __restrict__ A, const float* __restrict__ W,
            const float* __restrict__ bias, TC* __restrict__ C,
            int N, int K, int M)
{
    const int BK = 16, LDA = 133;
    __shared__ float As[BK * LDA];
    __shared__ float Bs[BK * LDA];
    const int brow = blockIdx.y * 128;
    const int bcol = blockIdx.x * 128;
    const int tid  = threadIdx.x;
    const int tr = tid >> 4, tc = tid & 15;

    float acc[8][8];
    #pragma unroll
    for (int i = 0; i < 8; ++i)
        #pragma unroll
        for (int j = 0; j < 8; ++j) acc[i][j] = 0.f;

    for (int k0 = 0; k0 < K; k0 += BK) {
        #pragma unroll
        for (int u = 0; u < 8; ++u) {
            int idx = tid + u * 256;
            int m = idx >> 4, kk = idx & 15;
            As[kk * LDA + m] = A[(long)(brow + m) * K + k0 + kk];
        }
        #pragma unroll
        for (int u = 0; u < 8; ++u) {
            int idx = tid + u * 256;
            int kk = idx >> 7, n = idx & 127;
            int col = bcol + n;
            Bs[kk * LDA + n] = (col < M) ? W[(long)(k0 + kk) * M + col] : 0.f;
        }
        __syncthreads();
        #pragma unroll
        for (int kk = 0; kk < BK; ++kk) {
            float av[8], bv[8];
            float4 a0 = *(const float4*)&As[kk * LDA + tr * 8];
            float4 a1 = *(const float4*)&As[kk * LDA + tr * 8 + 4];
            float4 b0 = *(const float4*)&Bs[kk * LDA + tc * 8];
            float4 b1 = *(const float4*)&Bs[kk * LDA + tc * 8 + 4];
            av[0]=a0.x; av[1]=a0.y; av[2]=a0.z; av[3]=a0.w;
            av[4]=a1.x; av[5]=a1.y; av[6]=a1.z; av[7]=a1.w;
            bv[0]=b0.x; bv[1]=b0.y; bv[2]=b0.z; bv[3]=b0.w;
            bv[4]=b1.x; bv[5]=b1.y; bv[6]=b1.z; bv[7]=b1.w;
            #pragma unroll
            for (int i = 0; i < 8; ++i)
                #pragma unroll
                for (int j = 0; j < 8; ++j)
                    acc[i][j] = fmaf(av[i], bv[j], acc[i][j]);
        }
        __syncthreads();
    }
    #pragma unroll
    for (int i = 0; i < 8; ++i) {
        int row = brow + tr * 8 + i;
        #pragma unroll
        for (int j = 0; j < 8; ++j) {
            int col = bcol + tc * 8 + j;
            if (col < M) {
                float v = acc[i][j] + bias[col];
                if (RELU) v = fmaxf(v, 0.f);
                if constexpr (sizeof(TC) == 2) ((ushort_t*)C)[(long)row * M + col] = f2h(v);
                else                           ((float*)C)[(long)row * M + col] = v;
            }
        }
    }
}

__global__ void count_idx(const int* __restrict__ idx, int n, int* __restrict__ cnt)
{
    int i = blockIdx.x * blockDim.x + threadIdx.x;
    if (i < n) atomicAdd(&cnt[idx[i]], 1);
}

// ---- parallel exclusive scan (3 phases) ----
__global__ __launch_bounds__(256)
void scan_p1(const int* __restrict__ cnt, int n, int* __restrict__ partials)
{
    __shared__ int sd[256];
    int i = blockIdx.x * 256 + threadIdx.x;
    sd[threadIdx.x] = (i < n) ? cnt[i] : 0;
    __syncthreads();
    #pragma unroll
    for (int s = 128; s > 0; s >>= 1) {
        if (threadIdx.x < s) sd[threadIdx.x] += sd[threadIdx.x + s];
        __syncthreads();
    }
    if (threadIdx.x == 0) partials[blockIdx.x] = sd[0];
}

__global__ __launch_bounds__(1024)
void scan_p2(int* __restrict__ partials, int nb, int* __restrict__ off, int n)
{
    __shared__ int sd[1024];
    int t = threadIdx.x;
    int v = (t < nb) ? partials[t] : 0;
    sd[t] = v;
    __syncthreads();
    for (int d = 1; d < 1024; d <<= 1) {
        int x = (t >= d) ? sd[t - d] : 0;
        __syncthreads();
        sd[t] += x;
        __syncthreads();
    }
    if (t < nb) partials[t] = sd[t] - v;
    if (t == 1023) off[n] = sd[nb - 1];
}

__global__ __launch_bounds__(256)
void scan_p3(const int* __restrict__ cnt, int n, const int* __restrict__ partials,
             int* __restrict__ off, int* __restrict__ cursor)
{
    __shared__ int sd[256];
    int i = blockIdx.x * 256 + threadIdx.x;
    int v = (i < n) ? cnt[i] : 0;
    sd[threadIdx.x] = v;
    __syncthreads();
    for (int d = 1; d < 256; d <<= 1) {
        int x = (threadIdx.x >= d) ? sd[threadIdx.x - d] : 0;
        __syncthreads();
        sd[threadIdx.x] += x;
        __syncthreads();
    }
    if (i < n) {
        int e = partials[blockIdx.x] + sd[threadIdx.x] - v;
        off[i] = e; cursor[i] = e;
    }
}

__global__ void csr_fill(const int* __restrict__ idx, int n,
                         int* __restrict__ cursor, int* __restrict__ elist)
{
    int i = blockIdx.x * blockDim.x + threadIdx.x;
    if (i < n) { int p = atomicAdd(&cursor[idx[i]], 1); elist[p] = i; }
}

__global__ __launch_bounds__(256)
void seg_pool(const ushort_t* __restrict__ X, const int* __restrict__ bidx,
              int nrows, float* __restrict__ pooled)
{
    int b = blockIdx.x, t = threadIdx.x;
    int lo = 0, hi = nrows;
    while (lo < hi) { int mid = (lo + hi) >> 1; if (bidx[mid] < b) lo = mid + 1; else hi = mid; }
    int s = lo; hi = nrows;
    while (lo < hi) { int mid = (lo + hi) >> 1; if (bidx[mid] < b + 1) lo = mid + 1; else hi = mid; }
    int e = lo;
    float acc = 0.f;
    for (int r = s; r < e; ++r) acc += h2f(X[(long)r * 256 + t]);
    pooled[(long)b * 256 + t] = acc / fmaxf((float)(e - s), 1.f);
}

__global__ void vadd(float* __restrict__ out, const float* __restrict__ in, long n4)
{
    long t = (long)blockIdx.x * blockDim.x + threadIdx.x;
    if (t >= n4) return;
    float4 a = ((float4*)out)[t];
    float4 b = ((const float4*)in)[t];
    a.x += b.x; a.y += b.y; a.z += b.z; a.w += b.w;
    ((float4*)out)[t] = a;
}

// ---------------------------------------------------------------------------
extern "C" void kernel_launch(void* const* d_in, const int* in_sizes, int n_in,
                              void* d_out, int out_size, void* d_ws, size_t ws_size,
                              hipStream_t stream)
{
    (void)in_sizes; (void)n_in;
    const float* x          = (const float*)d_in[0];
    const float* fragments  = (const float*)d_in[1];
    const float* edge_attr  = (const float*)d_in[2];
    const float* atom_enc_W = (const float*)d_in[3];
    const float* atom_enc_b = (const float*)d_in[4];
    const float* frag_enc_W = (const float*)d_in[5];
    const float* frag_enc_b = (const float*)d_in[6];
    const float* bond_W     = (const float*)d_in[7];
    const float* bond_b     = (const float*)d_in[8];
    const float* gine_eps   = (const float*)d_in[9];
    const float* gine_W1    = (const float*)d_in[10];
    const float* gine_b1    = (const float*)d_in[11];
    const float* gine_bn_g  = (const float*)d_in[12];
    const float* gine_bn_b  = (const float*)d_in[13];
    const float* gine_W2    = (const float*)d_in[14];
    const float* gine_b2    = (const float*)d_in[15];
    const float* atom_bn_g  = (const float*)d_in[16];
    const float* atom_bn_b  = (const float*)d_in[17];
    const float* gin_eps    = (const float*)d_in[18];
    const float* gin_W1     = (const float*)d_in[19];
    const float* gin_b1     = (const float*)d_in[20];
    const float* gin_bn_g   = (const float*)d_in[21];
    const float* gin_bn_b   = (const float*)d_in[22];
    const float* gin_W2     = (const float*)d_in[23];
    const float* gin_b2     = (const float*)d_in[24];
    const float* frag_bn_g  = (const float*)d_in[25];
    const float* frag_bn_b  = (const float*)d_in[26];
    const float* a2f_W      = (const float*)d_in[27];
    const float* a2f_b      = (const float*)d_in[28];
    const float* f2a_W      = (const float*)d_in[29];
    const float* f2a_b      = (const float*)d_in[30];
    const float* fo_W1      = (const float*)d_in[31];
    const float* fo_b1      = (const float*)d_in[32];
    const float* fo_W2      = (const float*)d_in[33];
    const float* fo_b2      = (const float*)d_in[34];
    const float* ao_W1      = (const float*)d_in[35];
    const float* ao_b1      = (const float*)d_in[36];
    const float* ao_W2      = (const float*)d_in[37];
    const float* ao_b2      = (const float*)d_in[38];
    const float* out_W1     = (const float*)d_in[39];
    const float* out_b1     = (const float*)d_in[40];
    const float* out_W2     = (const float*)d_in[41];
    const float* out_b2     = (const float*)d_in[42];
    const int* edge_index   = (const int*)d_in[43];
    const int* fedge_index  = (const int*)d_in[44];
    const int* batch        = (const int*)d_in[45];
    const int* fbatch       = (const int*)d_in[46];
    const int* mem_atom     = (const int*)d_in[47];
    const int* mem_frag     = (const int*)d_in[48];

    const int* src  = edge_index;
    const int* dst  = edge_index + N_EDGE;
    const int* fsrc = fedge_index;
    const int* fdst = fedge_index + N_FEDGE;

    // ---- arena ----
    const size_t WPN = 2646016;   // total prepped-weight elems (incl. encoders)
    size_t off = 0;
    auto take = [&](size_t b) -> size_t { size_t p = off; off = (off + b + 255) & ~(size_t)255; return p; };
    size_t o_big   = take((size_t)N_ATOM * 512 * 2);     // 134 MB
    size_t o_a     = take((size_t)N_ATOM * H * 2);       // 67 MB
    size_t o_f     = take((size_t)N_FRAG * H * 2);
    size_t o_f2    = take((size_t)N_FRAG * H * 2);
    size_t o_offea = take((size_t)(N_ATOM + 1) * 4);
    size_t o_elea  = take((size_t)N_EDGE * 4);
    size_t o_offef = take((size_t)(N_FRAG + 1) * 4);
    size_t o_elef  = take((size_t)N_FEDGE * 4);
    size_t o_offma = take((size_t)(N_ATOM + 1) * 4);
    size_t o_elma  = take((size_t)N_MEM * 4);
    size_t o_offmf = take((size_t)(N_FRAG + 1) * 4);
    size_t o_elmf  = take((size_t)N_MEM * 4);
    size_t o_cnta  = take((size_t)N_ATOM * 4);
    size_t o_cntf  = take((size_t)N_FRAG * 4);
    size_t o_part  = take(1024 * 4);
    size_t o_stats = take((size_t)NREP * 3072 * 4);
    size_t o_aff   = take(3072 * 4);
    size_t o_hi    = take(WPN * 2);
    size_t need = off;

    if (need > ws_size) {
        fill_const<<<64, 256, 0, stream>>>((float*)d_out, out_size,
                                           (float)((double)ws_size / 1024.0));
        return;
    }
    char* base = (char*)d_ws;
    char*     big     = base + o_big;
    ushort_t* a       = (ushort_t*)(base + o_a);
    ushort_t* f       = (ushort_t*)(base + o_f);
    ushort_t* f2      = (ushort_t*)(base + o_f2);
    int* off_ea = (int*)(base + o_offea);
    int* el_ea  = (int*)(base + o_elea);
    int* off_ef = (int*)(base + o_offef);
    int* el_ef  = (int*)(base + o_elef);
    int* off_ma = (int*)(base + o_offma);
    int* el_ma  = (int*)(base + o_elma);
    int* off_mf = (int*)(base + o_offmf);
    int* el_mf  = (int*)(base + o_elmf);
    int* cnt_a  = (int*)(base + o_cnta);
    int* cnt_f  = (int*)(base + o_cntf);
    int* parts  = (int*)(base + o_part);
    float* statsR = (float*)(base + o_stats);
    float* affs   = (float*)(base + o_aff);
    ushort_t* Wp_hi = (ushort_t*)(base + o_hi);

    float* cst1a = statsR;
    float* cst2a = statsR + (size_t)NREP * 1024;
    float* cst1f = statsR + (size_t)NREP * 1536;
    float* cst2f = statsR + (size_t)NREP * 2560;
    float* aff1_a = affs;
    float* aff2_a = affs + 1024;
    float* aff1_f = affs + 1536;
    float* aff2_f = affs + 2560;

    ushort_t* big_u = (ushort_t*)big;
    const size_t HALF_U = (size_t)N_ATOM * 256;
    ushort_t* ha  = big_u + HALF_U;
    const size_t PAN_A = (size_t)N_ATOM * 128;
    const size_t PAN_F = (size_t)N_FRAG * 128;
    ushort_t* Ua = big_u;
    float* pooled_f = (float*)big;
    float* pooled_a = (float*)(big + (size_t)8 * 1024 * 1024);
    float* tmp      = (float*)(big + (size_t)16 * 1024 * 1024);
    // encoder-time aliases of big (consumed before layer loop writes big)
    ushort_t* xh = big_u;                                 // 131072*64 f16
    ushort_t* fh = big_u + (size_t)N_ATOM * 64;           // 32768*32 f16

    const long WG0 = 0, WG1 = 524288, WG2 = 1048576, WG3 = 1572864,
               WG4 = 2097152, WG5 = 2359296, WG6 = 2621440, WG7 = 2637824;

    auto build_csr = [&](const int* idx, int n_edges, int n_nodes,
                         int* cnt, int* offs, int* elist) {
        hipMemsetAsync(cnt, 0, (size_t)n_nodes * 4, stream);
        count_idx<<<CDIV(n_edges,256),256,0,stream>>>(idx, n_edges, cnt);
        int nb = CDIV(n_nodes, 256);
        scan_p1<<<nb, 256, 0, stream>>>(cnt, n_nodes, parts);
        scan_p2<<<1, 1024, 0, stream>>>(parts, nb, offs, n_nodes);
        scan_p3<<<nb, 256, 0, stream>>>(cnt, n_nodes, parts, offs, cnt);
        csr_fill<<<CDIV(n_edges,256),256,0,stream>>>(idx, n_edges, cnt, elist);
    };

    // ---- weight prep + CSR builds ----
    prep_w<<<CDIV((long)WPN, 256), 256, 0, stream>>>(gine_W1, gine_W2, gin_W1, gin_W2,
                                                     a2f_W, f2a_W, atom_enc_W, frag_enc_W,
                                                     Wp_hi);
    build_csr(dst,      N_EDGE,  N_ATOM, cnt_a, off_ea, el_ea);
    build_csr(fdst,     N_FEDGE, N_FRAG, cnt_f, off_ef, el_ef);
    build_csr(mem_atom, N_MEM,   N_ATOM, cnt_a, off_ma, el_ma);
    build_csr(mem_frag, N_MEM,   N_FRAG, cnt_f, off_mf, el_mf);

    // ---- encoders via MFMA (f16 inputs staged in big) ----
    conv_f2h<<<2048, 256, 0, stream>>>(x, xh, (long)N_ATOM * 64);
    conv_f2h<<<512, 256, 0, stream>>>(fragments, fh, (long)N_FRAG * 32);
    {
        PanelsIn Ein; PanelsOut Eout;
        for (int i = 0; i < 4; ++i) Ein.p[i] = xh;
        Eout.p[0] = a; Eout.p[1] = a + 128; Eout.p[2] = a; Eout.p[3] = a;
        mfma_gemm<0><<<dim3(2, N_ATOM/128), 256, 0, stream>>>(
            Ein, 64, Wp_hi + WG6, atom_enc_b, Eout, 256, nullptr, nullptr,
            N_ATOM, 64, 256);
        PanelsIn Fin; PanelsOut Fout;
        for (int i = 0; i < 4; ++i) Fin.p[i] = fh;
        Fout.p[0] = f; Fout.p[1] = f + 128; Fout.p[2] = f; Fout.p[3] = f;
        mfma_gemm<0><<<dim3(2, N_FRAG/128), 256, 0, stream>>>(
            Fin, 32, Wp_hi + WG7, frag_enc_b, Fout, 256, nullptr, nullptr,
            N_FRAG, 32, 256);
    }

    const float invNA = 1.f / N_ATOM, invNF = 1.f / N_FRAG;

    for (int l = 0; l < 4; ++l) {
        hipMemsetAsync(statsR, 0, (size_t)NREP * 3072 * 4, stream);

        // ===== atoms: GINE + MLP =====
        csr_agg<1><<<2048, 256, 0, stream>>>(a, ha, off_ea, el_ea, src, edge_attr,
            bond_W + (long)l*16*H, bond_b + l*H, gine_eps + l, N_ATOM);

        PanelsIn A1in; PanelsOut A1out;
        for (int i = 0; i < 4; ++i) A1in.p[i] = ha + i * 128;
        A1out.p[0] = a;          A1out.p[1] = a + PAN_A;
        A1out.p[2] = big_u;      A1out.p[3] = big_u + PAN_A;
        mfma_gemm<0><<<dim3(4, N_ATOM/128), 256, 0, stream>>>(
            A1in, 256, Wp_hi + WG0 + (long)l*131072,
            gine_b1 + l*512, A1out, 128, nullptr, cst1a, N_ATOM, 256, 512);
        finalize_aff<<<2, 256, 0, stream>>>(cst1a, 512, invNA,
            gine_bn_g + l*512, gine_bn_b + l*512, aff1_a);

        PanelsIn A2in; PanelsOut A2out;
        A2in.p[0] = a;       A2in.p[1] = a + PAN_A;
        A2in.p[2] = big_u;   A2in.p[3] = big_u + PAN_A;
        A2out.p[0] = ha; A2out.p[1] = ha + 128; A2out.p[2] = ha; A2out.p[3] = ha;
        mfma_gemm<0><<<dim3(2, N_ATOM/128), 256, 0, stream>>>(
            A2in, 128, Wp_hi + WG1 + (long)l*131072,
            gine_b2 + l*H, A2out, 256, aff1_a, cst2a, N_ATOM, 512, 256);
        finalize_aff<<<1, 256, 0, stream>>>(cst2a, 256, invNA,
            atom_bn_g + l*H, atom_bn_b + l*H, aff2_a);

        // ===== fragments: GIN + MLP =====
        csr_agg<0><<<512, 256, 0, stream>>>(f, f2, off_ef, el_ef, fsrc, nullptr,
            nullptr, nullptr, gin_eps + l, N_FRAG);

        PanelsIn F1in; PanelsOut F1out;
        for (int i = 0; i < 4; ++i) F1in.p[i] = f2 + i * 128;
        for (int i = 0; i < 4; ++i) F1out.p[i] = big_u + i * PAN_F;
        mfma_gemm<0><<<dim3(4, N_FRAG/128), 256, 0, stream>>>(
            F1in, 256, Wp_hi + WG2 + (long)l*131072,
            gin_b1 + l*512, F1out, 128, nullptr, cst1f, N_FRAG, 256, 512);
        finalize_aff<<<2, 256, 0, stream>>>(cst1f, 512, invNF,
            gin_bn_g + l*512, gin_bn_b + l*512, aff1_f);

        PanelsIn F2in; PanelsOut F2out;
        for (int i = 0; i < 4; ++i) F2in.p[i] = big_u + i * PAN_F;
        F2out.p[0] = f2; F2out.p[1] = f2 + 128; F2out.p[2] = f2; F2out.p[3] = f2;
        mfma_gemm<0><<<dim3(2, N_FRAG/128), 256, 0, stream>>>(
            F2in, 128, Wp_hi + WG3 + (long)l*131072,
            gin_b2 + l*H, F2out, 256, aff1_f, cst2f, N_FRAG, 512, 256);
        finalize_aff<<<1, 256, 0, stream>>>(cst2f, 256, invNF,
            frag_bn_g + l*H, frag_bn_b + l*H, aff2_f);

        // ===== inter MP =====
        PanelsIn UAin; PanelsOut UAout;
        for (int i = 0; i < 4; ++i) UAin.p[i] = ha + i * 128;
        UAout.p[0] = Ua; UAout.p[1] = Ua + 128; UAout.p[2] = Ua; UAout.p[3] = Ua;
        mfma_gemm<1><<<dim3(2, N_ATOM/128), 256, 0, stream>>>(
            UAin, 256, Wp_hi + WG4 + (long)l*65536,
            a2f_b + l*H, UAout, 256, aff2_a, nullptr, N_ATOM, 256, 256);
        csr_mean_aff<<<N_FRAG, 128, 0, stream>>>(f2, Ua, mem_atom, el_mf, off_mf,
                                                 aff2_f, f);
        PanelsIn UFin; PanelsOut UFout;
        for (int i = 0; i < 4; ++i) UFin.p[i] = f + i * 128;
        UFout.p[0] = f2; UFout.p[1] = f2 + 128; UFout.p[2] = f2; UFout.p[3] = f2;
        mfma_gemm<1><<<dim3(2, N_FRAG/128), 256, 0, stream>>>(
            UFin, 256, Wp_hi + WG5 + (long)l*65536,
            f2a_b + l*H, UFout, 256, nullptr, nullptr, N_FRAG, 256, 256);
        csr_mean_aff<<<N_ATOM, 128, 0, stream>>>(ha, f2, mem_frag, el_ma, off_ma,
                                                 aff2_a, a);
    }

    // ===== readout =====
    seg_pool<<<BATCH, 256, 0, stream>>>(f, fbatch, N_FRAG, pooled_f);
    gemm_k<1,float><<<dim3(2, BATCH/128), 256, 0, stream>>>(
        pooled_f, fo_W1, fo_b1, tmp, BATCH, H, H);
    gemm_k<1,float><<<dim3(2, BATCH/128), 256, 0, stream>>>(
        tmp, fo_W2, fo_b2, pooled_f, BATCH, H, H);

    seg_pool<<<BATCH, 256, 0, stream>>>(a, batch, N_ATOM, pooled_a);
    gemm_k<1,float><<<dim3(2, BATCH/128), 256, 0, stream>>>(
        pooled_a, ao_W1, ao_b1, tmp, BATCH, H, H);
    gemm_k<1,float><<<dim3(2, BATCH/128), 256, 0, stream>>>(
        tmp, ao_W2, ao_b2, pooled_a, BATCH, H, H);

    vadd<<<(int)CDIV((long)BATCH*H/4,256), 256, 0, stream>>>(
        pooled_a, pooled_f, (long)BATCH * H / 4);
    gemm_k<1,float><<<dim3(2, BATCH/128), 256, 0, stream>>>(
        pooled_a, out_W1, out_b1, tmp, BATCH, H, H);
    gemm_k<0,float><<<dim3(1, BATCH/128), 256, 0, stream>>>(
        tmp, out_W2, out_b2, (float*)d_out, BATCH, H, 1);
}